// Round 3
// baseline (697.324 us; speedup 1.0000x reference)
//
#include <hip/hip_runtime.h>

// ---------------- constants ----------------
#define Bb 8
#define Tt 512
#define Cc 1024
#define Hh 16
#define Nh 64
#define Mm 4096            // B*T
#define BTC 4194304        // M*C
#define DEV __device__ __forceinline__

typedef __attribute__((ext_vector_type(8))) short short8;
typedef __attribute__((ext_vector_type(4))) float f32x4;

DEV unsigned short f2bf(float f) {
  unsigned int u = __builtin_bit_cast(unsigned int, f);
  u += 0x7fffu + ((u >> 16) & 1u);
  return (unsigned short)(u >> 16);
}

// DPP butterfly add — pure VALU. 0xB1=quad xor1, 0x4E=quad xor2,
// 0x124=row_ror:4, 0x128=row_ror:8 (within 16-lane DPP row).
// After xor1+xor2 each quad holds its quad-sum; ror:4 adds the
// neighboring quad's sum, ror:8 adds the remaining half -> full 16-lane sum.
template <int CTRL>
DEV float dppadd(float x) {
  int xi = __builtin_bit_cast(int, x);
  int yi = __builtin_amdgcn_update_dpp(0, xi, CTRL, 0xF, 0xF, true);
  return x + __builtin_bit_cast(float, yi);
}

// ---------------- merged transpose f32 (K x N) -> bf16 (N x K) ----------------
// 8 jobs in one dispatch (R3: was 8 separate launches ~2-3us overhead each).
struct TDesc { const float* in; unsigned short* out; int K, N, bstart, nbx; };
struct TPack { TDesc d[8]; };

__global__ __launch_bounds__(256) void kt_transpose_multi(TPack p) {
  __shared__ float tile[32][33];
  const int bid = blockIdx.x;
  int i = 0;
  #pragma unroll
  for (int j = 1; j < 8; ++j) if (bid >= p.d[j].bstart) i = j;
  const float* in = p.d[i].in;
  unsigned short* out = p.d[i].out;
  const int K = p.d[i].K, N = p.d[i].N;
  const int local = bid - p.d[i].bstart;
  const int byq = local / p.d[i].nbx;
  const int bx = (local - byq * p.d[i].nbx) * 32;
  const int by = byq * 32;
  int tx = threadIdx.x, ty = threadIdx.y;
  #pragma unroll
  for (int q = ty; q < 32; q += 8) {
    int kk = by + q, nn = bx + tx;
    tile[q][tx] = (kk < K && nn < N) ? in[(size_t)kk * N + nn] : 0.f;
  }
  __syncthreads();
  #pragma unroll
  for (int q = ty; q < 32; q += 8) {
    int nn = bx + q, kk = by + tx;
    if (nn < N && kk < K) out[(size_t)nn * K + kk] = f2bf(tile[tx][q]);
  }
}

// batched square 1024x1024 transpose: z selects among 4 matrices
__global__ __launch_bounds__(256) void kt_transpose4(
    const float* __restrict__ i0, const float* __restrict__ i1,
    const float* __restrict__ i2, const float* __restrict__ i3,
    unsigned short* __restrict__ o0, unsigned short* __restrict__ o1,
    unsigned short* __restrict__ o2, unsigned short* __restrict__ o3) {
  __shared__ float tile[32][33];
  const float* in = blockIdx.z == 0 ? i0 : blockIdx.z == 1 ? i1 : blockIdx.z == 2 ? i2 : i3;
  unsigned short* out = blockIdx.z == 0 ? o0 : blockIdx.z == 1 ? o1 : blockIdx.z == 2 ? o2 : o3;
  int bx = blockIdx.x * 32, by = blockIdx.y * 32;
  int tx = threadIdx.x, ty = threadIdx.y;
  #pragma unroll
  for (int i = ty; i < 32; i += 8)
    tile[i][tx] = in[(size_t)(by + i) * 1024 + bx + tx];
  __syncthreads();
  #pragma unroll
  for (int i = ty; i < 32; i += 8)
    out[(size_t)(bx + i) * 1024 + by + tx] = f2bf(tile[tx][i]);
}

// ---------------- block row stats (1024 elems over 256 threads) ----------------
DEV void row_stats(float v0, float v1, float v2, float v3, float* red,
                   float& mu, float& rs, float eps) {
  float s = v0 + v1 + v2 + v3;
  float q = v0 * v0 + v1 * v1 + v2 * v2 + v3 * v3;
  #pragma unroll
  for (int o = 32; o; o >>= 1) { s += __shfl_down(s, o); q += __shfl_down(q, o); }
  int w = threadIdx.x >> 6;
  __syncthreads();
  if ((threadIdx.x & 63) == 0) { red[w] = s; red[4 + w] = q; }
  __syncthreads();
  s = red[0] + red[1] + red[2] + red[3];
  q = red[4] + red[5] + red[6] + red[7];
  mu = s * (1.f / 1024.f);
  float var = q * (1.f / 1024.f) - mu * mu;
  rs = rsqrtf(var + eps);
}

// ---------------- K1: pre-LN + attn-LN + time-shift mixes ----------------
__global__ __launch_bounds__(256) void k1_mix(
    const float* __restrict__ x,
    const float* __restrict__ lnpw, const float* __restrict__ lnpb,
    const float* __restrict__ lnaw, const float* __restrict__ lnab,
    const float* __restrict__ cr, const float* __restrict__ cw,
    const float* __restrict__ ck, const float* __restrict__ cv,
    const float* __restrict__ ca, const float* __restrict__ cg,
    float* __restrict__ xln,
    unsigned short* __restrict__ mR, unsigned short* __restrict__ mW,
    unsigned short* __restrict__ mK, unsigned short* __restrict__ mV,
    unsigned short* __restrict__ mA, unsigned short* __restrict__ mG) {
  __shared__ float red[8];
  const int row = blockIdx.x;
  const int t = row & (Tt - 1);
  const int tid = threadIdx.x;
  const int c = tid * 4;
  const size_t base = (size_t)row * Cc + c;
  float a0 = x[base], a1 = x[base + 1], a2 = x[base + 2], a3 = x[base + 3];
  float mu, rs;
  row_stats(a0, a1, a2, a3, red, mu, rs, 1e-5f);
  float pw0 = lnpw[c], pw1 = lnpw[c + 1], pw2 = lnpw[c + 2], pw3 = lnpw[c + 3];
  float pb0 = lnpb[c], pb1 = lnpb[c + 1], pb2 = lnpb[c + 2], pb3 = lnpb[c + 3];
  float l0 = (a0 - mu) * rs * pw0 + pb0, l1 = (a1 - mu) * rs * pw1 + pb1;
  float l2 = (a2 - mu) * rs * pw2 + pb2, l3 = (a3 - mu) * rs * pw3 + pb3;
  float4 st; st.x = l0; st.y = l1; st.z = l2; st.w = l3;
  *(float4*)(xln + base) = st;
  row_stats(l0, l1, l2, l3, red, mu, rs, 1e-5f);
  float aw0 = lnaw[c], aw1 = lnaw[c + 1], aw2 = lnaw[c + 2], aw3 = lnaw[c + 3];
  float ab0 = lnab[c], ab1 = lnab[c + 1], ab2 = lnab[c + 2], ab3 = lnab[c + 3];
  float n0 = (l0 - mu) * rs * aw0 + ab0, n1 = (l1 - mu) * rs * aw1 + ab1;
  float n2 = (l2 - mu) * rs * aw2 + ab2, n3 = (l3 - mu) * rs * aw3 + ab3;
  float p0 = 0.f, p1 = 0.f, p2 = 0.f, p3 = 0.f;
  if (t > 0) {  // uniform over block
    const size_t pb_ = base - Cc;
    float q0 = x[pb_], q1 = x[pb_ + 1], q2 = x[pb_ + 2], q3 = x[pb_ + 3];
    row_stats(q0, q1, q2, q3, red, mu, rs, 1e-5f);
    float e0 = (q0 - mu) * rs * pw0 + pb0, e1 = (q1 - mu) * rs * pw1 + pb1;
    float e2 = (q2 - mu) * rs * pw2 + pb2, e3 = (q3 - mu) * rs * pw3 + pb3;
    row_stats(e0, e1, e2, e3, red, mu, rs, 1e-5f);
    p0 = (e0 - mu) * rs * aw0 + ab0; p1 = (e1 - mu) * rs * aw1 + ab1;
    p2 = (e2 - mu) * rs * aw2 + ab2; p3 = (e3 - mu) * rs * aw3 + ab3;
  }
  float d0 = p0 - n0, d1 = p1 - n1, d2 = p2 - n2, d3 = p3 - n3;
  #define EMIT(cf, dst) { \
    float f0 = cf[c], f1 = cf[c + 1], f2 = cf[c + 2], f3 = cf[c + 3]; \
    ushort4 u; u.x = f2bf(n0 + d0 * f0); u.y = f2bf(n1 + d1 * f1); \
    u.z = f2bf(n2 + d2 * f2); u.w = f2bf(n3 + d3 * f3); \
    *(ushort4*)(dst + base) = u; }
  EMIT(cr, mR) EMIT(cw, mW) EMIT(ck, mK) EMIT(cv, mV) EMIT(ca, mA) EMIT(cg, mG)
  #undef EMIT
}

// ---------------- bf16 MFMA GEMM (m97-style staging) ----------------
// A: (M,K) bf16 row-major; Bt: (N,K) bf16 row-major.
// MODE: 0 f32 | 1 bf16 | 2 tanh->bf16 | 3 sigmoid->bf16 | 4 relu^2->bf16
//       5 sigmoid(z+bias[col])->f32 | 6 exp(-sigmoid(z+bias[col])*e^-.5)->f32 | 7 z+res->f32
DEV void gll16(const unsigned short* g, unsigned short* l) {
  __builtin_amdgcn_global_load_lds(
      (const __attribute__((address_space(1))) void*)g,
      (__attribute__((address_space(3))) void*)l, 16, 0, 0);
}

template <int MODE>
DEV void gemm_epi(float z, size_t oi, int col,
                  float* outF, unsigned short* outB,
                  const float* bias, const float* res) {
  if constexpr (MODE == 0) outF[oi] = z;
  else if constexpr (MODE == 1) outB[oi] = f2bf(z);
  else if constexpr (MODE == 2) outB[oi] = f2bf(tanhf(z));
  else if constexpr (MODE == 3) outB[oi] = f2bf(1.f / (1.f + expf(-z)));
  else if constexpr (MODE == 4) { float m = fmaxf(z, 0.f); outB[oi] = f2bf(m * m); }
  else if constexpr (MODE == 5) { z += bias[col]; outF[oi] = 1.f / (1.f + expf(-z)); }
  else if constexpr (MODE == 6) {
    z += bias[col];
    float sg = 1.f / (1.f + expf(-z));
    outF[oi] = expf(-0.6065306597126334f * sg);
  } else { outF[oi] = z + res[oi]; }
}

// 128M x 64N tile: for N=1024 grids -> 512 blocks = 2/CU (barrier drain of one
// block hides behind the other's MFMA).
template <int MODE>
__global__ __launch_bounds__(256) void kg_gemm(
    const unsigned short* __restrict__ A, const unsigned short* __restrict__ Bt,
    int M, int Nn, int K,
    float* __restrict__ outF, unsigned short* __restrict__ outB,
    const float* __restrict__ bias, const float* __restrict__ res) {
  __shared__ unsigned short lsA[128 * 32];
  __shared__ unsigned short lsB[64 * 32];
  const int tid = threadIdx.x;
  const int lane = tid & 63;
  const int wave = tid >> 6;
  const int wy = wave >> 1, wx = wave & 1;
  const int m0 = blockIdx.y * 128;
  const int n0 = blockIdx.x * 64;
  const int sl4 = lane >> 2;        // row within 16-row group
  const int sc = (lane & 3) << 3;   // k-elem offset {0,8,16,24}
  f32x4 acc[4][2];
  #pragma unroll
  for (int i = 0; i < 4; ++i)
    #pragma unroll
    for (int j = 0; j < 2; ++j) { f32x4 z = {0.f, 0.f, 0.f, 0.f}; acc[i][j] = z; }
  const int fr = lane & 15;
  const int fk = (lane >> 4) << 3;
  for (int k0 = 0; k0 < K; k0 += 32) {
    #pragma unroll
    for (int j = 0; j < 2; ++j) {        // A: 8 groups of 16 rows, wave does 2
      const int rb = (wave + j * 4) * 16;
      gll16(A + (size_t)(m0 + rb + sl4) * K + k0 + sc, lsA + rb * 32);
    }
    {                                    // B: 4 groups, wave does 1
      const int rb = wave * 16;
      int br = n0 + rb + sl4;
      br = br < Nn ? br : Nn - 1;
      gll16(Bt + (size_t)br * K + k0 + sc, lsB + rb * 32);
    }
    __syncthreads();
    short8 af[4], bf[2];
    #pragma unroll
    for (int mt = 0; mt < 4; ++mt)
      af[mt] = *(const short8*)(lsA + (wy * 64 + mt * 16 + fr) * 32 + fk);
    #pragma unroll
    for (int nt = 0; nt < 2; ++nt)
      bf[nt] = *(const short8*)(lsB + (wx * 32 + nt * 16 + fr) * 32 + fk);
    #pragma unroll
    for (int mt = 0; mt < 4; ++mt)
      #pragma unroll
      for (int nt = 0; nt < 2; ++nt)
        acc[mt][nt] = __builtin_amdgcn_mfma_f32_16x16x32_bf16(af[mt], bf[nt], acc[mt][nt], 0, 0, 0);
    __syncthreads();
  }
  const int rbase = (lane >> 4) << 2;
  const int cbase = lane & 15;
  #pragma unroll
  for (int mt = 0; mt < 4; ++mt)
    #pragma unroll
    for (int nt = 0; nt < 2; ++nt)
      #pragma unroll
      for (int rr = 0; rr < 4; ++rr) {
        int row = m0 + wy * 64 + mt * 16 + rbase + rr;
        int col = n0 + wx * 32 + nt * 16 + cbase;
        if (col < Nn)
          gemm_epi<MODE>(acc[mt][nt][rr], (size_t)row * Nn + col, col, outF, outB, bias, res);
      }
}

// 128M x 128N tile (exact m97 structure) — for large-N GEMMs (FFN1: 1024 blocks).
template <int MODE>
__global__ __launch_bounds__(256) void kg_gemm2(
    const unsigned short* __restrict__ A, const unsigned short* __restrict__ Bt,
    int M, int Nn, int K,
    float* __restrict__ outF, unsigned short* __restrict__ outB,
    const float* __restrict__ bias, const float* __restrict__ res) {
  __shared__ unsigned short lsA[128 * 32];
  __shared__ unsigned short lsB[128 * 32];
  const int tid = threadIdx.x;
  const int lane = tid & 63;
  const int wave = tid >> 6;
  const int wy = wave >> 1, wx = wave & 1;
  const int m0 = blockIdx.y * 128;
  const int n0 = blockIdx.x * 128;
  const int sl4 = lane >> 2;
  const int sc = (lane & 3) << 3;
  f32x4 acc[4][4];
  #pragma unroll
  for (int i = 0; i < 4; ++i)
    #pragma unroll
    for (int j = 0; j < 4; ++j) { f32x4 z = {0.f, 0.f, 0.f, 0.f}; acc[i][j] = z; }
  const int fr = lane & 15;
  const int fk = (lane >> 4) << 3;
  for (int k0 = 0; k0 < K; k0 += 32) {
    #pragma unroll
    for (int j = 0; j < 2; ++j) {        // A and B: 8 groups of 16 rows each, wave does 2+2
      const int rb = (wave + j * 4) * 16;
      gll16(A + (size_t)(m0 + rb + sl4) * K + k0 + sc, lsA + rb * 32);
      int br = n0 + rb + sl4;
      br = br < Nn ? br : Nn - 1;
      gll16(Bt + (size_t)br * K + k0 + sc, lsB + rb * 32);
    }
    __syncthreads();
    short8 af[4], bf[4];
    #pragma unroll
    for (int mt = 0; mt < 4; ++mt)
      af[mt] = *(const short8*)(lsA + (wy * 64 + mt * 16 + fr) * 32 + fk);
    #pragma unroll
    for (int nt = 0; nt < 4; ++nt)
      bf[nt] = *(const short8*)(lsB + (wx * 64 + nt * 16 + fr) * 32 + fk);
    #pragma unroll
    for (int mt = 0; mt < 4; ++mt)
      #pragma unroll
      for (int nt = 0; nt < 4; ++nt)
        acc[mt][nt] = __builtin_amdgcn_mfma_f32_16x16x32_bf16(af[mt], bf[nt], acc[mt][nt], 0, 0, 0);
    __syncthreads();
  }
  const int rbase = (lane >> 4) << 2;
  const int cbase = lane & 15;
  #pragma unroll
  for (int mt = 0; mt < 4; ++mt)
    #pragma unroll
    for (int nt = 0; nt < 4; ++nt)
      #pragma unroll
      for (int rr = 0; rr < 4; ++rr) {
        int row = m0 + wy * 64 + mt * 16 + rbase + rr;
        int col = n0 + wx * 64 + nt * 16 + cbase;
        if (col < Nn)
          gemm_epi<MODE>(acc[mt][nt][rr], (size_t)row * Nn + col, col, outF, outB, bias, res);
      }
}

// ---------------- K4: kk-normalize, a/b vectors, k update (in place) ----------------
__global__ __launch_bounds__(256) void k4_prep(
    float* __restrict__ k, const float* __restrict__ a,
    const float* __restrict__ kkc, const float* __restrict__ kac,
    float* __restrict__ aw, float* __restrict__ bw) {
  const int row = blockIdx.x, tid = threadIdx.x;
  const int c = tid * 4;
  const size_t base = (size_t)row * Cc + c;
  float k0 = k[base], k1 = k[base + 1], k2 = k[base + 2], k3 = k[base + 3];
  float a0 = a[base], a1 = a[base + 1], a2 = a[base + 2], a3 = a[base + 3];
  float h0 = k0 * kkc[c], h1 = k1 * kkc[c + 1], h2 = k2 * kkc[c + 2], h3 = k3 * kkc[c + 3];
  float ss = h0 * h0 + h1 * h1 + h2 * h2 + h3 * h3;
  #pragma unroll
  for (int m = 8; m; m >>= 1) ss += __shfl_xor(ss, m);
  float inv = 1.f / fmaxf(sqrtf(ss), 1e-12f);
  h0 *= inv; h1 *= inv; h2 *= inv; h3 *= inv;
  float4 v4;
  v4.x = -h0; v4.y = -h1; v4.z = -h2; v4.w = -h3;
  *(float4*)(aw + base) = v4;
  v4.x = h0 * a0; v4.y = h1 * a1; v4.z = h2 * a2; v4.w = h3 * a3;
  *(float4*)(bw + base) = v4;
  v4.x = k0 * (1.f + (a0 - 1.f) * kac[c]);
  v4.y = k1 * (1.f + (a1 - 1.f) * kac[c + 1]);
  v4.z = k2 * (1.f + (a2 - 1.f) * kac[c + 2]);
  v4.w = k3 * (1.f + (a3 - 1.f) * kac[c + 3]);
  *(float4*)(k + base) = v4;
}

// ---------------- K5: WKV7 — 4 waves x 8 rows (2 rows/lane): halve LDS issue ----------------
// R3: R2 was LDS-issue-bound (538cy/step measured == 8 waves x 66cy model).
// Operand reads (a,d,b,k,r) are row-independent, so doubling rows/lane halves
// the per-CU LDS instruction count: 4 waves x (5 b128 + 1 b64) = 24 ops/step
// (~270cy) vs R2's 48 (~530cy). Lane = (rg = lane>>4 -> 2 rows, cg = lane&15
// -> 4 cols), S[2][4]; same 16-lane DPP reduce, two independent chains.
// 256 blocks (half x bh) x 256 threads; global traffic unchanged vs R2.
// CS=16 (2 x 24KB LDS, 1 block/CU) halves chunk-barrier overhead.
#define CS 16
__global__ __launch_bounds__(256, 1) void k5_wkv7(
    const float* __restrict__ r, const float* __restrict__ dec,
    const float* __restrict__ k, const float* __restrict__ v,
    const float* __restrict__ aw, const float* __restrict__ bw,
    float* __restrict__ o) {
  const int blk = blockIdx.x;              // 0..255
  const int bh = blk & 127, half = blk >> 7;
  const int b = bh >> 4, h = bh & 15;
  const int tid = threadIdx.x;
  const int lane = tid & 63;
  const int w = tid >> 6;                  // wave 0..3
  const int cg = lane & 15;                // column group (4 cols)
  const int rg = lane >> 4;                // row-pair within wave (0..3)
  const int lrow = half * 32 + w * 8 + rg * 2;  // first of lane's 2 rows (even)
  const int cb = cg << 2;                  // column base j0

  __shared__ float buf[2][6 * CS * 64];    // 2 x 24 KB

  float S[2][4];
  #pragma unroll
  for (int p = 0; p < 2; ++p)
    #pragma unroll
    for (int j = 0; j < 4; ++j) S[p][j] = 0.f;

  const size_t base = (size_t)b * Tt * Cc + (size_t)h * Nh;

  // staging: thread tid loads uint4 #tid of each of the 6 arrays per chunk
  // (array = CS*64 floats = 256 uint4; t = tid>>4, col = (tid&15)*4)
  const int st_t = tid >> 4;
  const int st_c = (tid & 15) << 2;

  uint4 R[6];
  #define LOADC(cstart) { \
    const size_t g0 = base + (size_t)((cstart) + st_t) * Cc + st_c; \
    R[0] = *(const uint4*)(aw  + g0); \
    R[1] = *(const uint4*)(dec + g0); \
    R[2] = *(const uint4*)(bw  + g0); \
    R[3] = *(const uint4*)(k   + g0); \
    R[4] = *(const uint4*)(r   + g0); \
    R[5] = *(const uint4*)(v   + g0); }

  LOADC(0)

  #pragma unroll 1
  for (int c = 0; c < Tt / CS; ++c) {
    float* bp = buf[c & 1];
    #pragma unroll
    for (int j = 0; j < 6; ++j)
      *(uint4*)(bp + j * (CS * 64) + (tid << 2)) = R[j];
    const int cn = (c + 1 < Tt / CS) ? (c + 1) : c;
    LOADC(cn * CS)
    __syncthreads();

    // operand register double-buffer (one step each)
    float4 Aq[2], Dq[2], Bq[2], Kq[2], Rq[2];
    float2 Vv[2];
    #define LOADOPS(slot, ss) { \
      const float* sp_ = bp + (ss) * 64; \
      Aq[slot] = *(const float4*)(sp_ + cb); \
      Dq[slot] = *(const float4*)(sp_ + 1 * (CS * 64) + cb); \
      Bq[slot] = *(const float4*)(sp_ + 2 * (CS * 64) + cb); \
      Kq[slot] = *(const float4*)(sp_ + 3 * (CS * 64) + cb); \
      Rq[slot] = *(const float4*)(sp_ + 4 * (CS * 64) + cb); \
      Vv[slot] = *(const float2*)(sp_ + 5 * (CS * 64) + lrow); }

    LOADOPS(0, 0)
    #pragma unroll
    for (int s = 0; s < CS; ++s) {
      const int cu = s & 1, nx = cu ^ 1;
      if (s + 1 < CS) LOADOPS(nx, s + 1)     // prefetch next step's operands

      float4 a4 = Aq[cu];
      float sa0 = fmaf(S[0][1], a4.y, S[0][0] * a4.x) + fmaf(S[0][3], a4.w, S[0][2] * a4.z);
      float sa1 = fmaf(S[1][1], a4.y, S[1][0] * a4.x) + fmaf(S[1][3], a4.w, S[1][2] * a4.z);
      sa0 = dppadd<0xB1>(sa0);   sa1 = dppadd<0xB1>(sa1);
      sa0 = dppadd<0x4E>(sa0);   sa1 = dppadd<0x4E>(sa1);
      sa0 = dppadd<0x124>(sa0);  sa1 = dppadd<0x124>(sa1);
      sa0 = dppadd<0x128>(sa0);  sa1 = dppadd<0x128>(sa1);

      float4 d4 = Dq[cu], b4 = Bq[cu], k4 = Kq[cu], r4 = Rq[cu];
      float2 vv = Vv[cu];
      // row 0 of pair
      S[0][0] = fmaf(S[0][0], d4.x, fmaf(vv.x, k4.x, sa0 * b4.x));
      float o0 = S[0][0] * r4.x;
      S[0][1] = fmaf(S[0][1], d4.y, fmaf(vv.x, k4.y, sa0 * b4.y));
      o0 = fmaf(S[0][1], r4.y, o0);
      S[0][2] = fmaf(S[0][2], d4.z, fmaf(vv.x, k4.z, sa0 * b4.z));
      o0 = fmaf(S[0][2], r4.z, o0);
      S[0][3] = fmaf(S[0][3], d4.w, fmaf(vv.x, k4.w, sa0 * b4.w));
      o0 = fmaf(S[0][3], r4.w, o0);
      // row 1 of pair
      S[1][0] = fmaf(S[1][0], d4.x, fmaf(vv.y, k4.x, sa1 * b4.x));
      float o1 = S[1][0] * r4.x;
      S[1][1] = fmaf(S[1][1], d4.y, fmaf(vv.y, k4.y, sa1 * b4.y));
      o1 = fmaf(S[1][1], r4.y, o1);
      S[1][2] = fmaf(S[1][2], d4.z, fmaf(vv.y, k4.z, sa1 * b4.z));
      o1 = fmaf(S[1][2], r4.z, o1);
      S[1][3] = fmaf(S[1][3], d4.w, fmaf(vv.y, k4.w, sa1 * b4.w));
      o1 = fmaf(S[1][3], r4.w, o1);

      o0 = dppadd<0xB1>(o0);   o1 = dppadd<0xB1>(o1);
      o0 = dppadd<0x4E>(o0);   o1 = dppadd<0x4E>(o1);
      o0 = dppadd<0x124>(o0);  o1 = dppadd<0x124>(o1);
      o0 = dppadd<0x128>(o0);  o1 = dppadd<0x128>(o1);
      if (cg == 0) {
        float2 ov; ov.x = o0; ov.y = o1;
        *(float2*)(o + base + (size_t)(c * CS + s) * Cc + lrow) = ov;
      }
    }
    #undef LOADOPS
  }
  #undef LOADC
}

// ---------------- K6: head GroupNorm + rk bonus + gate ----------------
__global__ __launch_bounds__(256) void k6_out(
    const float* __restrict__ o, const float* __restrict__ r, const float* __restrict__ k,
    const float* __restrict__ v, const float* __restrict__ rk,
    const float* __restrict__ gnw, const float* __restrict__ gnb,
    const float* __restrict__ g, unsigned short* __restrict__ og) {
  const int row = blockIdx.x, tid = threadIdx.x;
  const int c = tid * 4;
  const size_t base = (size_t)row * Cc + c;
  float o0 = o[base], o1 = o[base + 1], o2 = o[base + 2], o3 = o[base + 3];
  float r0 = r[base], r1 = r[base + 1], r2 = r[base + 2], r3 = r[base + 3];
  float k0 = k[base], k1 = k[base + 1], k2 = k[base + 2], k3 = k[base + 3];
  float s = o0 + o1 + o2 + o3;
  float q = o0 * o0 + o1 * o1 + o2 * o2 + o3 * o3;
  float bs = r0 * k0 * rk[c] + r1 * k1 * rk[c + 1] + r2 * k2 * rk[c + 2] + r3 * k3 * rk[c + 3];
  #pragma unroll
  for (int m = 8; m; m >>= 1) {
    s += __shfl_xor(s, m); q += __shfl_xor(q, m); bs += __shfl_xor(bs, m);
  }
  float mu = s * (1.f / 64.f);
  float var = q * (1.f / 64.f) - mu * mu;
  float rs = rsqrtf(var + 64e-5f);
  float v0 = v[base], v1 = v[base + 1], v2 = v[base + 2], v3 = v[base + 3];
  float z0 = (o0 - mu) * rs * gnw[c] + gnb[c] + bs * v0;
  float z1 = (o1 - mu) * rs * gnw[c + 1] + gnb[c + 1] + bs * v1;
  float z2 = (o2 - mu) * rs * gnw[c + 2] + gnb[c + 2] + bs * v2;
  float z3 = (o3 - mu) * rs * gnw[c + 3] + gnb[c + 3] + bs * v3;
  ushort4 u;
  u.x = f2bf(z0 * g[base]); u.y = f2bf(z1 * g[base + 1]);
  u.z = f2bf(z2 * g[base + 2]); u.w = f2bf(z3 * g[base + 3]);
  *(ushort4*)(og + base) = u;
}

// ---------------- K8: FFN LN + time-shift mix ----------------
__global__ __launch_bounds__(256) void k8_ffnmix(
    const float* __restrict__ x2, const float* __restrict__ lnw, const float* __restrict__ lnb,
    const float* __restrict__ fxk, unsigned short* __restrict__ kf) {
  __shared__ float red[8];
  const int row = blockIdx.x;
  const int t = row & (Tt - 1);
  const int tid = threadIdx.x;
  const int c = tid * 4;
  const size_t base = (size_t)row * Cc + c;
  float a0 = x2[base], a1 = x2[base + 1], a2 = x2[base + 2], a3 = x2[base + 3];
  float mu, rs;
  row_stats(a0, a1, a2, a3, red, mu, rs, 1e-5f);
  float w0 = lnw[c], w1 = lnw[c + 1], w2 = lnw[c + 2], w3 = lnw[c + 3];
  float b0 = lnb[c], b1 = lnb[c + 1], b2 = lnb[c + 2], b3 = lnb[c + 3];
  float f0 = (a0 - mu) * rs * w0 + b0, f1 = (a1 - mu) * rs * w1 + b1;
  float f2 = (a2 - mu) * rs * w2 + b2, f3 = (a3 - mu) * rs * w3 + b3;
  float p0 = 0.f, p1 = 0.f, p2 = 0.f, p3 = 0.f;
  if (t > 0) {
    const size_t pb_ = base - Cc;
    float q0 = x2[pb_], q1 = x2[pb_ + 1], q2 = x2[pb_ + 2], q3 = x2[pb_ + 3];
    row_stats(q0, q1, q2, q3, red, mu, rs, 1e-5f);
    p0 = (q0 - mu) * rs * w0 + b0; p1 = (q1 - mu) * rs * w1 + b1;
    p2 = (q2 - mu) * rs * w2 + b2; p3 = (q3 - mu) * rs * w3 + b3;
  }
  ushort4 u;
  u.x = f2bf(f0 + (p0 - f0) * fxk[c]);
  u.y = f2bf(f1 + (p1 - f1) * fxk[c + 1]);
  u.z = f2bf(f2 + (p2 - f2) * fxk[c + 2]);
  u.w = f2bf(f3 + (p3 - f3) * fxk[c + 3]);
  *(ushort4*)(kf + base) = u;
}

// ---------------- host ----------------
extern "C" void kernel_launch(void* const* d_in, const int* in_sizes, int n_in,
                              void* d_out, int out_size, void* d_ws, size_t ws_size,
                              hipStream_t stream) {
  (void)in_sizes; (void)n_in; (void)out_size; (void)ws_size;
  const float* x    = (const float*)d_in[0];
  const float* lnpw = (const float*)d_in[2];
  const float* lnpb = (const float*)d_in[3];
  const float* lnaw = (const float*)d_in[4];
  const float* lnab = (const float*)d_in[5];
  const float* lnfw = (const float*)d_in[6];
  const float* lnfb = (const float*)d_in[7];
  const float* cxr  = (const float*)d_in[8];
  const float* cxw  = (const float*)d_in[9];
  const float* cxk  = (const float*)d_in[10];
  const float* cxv  = (const float*)d_in[11];
  const float* cxa  = (const float*)d_in[12];
  const float* cxg  = (const float*)d_in[13];
  const float* w0v  = (const float*)d_in[14];
  const float* w1m  = (const float*)d_in[15];
  const float* w2m  = (const float*)d_in[16];
  const float* a0v  = (const float*)d_in[17];
  const float* a1m  = (const float*)d_in[18];
  const float* a2m  = (const float*)d_in[19];
  const float* g1m  = (const float*)d_in[20];
  const float* g2m  = (const float*)d_in[21];
  const float* kkv  = (const float*)d_in[22];
  const float* kav  = (const float*)d_in[23];
  const float* rkv  = (const float*)d_in[24];
  const float* Wr   = (const float*)d_in[25];
  const float* Wk   = (const float*)d_in[26];
  const float* Wv   = (const float*)d_in[27];
  const float* Wo   = (const float*)d_in[28];
  const float* gnw  = (const float*)d_in[29];
  const float* gnb  = (const float*)d_in[30];
  const float* fxk  = (const float*)d_in[31];
  const float* Wf1  = (const float*)d_in[32];
  const float* Wf2  = (const float*)d_in[33];

  char* ws = (char*)d_ws;
  float* outx = (float*)d_out;          // final x (B,T,C)
  float* vout = outx + BTC;             // v_first = v (B,T,C)

  // workspace layout (aliases noted)
  size_t off = 0;
  unsigned short* WrT  = (unsigned short*)(ws + off); off += 2097152;
  unsigned short* WkT  = (unsigned short*)(ws + off); off += 2097152;
  unsigned short* WvT  = (unsigned short*)(ws + off); off += 2097152;
  unsigned short* WoT  = (unsigned short*)(ws + off); off += 2097152;
  unsigned short* Wf1T = (unsigned short*)(ws + off); off += 8388608;
  unsigned short* Wf2T = (unsigned short*)(ws + off); off += 8388608;
  unsigned short* w1T  = (unsigned short*)(ws + off); off += 131072;
  unsigned short* w2T  = (unsigned short*)(ws + off); off += 131072;
  unsigned short* a1T  = (unsigned short*)(ws + off); off += 131072;
  unsigned short* a2T  = (unsigned short*)(ws + off); off += 131072;
  unsigned short* g1T  = (unsigned short*)(ws + off); off += 262144;
  unsigned short* g2T  = (unsigned short*)(ws + off); off += 262144;
  float* xln = (float*)(ws + off); off += 16777216;
  unsigned short* mixR = (unsigned short*)(ws + off);          // 6 x 8388608
  unsigned short* mixW = (unsigned short*)(ws + off + 8388608);
  unsigned short* mixK = (unsigned short*)(ws + off + 16777216);
  unsigned short* mixV = (unsigned short*)(ws + off + 25165824);
  unsigned short* mixA = (unsigned short*)(ws + off + 33554432);
  unsigned short* mixG = (unsigned short*)(ws + off + 41943040);
  unsigned short* hbuf = (unsigned short*)(ws + off);          // alias mix (dead by then)
  off += 50331648;
  unsigned short* tmpw = (unsigned short*)(ws + off); off += 524288;
  unsigned short* tmpa = (unsigned short*)(ws + off); off += 524288;
  unsigned short* tmpg = (unsigned short*)(ws + off); off += 1048576;
  float* decay = (float*)(ws + off);
  unsigned short* og = (unsigned short*)(ws + off);            // alias decay (dead after K5)
  off += 16777216;
  float* aicl = (float*)(ws + off);
  float* obuf = (float*)(ws + off);                            // alias aicl (dead after K4)
  off += 16777216;
  float* gout = (float*)(ws + off); off += 16777216;
  float* rbuf = (float*)(ws + off);
  float* x2   = (float*)(ws + off);                            // alias rbuf (dead after K6)
  off += 16777216;
  float* kbuf = (float*)(ws + off); off += 16777216;
  float* awb  = (float*)(ws + off);
  unsigned short* kf = (unsigned short*)(ws + off);            // alias awb (dead after K5)
  off += 16777216;
  float* bwb  = (float*)(ws + off); off += 16777216;           // total ~187 MB

  dim3 tb(32, 8);
  // weight prep: f32 (K,N) -> bf16 (N,K). 4 squares in one dispatch + 8 generic in one.
  kt_transpose4<<<dim3(32, 32, 4), tb, 0, stream>>>(Wr, Wk, Wv, Wo, WrT, WkT, WvT, WoT);
  TPack tp;
  tp.d[0] = TDesc{Wf1, Wf1T, 1024, 4096, 0,    128};
  tp.d[1] = TDesc{Wf2, Wf2T, 4096, 1024, 4096, 32};
  tp.d[2] = TDesc{w1m, w1T,  1024, 64,   8192, 2};
  tp.d[3] = TDesc{w2m, w2T,  64,   1024, 8256, 32};
  tp.d[4] = TDesc{a1m, a1T,  1024, 64,   8320, 2};
  tp.d[5] = TDesc{a2m, a2T,  64,   1024, 8384, 32};
  tp.d[6] = TDesc{g1m, g1T,  1024, 128,  8448, 4};
  tp.d[7] = TDesc{g2m, g2T,  128,  1024, 8576, 32};
  kt_transpose_multi<<<8704, tb, 0, stream>>>(tp);

  // K1: pre-LN + attn-LN + shift mixes
  k1_mix<<<Mm, 256, 0, stream>>>(x, lnpw, lnpb, lnaw, lnab, cxr, cxw, cxk, cxv, cxa, cxg,
                                 xln, mixR, mixW, mixK, mixV, mixA, mixG);

  // LoRA chains (N-tile = 64)
  kg_gemm<2><<<dim3(1, 32), 256, 0, stream>>>(mixW, w1T, Mm, 64, 1024, nullptr, tmpw, nullptr, nullptr);
  kg_gemm<6><<<dim3(16, 32), 256, 0, stream>>>(tmpw, w2T, Mm, 1024, 64, decay, nullptr, w0v, nullptr);
  kg_gemm<1><<<dim3(1, 32), 256, 0, stream>>>(mixA, a1T, Mm, 64, 1024, nullptr, tmpa, nullptr, nullptr);
  kg_gemm<5><<<dim3(16, 32), 256, 0, stream>>>(tmpa, a2T, Mm, 1024, 64, aicl, nullptr, a0v, nullptr);
  kg_gemm<3><<<dim3(2, 32), 256, 0, stream>>>(mixG, g1T, Mm, 128, 1024, nullptr, tmpg, nullptr, nullptr);
  kg_gemm<0><<<dim3(16, 32), 256, 0, stream>>>(tmpg, g2T, Mm, 1024, 128, gout, nullptr, nullptr, nullptr);

  // r / k / v projections (v straight into d_out as v_first)
  kg_gemm<0><<<dim3(16, 32), 256, 0, stream>>>(mixR, WrT, Mm, 1024, 1024, rbuf, nullptr, nullptr, nullptr);
  kg_gemm<0><<<dim3(16, 32), 256, 0, stream>>>(mixK, WkT, Mm, 1024, 1024, kbuf, nullptr, nullptr, nullptr);
  kg_gemm<0><<<dim3(16, 32), 256, 0, stream>>>(mixV, WvT, Mm, 1024, 1024, vout, nullptr, nullptr, nullptr);

  // recurrence inputs
  k4_prep<<<Mm, 256, 0, stream>>>(kbuf, aicl, kkv, kav, awb, bwb);
  // WKV7 scan — 256 blocks (2 halves x 128 bh) x 4 waves
  k5_wkv7<<<256, 256, 0, stream>>>(rbuf, decay, kbuf, vout, awb, bwb, obuf);
  // GN + bonus + gate
  k6_out<<<Mm, 256, 0, stream>>>(obuf, rbuf, kbuf, vout, rkv, gnw, gnb, gout, og);
  // o-projection + residual -> x2
  kg_gemm<7><<<dim3(16, 32), 256, 0, stream>>>(og, WoT, Mm, 1024, 1024, x2, nullptr, nullptr, xln);
  // FFN
  k8_ffnmix<<<Mm, 256, 0, stream>>>(x2, lnfw, lnfb, fxk, kf);
  kg_gemm2<4><<<dim3(32, 32), 256, 0, stream>>>(kf, Wf1T, Mm, 4096, 1024, nullptr, hbuf, nullptr, nullptr);
  kg_gemm<7><<<dim3(16, 32), 256, 0, stream>>>(hbuf, Wf2T, Mm, 1024, 4096, outx, nullptr, nullptr, x2);
}

// Round 4
// 636.541 us; speedup vs baseline: 1.0955x; 1.0955x over previous
//
#include <hip/hip_runtime.h>

// ---------------- constants ----------------
#define Bb 8
#define Tt 512
#define Cc 1024
#define Hh 16
#define Nh 64
#define Mm 4096            // B*T
#define BTC 4194304        // M*C
#define DEV __device__ __forceinline__

typedef __attribute__((ext_vector_type(8))) short short8;
typedef __attribute__((ext_vector_type(4))) float f32x4;

DEV unsigned short f2bf(float f) {
  unsigned int u = __builtin_bit_cast(unsigned int, f);
  u += 0x7fffu + ((u >> 16) & 1u);
  return (unsigned short)(u >> 16);
}

DEV float bflo(unsigned int u) { return __builtin_bit_cast(float, u << 16); }
DEV float bfhi(unsigned int u) { return __builtin_bit_cast(float, u & 0xFFFF0000u); }

// DPP butterfly add — pure VALU. 0xB1=quad xor1, 0x4E=quad xor2,
// 0x124=row_ror:4, 0x128=row_ror:8 (within 16-lane DPP row).
template <int CTRL>
DEV float dppadd(float x) {
  int xi = __builtin_bit_cast(int, x);
  int yi = __builtin_amdgcn_update_dpp(0, xi, CTRL, 0xF, 0xF, true);
  return x + __builtin_bit_cast(float, yi);
}

// ---------------- merged transpose f32 (K x N) -> bf16 (N x K) ----------------
// all 12 weight-prep jobs in ONE dispatch (R4: was 2 dispatches / was 9 in R2).
struct TDesc { const float* in; unsigned short* out; int K, N, bstart, nbx; };
struct TPack { TDesc d[12]; };

__global__ __launch_bounds__(256) void kt_transpose_multi(TPack p) {
  __shared__ float tile[32][33];
  const int bid = blockIdx.x;
  int i = 0;
  #pragma unroll
  for (int j = 1; j < 12; ++j) if (bid >= p.d[j].bstart) i = j;
  const float* in = p.d[i].in;
  unsigned short* out = p.d[i].out;
  const int K = p.d[i].K, N = p.d[i].N;
  const int local = bid - p.d[i].bstart;
  const int byq = local / p.d[i].nbx;
  const int bx = (local - byq * p.d[i].nbx) * 32;
  const int by = byq * 32;
  int tx = threadIdx.x, ty = threadIdx.y;
  #pragma unroll
  for (int q = ty; q < 32; q += 8) {
    int kk = by + q, nn = bx + tx;
    tile[q][tx] = (kk < K && nn < N) ? in[(size_t)kk * N + nn] : 0.f;
  }
  __syncthreads();
  #pragma unroll
  for (int q = ty; q < 32; q += 8) {
    int nn = bx + q, kk = by + tx;
    if (nn < N && kk < K) out[(size_t)nn * K + kk] = f2bf(tile[tx][q]);
  }
}

// ---------------- block row stats (1024 elems over 256 threads) ----------------
DEV void row_stats(float v0, float v1, float v2, float v3, float* red,
                   float& mu, float& rs, float eps) {
  float s = v0 + v1 + v2 + v3;
  float q = v0 * v0 + v1 * v1 + v2 * v2 + v3 * v3;
  #pragma unroll
  for (int o = 32; o; o >>= 1) { s += __shfl_down(s, o); q += __shfl_down(q, o); }
  int w = threadIdx.x >> 6;
  __syncthreads();
  if ((threadIdx.x & 63) == 0) { red[w] = s; red[4 + w] = q; }
  __syncthreads();
  s = red[0] + red[1] + red[2] + red[3];
  q = red[4] + red[5] + red[6] + red[7];
  mu = s * (1.f / 1024.f);
  float var = q * (1.f / 1024.f) - mu * mu;
  rs = rsqrtf(var + eps);
}

// ---------------- K1: pre-LN + attn-LN + time-shift mixes ----------------
__global__ __launch_bounds__(256) void k1_mix(
    const float* __restrict__ x,
    const float* __restrict__ lnpw, const float* __restrict__ lnpb,
    const float* __restrict__ lnaw, const float* __restrict__ lnab,
    const float* __restrict__ cr, const float* __restrict__ cw,
    const float* __restrict__ ck, const float* __restrict__ cv,
    const float* __restrict__ ca, const float* __restrict__ cg,
    float* __restrict__ xln,
    unsigned short* __restrict__ mR, unsigned short* __restrict__ mW,
    unsigned short* __restrict__ mK, unsigned short* __restrict__ mV,
    unsigned short* __restrict__ mA, unsigned short* __restrict__ mG) {
  __shared__ float red[8];
  const int row = blockIdx.x;
  const int t = row & (Tt - 1);
  const int tid = threadIdx.x;
  const int c = tid * 4;
  const size_t base = (size_t)row * Cc + c;
  float a0 = x[base], a1 = x[base + 1], a2 = x[base + 2], a3 = x[base + 3];
  float mu, rs;
  row_stats(a0, a1, a2, a3, red, mu, rs, 1e-5f);
  float pw0 = lnpw[c], pw1 = lnpw[c + 1], pw2 = lnpw[c + 2], pw3 = lnpw[c + 3];
  float pb0 = lnpb[c], pb1 = lnpb[c + 1], pb2 = lnpb[c + 2], pb3 = lnpb[c + 3];
  float l0 = (a0 - mu) * rs * pw0 + pb0, l1 = (a1 - mu) * rs * pw1 + pb1;
  float l2 = (a2 - mu) * rs * pw2 + pb2, l3 = (a3 - mu) * rs * pw3 + pb3;
  float4 st; st.x = l0; st.y = l1; st.z = l2; st.w = l3;
  *(float4*)(xln + base) = st;
  row_stats(l0, l1, l2, l3, red, mu, rs, 1e-5f);
  float aw0 = lnaw[c], aw1 = lnaw[c + 1], aw2 = lnaw[c + 2], aw3 = lnaw[c + 3];
  float ab0 = lnab[c], ab1 = lnab[c + 1], ab2 = lnab[c + 2], ab3 = lnab[c + 3];
  float n0 = (l0 - mu) * rs * aw0 + ab0, n1 = (l1 - mu) * rs * aw1 + ab1;
  float n2 = (l2 - mu) * rs * aw2 + ab2, n3 = (l3 - mu) * rs * aw3 + ab3;
  float p0 = 0.f, p1 = 0.f, p2 = 0.f, p3 = 0.f;
  if (t > 0) {  // uniform over block
    const size_t pb_ = base - Cc;
    float q0 = x[pb_], q1 = x[pb_ + 1], q2 = x[pb_ + 2], q3 = x[pb_ + 3];
    row_stats(q0, q1, q2, q3, red, mu, rs, 1e-5f);
    float e0 = (q0 - mu) * rs * pw0 + pb0, e1 = (q1 - mu) * rs * pw1 + pb1;
    float e2 = (q2 - mu) * rs * pw2 + pb2, e3 = (q3 - mu) * rs * pw3 + pb3;
    row_stats(e0, e1, e2, e3, red, mu, rs, 1e-5f);
    p0 = (e0 - mu) * rs * aw0 + ab0; p1 = (e1 - mu) * rs * aw1 + ab1;
    p2 = (e2 - mu) * rs * aw2 + ab2; p3 = (e3 - mu) * rs * aw3 + ab3;
  }
  float d0 = p0 - n0, d1 = p1 - n1, d2 = p2 - n2, d3 = p3 - n3;
  #define EMIT(cf, dst) { \
    float f0 = cf[c], f1 = cf[c + 1], f2 = cf[c + 2], f3 = cf[c + 3]; \
    ushort4 u; u.x = f2bf(n0 + d0 * f0); u.y = f2bf(n1 + d1 * f1); \
    u.z = f2bf(n2 + d2 * f2); u.w = f2bf(n3 + d3 * f3); \
    *(ushort4*)(dst + base) = u; }
  EMIT(cr, mR) EMIT(cw, mW) EMIT(ck, mK) EMIT(cv, mV) EMIT(ca, mA) EMIT(cg, mG)
  #undef EMIT
}

// ---------------- bf16 MFMA GEMM (m97-style staging) ----------------
// A: (M,K) bf16 row-major; Bt: (N,K) bf16 row-major.
// MODE: 0 f32 | 1 bf16 | 2 tanh->bf16 | 3 sigmoid->bf16 | 4 relu^2->bf16
//       5 sigmoid(z+bias[col])->f32 | 6 exp(-sigmoid(z+bias[col])*e^-.5)->f32 | 7 z+res->f32
DEV void gll16(const unsigned short* g, unsigned short* l) {
  __builtin_amdgcn_global_load_lds(
      (const __attribute__((address_space(1))) void*)g,
      (__attribute__((address_space(3))) void*)l, 16, 0, 0);
}

template <int MODE>
DEV void gemm_epi(float z, size_t oi, int col,
                  float* outF, unsigned short* outB,
                  const float* bias, const float* res) {
  if constexpr (MODE == 0) outF[oi] = z;
  else if constexpr (MODE == 1) outB[oi] = f2bf(z);
  else if constexpr (MODE == 2) outB[oi] = f2bf(tanhf(z));
  else if constexpr (MODE == 3) outB[oi] = f2bf(1.f / (1.f + expf(-z)));
  else if constexpr (MODE == 4) { float m = fmaxf(z, 0.f); outB[oi] = f2bf(m * m); }
  else if constexpr (MODE == 5) { z += bias[col]; outF[oi] = 1.f / (1.f + expf(-z)); }
  else if constexpr (MODE == 6) {
    z += bias[col];
    float sg = 1.f / (1.f + expf(-z));
    outF[oi] = expf(-0.6065306597126334f * sg);
  } else { outF[oi] = z + res[oi]; }
}

// 128M x 64N tile body (shared by kg_gemm and kg_gemm_qkv)
template <int MODE>
DEV void gemm_body(const unsigned short* A, const unsigned short* Bt,
                   int Nn, int K,
                   float* outF, unsigned short* outB,
                   const float* bias, const float* res,
                   unsigned short* lsA, unsigned short* lsB,
                   int m0, int n0) {
  const int tid = threadIdx.x;
  const int lane = tid & 63;
  const int wave = tid >> 6;
  const int wy = wave >> 1, wx = wave & 1;
  const int sl4 = lane >> 2;        // row within 16-row group
  const int sc = (lane & 3) << 3;   // k-elem offset {0,8,16,24}
  f32x4 acc[4][2];
  #pragma unroll
  for (int i = 0; i < 4; ++i)
    #pragma unroll
    for (int j = 0; j < 2; ++j) { f32x4 z = {0.f, 0.f, 0.f, 0.f}; acc[i][j] = z; }
  const int fr = lane & 15;
  const int fk = (lane >> 4) << 3;
  for (int k0 = 0; k0 < K; k0 += 32) {
    #pragma unroll
    for (int j = 0; j < 2; ++j) {        // A: 8 groups of 16 rows, wave does 2
      const int rb = (wave + j * 4) * 16;
      gll16(A + (size_t)(m0 + rb + sl4) * K + k0 + sc, lsA + rb * 32);
    }
    {                                    // B: 4 groups, wave does 1
      const int rb = wave * 16;
      int br = n0 + rb + sl4;
      br = br < Nn ? br : Nn - 1;
      gll16(Bt + (size_t)br * K + k0 + sc, lsB + rb * 32);
    }
    __syncthreads();
    short8 af[4], bf[2];
    #pragma unroll
    for (int mt = 0; mt < 4; ++mt)
      af[mt] = *(const short8*)(lsA + (wy * 64 + mt * 16 + fr) * 32 + fk);
    #pragma unroll
    for (int nt = 0; nt < 2; ++nt)
      bf[nt] = *(const short8*)(lsB + (wx * 32 + nt * 16 + fr) * 32 + fk);
    #pragma unroll
    for (int mt = 0; mt < 4; ++mt)
      #pragma unroll
      for (int nt = 0; nt < 2; ++nt)
        acc[mt][nt] = __builtin_amdgcn_mfma_f32_16x16x32_bf16(af[mt], bf[nt], acc[mt][nt], 0, 0, 0);
    __syncthreads();
  }
  const int rbase = (lane >> 4) << 2;
  const int cbase = lane & 15;
  #pragma unroll
  for (int mt = 0; mt < 4; ++mt)
    #pragma unroll
    for (int nt = 0; nt < 2; ++nt)
      #pragma unroll
      for (int rr = 0; rr < 4; ++rr) {
        int row = m0 + wy * 64 + mt * 16 + rbase + rr;
        int col = n0 + wx * 32 + nt * 16 + cbase;
        if (col < Nn)
          gemm_epi<MODE>(acc[mt][nt][rr], (size_t)row * Nn + col, col, outF, outB, bias, res);
      }
}

template <int MODE>
__global__ __launch_bounds__(256) void kg_gemm(
    const unsigned short* __restrict__ A, const unsigned short* __restrict__ Bt,
    int M, int Nn, int K,
    float* __restrict__ outF, unsigned short* __restrict__ outB,
    const float* __restrict__ bias, const float* __restrict__ res) {
  __shared__ unsigned short lsA[128 * 32];
  __shared__ unsigned short lsB[64 * 32];
  gemm_body<MODE>(A, Bt, Nn, K, outF, outB, bias, res, lsA, lsB,
                  blockIdx.y * 128, blockIdx.x * 64);
}

// r/k/v projections batched in one dispatch (z selects). M=4096,N=1024,K=1024.
__global__ __launch_bounds__(256) void kg_gemm_qkv(
    const unsigned short* __restrict__ A0, const unsigned short* __restrict__ A1,
    const unsigned short* __restrict__ A2,
    const unsigned short* __restrict__ B0, const unsigned short* __restrict__ B1,
    const unsigned short* __restrict__ B2,
    float* __restrict__ O0, float* __restrict__ O1, float* __restrict__ O2) {
  __shared__ unsigned short lsA[128 * 32];
  __shared__ unsigned short lsB[64 * 32];
  const int z = blockIdx.z;
  const unsigned short* A = z == 0 ? A0 : z == 1 ? A1 : A2;
  const unsigned short* Bt = z == 0 ? B0 : z == 1 ? B1 : B2;
  float* outF = z == 0 ? O0 : z == 1 ? O1 : O2;
  gemm_body<0>(A, Bt, 1024, 1024, outF, nullptr, nullptr, nullptr, lsA, lsB,
               blockIdx.y * 128, blockIdx.x * 64);
}

// 128M x 128N tile (exact m97 structure) — for large-N GEMMs (FFN1: 1024 blocks).
template <int MODE>
__global__ __launch_bounds__(256) void kg_gemm2(
    const unsigned short* __restrict__ A, const unsigned short* __restrict__ Bt,
    int M, int Nn, int K,
    float* __restrict__ outF, unsigned short* __restrict__ outB,
    const float* __restrict__ bias, const float* __restrict__ res) {
  __shared__ unsigned short lsA[128 * 32];
  __shared__ unsigned short lsB[128 * 32];
  const int tid = threadIdx.x;
  const int lane = tid & 63;
  const int wave = tid >> 6;
  const int wy = wave >> 1, wx = wave & 1;
  const int m0 = blockIdx.y * 128;
  const int n0 = blockIdx.x * 128;
  const int sl4 = lane >> 2;
  const int sc = (lane & 3) << 3;
  f32x4 acc[4][4];
  #pragma unroll
  for (int i = 0; i < 4; ++i)
    #pragma unroll
    for (int j = 0; j < 4; ++j) { f32x4 z = {0.f, 0.f, 0.f, 0.f}; acc[i][j] = z; }
  const int fr = lane & 15;
  const int fk = (lane >> 4) << 3;
  for (int k0 = 0; k0 < K; k0 += 32) {
    #pragma unroll
    for (int j = 0; j < 2; ++j) {        // A and B: 8 groups of 16 rows each, wave does 2+2
      const int rb = (wave + j * 4) * 16;
      gll16(A + (size_t)(m0 + rb + sl4) * K + k0 + sc, lsA + rb * 32);
      int br = n0 + rb + sl4;
      br = br < Nn ? br : Nn - 1;
      gll16(Bt + (size_t)br * K + k0 + sc, lsB + rb * 32);
    }
    __syncthreads();
    short8 af[4], bf[4];
    #pragma unroll
    for (int mt = 0; mt < 4; ++mt)
      af[mt] = *(const short8*)(lsA + (wy * 64 + mt * 16 + fr) * 32 + fk);
    #pragma unroll
    for (int nt = 0; nt < 4; ++nt)
      bf[nt] = *(const short8*)(lsB + (wx * 64 + nt * 16 + fr) * 32 + fk);
    #pragma unroll
    for (int mt = 0; mt < 4; ++mt)
      #pragma unroll
      for (int nt = 0; nt < 4; ++nt)
        acc[mt][nt] = __builtin_amdgcn_mfma_f32_16x16x32_bf16(af[mt], bf[nt], acc[mt][nt], 0, 0, 0);
    __syncthreads();
  }
  const int rbase = (lane >> 4) << 2;
  const int cbase = lane & 15;
  #pragma unroll
  for (int mt = 0; mt < 4; ++mt)
    #pragma unroll
    for (int nt = 0; nt < 4; ++nt)
      #pragma unroll
      for (int rr = 0; rr < 4; ++rr) {
        int row = m0 + wy * 64 + mt * 16 + rbase + rr;
        int col = n0 + wx * 64 + nt * 16 + cbase;
        if (col < Nn)
          gemm_epi<MODE>(acc[mt][nt][rr], (size_t)row * Nn + col, col, outF, outB, bias, res);
      }
}

// ---------------- K4: kk-normalize, a/b vectors, k update + bf16 packs ----------------
// R4: emits awh/bwh/kh as bf16 for k5 (halves those LDS bytes); keeps f32 k
// in place for k6. decay/v/r stay f32 (decay errors compound over 512 steps;
// r scales the output directly).
__global__ __launch_bounds__(256) void k4_prep(
    float* __restrict__ k, const float* __restrict__ a,
    const float* __restrict__ kkc, const float* __restrict__ kac,
    unsigned short* __restrict__ awh, unsigned short* __restrict__ bwh,
    unsigned short* __restrict__ kh) {
  const int row = blockIdx.x, tid = threadIdx.x;
  const int c = tid * 4;
  const size_t base = (size_t)row * Cc + c;
  float k0 = k[base], k1 = k[base + 1], k2 = k[base + 2], k3 = k[base + 3];
  float a0 = a[base], a1 = a[base + 1], a2 = a[base + 2], a3 = a[base + 3];
  float h0 = k0 * kkc[c], h1 = k1 * kkc[c + 1], h2 = k2 * kkc[c + 2], h3 = k3 * kkc[c + 3];
  float ss = h0 * h0 + h1 * h1 + h2 * h2 + h3 * h3;
  #pragma unroll
  for (int m = 8; m; m >>= 1) ss += __shfl_xor(ss, m);
  float inv = 1.f / fmaxf(sqrtf(ss), 1e-12f);
  h0 *= inv; h1 *= inv; h2 *= inv; h3 *= inv;
  ushort4 u;
  u.x = f2bf(-h0); u.y = f2bf(-h1); u.z = f2bf(-h2); u.w = f2bf(-h3);
  *(ushort4*)(awh + base) = u;
  u.x = f2bf(h0 * a0); u.y = f2bf(h1 * a1); u.z = f2bf(h2 * a2); u.w = f2bf(h3 * a3);
  *(ushort4*)(bwh + base) = u;
  float n0 = k0 * (1.f + (a0 - 1.f) * kac[c]);
  float n1 = k1 * (1.f + (a1 - 1.f) * kac[c + 1]);
  float n2 = k2 * (1.f + (a2 - 1.f) * kac[c + 2]);
  float n3 = k3 * (1.f + (a3 - 1.f) * kac[c + 3]);
  u.x = f2bf(n0); u.y = f2bf(n1); u.z = f2bf(n2); u.w = f2bf(n3);
  *(ushort4*)(kh + base) = u;
  float4 v4; v4.x = n0; v4.y = n1; v4.z = n2; v4.w = n3;
  *(float4*)(k + base) = v4;
}

// ---------------- K5: WKV7 — R2 geometry + bf16 a/b/k operands ----------------
// R2-proven: 256 blocks (half x bh) x 512 thr, 8 waves x 4 rows, lane =
// (rw = lane>>4, cg = lane&15), S[4], 4-stage DPP 16-lane reduce, CS=8,
// LDS double-buffer, one barrier/chunk. That measured 538cy/step ==
// LDS-byte wall (8 waves x ~5.2KB/step). R4 cuts bytes: a,b,k staged bf16
// -> per wave 2xb128(d... r) + b32(v) + 3xb64 ~ 54cy vs 66 -> ~430cy/step.
#define CS 8
__global__ __launch_bounds__(512, 2) void k5_wkv7(
    const float* __restrict__ r, const float* __restrict__ dec,
    const float* __restrict__ v,
    const unsigned short* __restrict__ awh, const unsigned short* __restrict__ bwh,
    const unsigned short* __restrict__ kh,
    float* __restrict__ o) {
  const int blk = blockIdx.x;              // 0..255
  const int bh = blk & 127, half = blk >> 7;
  const int b = bh >> 4, h = bh & 15;
  const int tid = threadIdx.x;
  const int lane = tid & 63;
  const int w = tid >> 6;                  // wave 0..7
  const int cg = lane & 15;                // column group (4 cols)
  const int rw = lane >> 4;                // row within wave's 4
  const int row = half * 32 + w * 4 + rw;  // state row i (0..63)
  const int cb = cg << 2;                  // column base j0

  // chunk layout (floats): [d 512][v 512][r 512][bf16 a|b|k 3x512 ushorts = 768]
  __shared__ float buf[2][2304];           // 2 x 9 KB

  float S[4];
  #pragma unroll
  for (int j = 0; j < 4; ++j) S[j] = 0.f;

  const size_t base = (size_t)b * Tt * Cc + (size_t)h * Nh;

  const int srow = lane >> 4, scol = (lane & 15) << 2;  // f32 staging (t, col)
  const int hrow = lane >> 3, hcol = (lane & 7) << 3;   // bf16 staging (t, col)

  uint4 R0, R1;
  #define LOADC(cstart) { \
    if (w < 3) { \
      const float* sp = w == 0 ? dec : w == 1 ? v : r; \
      const size_t g0 = base + (size_t)((cstart) + srow) * Cc + scol; \
      R0 = *(const uint4*)(sp + g0); \
      R1 = *(const uint4*)(sp + g0 + 4 * Cc); \
    } else if (w < 6) { \
      const unsigned short* sp = w == 3 ? awh : w == 4 ? bwh : kh; \
      const size_t g0 = base + (size_t)((cstart) + hrow) * Cc + hcol; \
      R0 = *(const uint4*)(sp + g0); \
    } }

  LOADC(0)

  #pragma unroll 1
  for (int c = 0; c < Tt / CS; ++c) {
    float* bp = buf[c & 1];
    if (w < 3) {
      *(uint4*)(bp + w * 512 + (lane << 2)) = R0;
      *(uint4*)(bp + w * 512 + 256 + (lane << 2)) = R1;
    } else if (w < 6) {
      unsigned short* hb = (unsigned short*)(bp + 1536);
      *(uint4*)(hb + (w - 3) * 512 + lane * 8) = R0;
    }
    const int cn = (c + 1 < Tt / CS) ? (c + 1) : c;
    LOADC(cn * CS)
    __syncthreads();

    // operand register double-buffer (one step each)
    float4 Dq[2], Rq[2];
    uint2 Ah[2], Bh[2], Kh[2];
    float Vv[2];
    #define LOADOPS(slot, ss) { \
      const float* sp_ = bp + (ss) * 64; \
      Dq[slot] = *(const float4*)(sp_ + cb); \
      Vv[slot] = sp_[512 + row]; \
      Rq[slot] = *(const float4*)(sp_ + 1024 + cb); \
      const unsigned short* hb_ = (const unsigned short*)(bp + 1536) + (ss) * 64 + cb; \
      Ah[slot] = *(const uint2*)(hb_); \
      Bh[slot] = *(const uint2*)(hb_ + 512); \
      Kh[slot] = *(const uint2*)(hb_ + 1024); }

    LOADOPS(0, 0)
    #pragma unroll
    for (int s = 0; s < CS; ++s) {
      const int cu = s & 1, nx = cu ^ 1;
      if (s + 1 < CS) LOADOPS(nx, s + 1)     // prefetch next step's operands

      float ax = bflo(Ah[cu].x), ay = bfhi(Ah[cu].x);
      float az = bflo(Ah[cu].y), aw_ = bfhi(Ah[cu].y);
      float sa = fmaf(S[1], ay, S[0] * ax) + fmaf(S[3], aw_, S[2] * az);
      sa = dppadd<0xB1>(sa);
      sa = dppadd<0x4E>(sa);
      sa = dppadd<0x124>(sa);
      sa = dppadd<0x128>(sa);

      float bx = bflo(Bh[cu].x), by = bfhi(Bh[cu].x);
      float bz = bflo(Bh[cu].y), bw_ = bfhi(Bh[cu].y);
      float kx = bflo(Kh[cu].x), ky = bfhi(Kh[cu].x);
      float kz = bflo(Kh[cu].y), kw_ = bfhi(Kh[cu].y);
      const float vv = Vv[cu];
      float4 d4 = Dq[cu], r4 = Rq[cu];
      S[0] = fmaf(S[0], d4.x, fmaf(vv, kx, sa * bx));
      float oo = S[0] * r4.x;
      S[1] = fmaf(S[1], d4.y, fmaf(vv, ky, sa * by));
      oo = fmaf(S[1], r4.y, oo);
      S[2] = fmaf(S[2], d4.z, fmaf(vv, kz, sa * bz));
      oo = fmaf(S[2], r4.z, oo);
      S[3] = fmaf(S[3], d4.w, fmaf(vv, kw_, sa * bw_));
      oo = fmaf(S[3], r4.w, oo);

      oo = dppadd<0xB1>(oo);
      oo = dppadd<0x4E>(oo);
      oo = dppadd<0x124>(oo);
      oo = dppadd<0x128>(oo);
      if (cg == 0) o[base + (size_t)(c * CS + s) * Cc + row] = oo;
    }
    #undef LOADOPS
  }
  #undef LOADC
}

// ---------------- K6: head GroupNorm + rk bonus + gate ----------------
__global__ __launch_bounds__(256) void k6_out(
    const float* __restrict__ o, const float* __restrict__ r, const float* __restrict__ k,
    const float* __restrict__ v, const float* __restrict__ rk,
    const float* __restrict__ gnw, const float* __restrict__ gnb,
    const float* __restrict__ g, unsigned short* __restrict__ og) {
  const int row = blockIdx.x, tid = threadIdx.x;
  const int c = tid * 4;
  const size_t base = (size_t)row * Cc + c;
  float o0 = o[base], o1 = o[base + 1], o2 = o[base + 2], o3 = o[base + 3];
  float r0 = r[base], r1 = r[base + 1], r2 = r[base + 2], r3 = r[base + 3];
  float k0 = k[base], k1 = k[base + 1], k2 = k[base + 2], k3 = k[base + 3];
  float s = o0 + o1 + o2 + o3;
  float q = o0 * o0 + o1 * o1 + o2 * o2 + o3 * o3;
  float bs = r0 * k0 * rk[c] + r1 * k1 * rk[c + 1] + r2 * k2 * rk[c + 2] + r3 * k3 * rk[c + 3];
  #pragma unroll
  for (int m = 8; m; m >>= 1) {
    s += __shfl_xor(s, m); q += __shfl_xor(q, m); bs += __shfl_xor(bs, m);
  }
  float mu = s * (1.f / 64.f);
  float var = q * (1.f / 64.f) - mu * mu;
  float rs = rsqrtf(var + 64e-5f);
  float v0 = v[base], v1 = v[base + 1], v2 = v[base + 2], v3 = v[base + 3];
  float z0 = (o0 - mu) * rs * gnw[c] + gnb[c] + bs * v0;
  float z1 = (o1 - mu) * rs * gnw[c + 1] + gnb[c + 1] + bs * v1;
  float z2 = (o2 - mu) * rs * gnw[c + 2] + gnb[c + 2] + bs * v2;
  float z3 = (o3 - mu) * rs * gnw[c + 3] + gnb[c + 3] + bs * v3;
  ushort4 u;
  u.x = f2bf(z0 * g[base]); u.y = f2bf(z1 * g[base + 1]);
  u.z = f2bf(z2 * g[base + 2]); u.w = f2bf(z3 * g[base + 3]);
  *(ushort4*)(og + base) = u;
}

// ---------------- K8: FFN LN + time-shift mix ----------------
__global__ __launch_bounds__(256) void k8_ffnmix(
    const float* __restrict__ x2, const float* __restrict__ lnw, const float* __restrict__ lnb,
    const float* __restrict__ fxk, unsigned short* __restrict__ kf) {
  __shared__ float red[8];
  const int row = blockIdx.x;
  const int t = row & (Tt - 1);
  const int tid = threadIdx.x;
  const int c = tid * 4;
  const size_t base = (size_t)row * Cc + c;
  float a0 = x2[base], a1 = x2[base + 1], a2 = x2[base + 2], a3 = x2[base + 3];
  float mu, rs;
  row_stats(a0, a1, a2, a3, red, mu, rs, 1e-5f);
  float w0 = lnw[c], w1 = lnw[c + 1], w2 = lnw[c + 2], w3 = lnw[c + 3];
  float b0 = lnb[c], b1 = lnb[c + 1], b2 = lnb[c + 2], b3 = lnb[c + 3];
  float f0 = (a0 - mu) * rs * w0 + b0, f1 = (a1 - mu) * rs * w1 + b1;
  float f2 = (a2 - mu) * rs * w2 + b2, f3 = (a3 - mu) * rs * w3 + b3;
  float p0 = 0.f, p1 = 0.f, p2 = 0.f, p3 = 0.f;
  if (t > 0) {
    const size_t pb_ = base - Cc;
    float q0 = x2[pb_], q1 = x2[pb_ + 1], q2 = x2[pb_ + 2], q3 = x2[pb_ + 3];
    row_stats(q0, q1, q2, q3, red, mu, rs, 1e-5f);
    p0 = (q0 - mu) * rs * w0 + b0; p1 = (q1 - mu) * rs * w1 + b1;
    p2 = (q2 - mu) * rs * w2 + b2; p3 = (q3 - mu) * rs * w3 + b3;
  }
  ushort4 u;
  u.x = f2bf(f0 + (p0 - f0) * fxk[c]);
  u.y = f2bf(f1 + (p1 - f1) * fxk[c + 1]);
  u.z = f2bf(f2 + (p2 - f2) * fxk[c + 2]);
  u.w = f2bf(f3 + (p3 - f3) * fxk[c + 3]);
  *(ushort4*)(kf + base) = u;
}

// ---------------- host ----------------
extern "C" void kernel_launch(void* const* d_in, const int* in_sizes, int n_in,
                              void* d_out, int out_size, void* d_ws, size_t ws_size,
                              hipStream_t stream) {
  (void)in_sizes; (void)n_in; (void)out_size; (void)ws_size;
  const float* x    = (const float*)d_in[0];
  const float* lnpw = (const float*)d_in[2];
  const float* lnpb = (const float*)d_in[3];
  const float* lnaw = (const float*)d_in[4];
  const float* lnab = (const float*)d_in[5];
  const float* lnfw = (const float*)d_in[6];
  const float* lnfb = (const float*)d_in[7];
  const float* cxr  = (const float*)d_in[8];
  const float* cxw  = (const float*)d_in[9];
  const float* cxk  = (const float*)d_in[10];
  const float* cxv  = (const float*)d_in[11];
  const float* cxa  = (const float*)d_in[12];
  const float* cxg  = (const float*)d_in[13];
  const float* w0v  = (const float*)d_in[14];
  const float* w1m  = (const float*)d_in[15];
  const float* w2m  = (const float*)d_in[16];
  const float* a0v  = (const float*)d_in[17];
  const float* a1m  = (const float*)d_in[18];
  const float* a2m  = (const float*)d_in[19];
  const float* g1m  = (const float*)d_in[20];
  const float* g2m  = (const float*)d_in[21];
  const float* kkv  = (const float*)d_in[22];
  const float* kav  = (const float*)d_in[23];
  const float* rkv  = (const float*)d_in[24];
  const float* Wr   = (const float*)d_in[25];
  const float* Wk   = (const float*)d_in[26];
  const float* Wv   = (const float*)d_in[27];
  const float* Wo   = (const float*)d_in[28];
  const float* gnw  = (const float*)d_in[29];
  const float* gnb  = (const float*)d_in[30];
  const float* fxk  = (const float*)d_in[31];
  const float* Wf1  = (const float*)d_in[32];
  const float* Wf2  = (const float*)d_in[33];

  char* ws = (char*)d_ws;
  float* outx = (float*)d_out;          // final x (B,T,C)
  float* vout = outx + BTC;             // v_first = v (B,T,C)

  // workspace layout (aliases noted)
  size_t off = 0;
  unsigned short* WrT  = (unsigned short*)(ws + off); off += 2097152;
  unsigned short* WkT  = (unsigned short*)(ws + off); off += 2097152;
  unsigned short* WvT  = (unsigned short*)(ws + off); off += 2097152;
  unsigned short* WoT  = (unsigned short*)(ws + off); off += 2097152;
  unsigned short* Wf1T = (unsigned short*)(ws + off); off += 8388608;
  unsigned short* Wf2T = (unsigned short*)(ws + off); off += 8388608;
  unsigned short* w1T  = (unsigned short*)(ws + off); off += 131072;
  unsigned short* w2T  = (unsigned short*)(ws + off); off += 131072;
  unsigned short* a1T  = (unsigned short*)(ws + off); off += 131072;
  unsigned short* a2T  = (unsigned short*)(ws + off); off += 131072;
  unsigned short* g1T  = (unsigned short*)(ws + off); off += 262144;
  unsigned short* g2T  = (unsigned short*)(ws + off); off += 262144;
  float* xln = (float*)(ws + off); off += 16777216;
  unsigned short* mixR = (unsigned short*)(ws + off);          // 6 x 8388608
  unsigned short* mixW = (unsigned short*)(ws + off + 8388608);
  unsigned short* mixK = (unsigned short*)(ws + off + 16777216);
  unsigned short* mixV = (unsigned short*)(ws + off + 25165824);
  unsigned short* mixA = (unsigned short*)(ws + off + 33554432);
  unsigned short* mixG = (unsigned short*)(ws + off + 41943040);
  unsigned short* hbuf = (unsigned short*)(ws + off);          // alias mix (dead by then)
  off += 50331648;
  unsigned short* tmpw = (unsigned short*)(ws + off); off += 524288;
  unsigned short* tmpa = (unsigned short*)(ws + off); off += 524288;
  unsigned short* tmpg = (unsigned short*)(ws + off); off += 1048576;
  float* decay = (float*)(ws + off);
  unsigned short* og = (unsigned short*)(ws + off);            // alias decay (dead after K5)
  off += 16777216;
  float* aicl = (float*)(ws + off);
  float* obuf = (float*)(ws + off);                            // alias aicl (dead after K4)
  off += 16777216;
  float* gout = (float*)(ws + off); off += 16777216;
  float* rbuf = (float*)(ws + off);
  float* x2   = (float*)(ws + off);                            // alias rbuf (dead after K6)
  off += 16777216;
  float* kbuf = (float*)(ws + off); off += 16777216;
  unsigned short* awh = (unsigned short*)(ws + off);           // bf16 -kk     (8MB)
  unsigned short* kf  = (unsigned short*)(ws + off);           // alias awh (dead after K5)
  unsigned short* bwh = awh + BTC;                             // bf16 kk*a    (8MB)
  off += 16777216;
  unsigned short* khb = (unsigned short*)(ws + off);           // bf16 k       (8MB)
  off += 16777216;                                             // total ~187 MB

  dim3 tb(32, 8);
  // weight prep: f32 (K,N) -> bf16 (N,K) — ALL 12 jobs in one dispatch
  TPack tp;
  tp.d[0]  = TDesc{Wr,  WrT,  1024, 1024, 0,     32};
  tp.d[1]  = TDesc{Wk,  WkT,  1024, 1024, 1024,  32};
  tp.d[2]  = TDesc{Wv,  WvT,  1024, 1024, 2048,  32};
  tp.d[3]  = TDesc{Wo,  WoT,  1024, 1024, 3072,  32};
  tp.d[4]  = TDesc{Wf1, Wf1T, 1024, 4096, 4096,  128};
  tp.d[5]  = TDesc{Wf2, Wf2T, 4096, 1024, 8192,  32};
  tp.d[6]  = TDesc{w1m, w1T,  1024, 64,   12288, 2};
  tp.d[7]  = TDesc{w2m, w2T,  64,   1024, 12352, 32};
  tp.d[8]  = TDesc{a1m, a1T,  1024, 64,   12416, 2};
  tp.d[9]  = TDesc{a2m, a2T,  64,   1024, 12480, 32};
  tp.d[10] = TDesc{g1m, g1T,  1024, 128,  12544, 4};
  tp.d[11] = TDesc{g2m, g2T,  128,  1024, 12672, 32};
  kt_transpose_multi<<<12800, tb, 0, stream>>>(tp);

  // K1: pre-LN + attn-LN + shift mixes
  k1_mix<<<Mm, 256, 0, stream>>>(x, lnpw, lnpb, lnaw, lnab, cxr, cxw, cxk, cxv, cxa, cxg,
                                 xln, mixR, mixW, mixK, mixV, mixA, mixG);

  // LoRA chains (N-tile = 64)
  kg_gemm<2><<<dim3(1, 32), 256, 0, stream>>>(mixW, w1T, Mm, 64, 1024, nullptr, tmpw, nullptr, nullptr);
  kg_gemm<6><<<dim3(16, 32), 256, 0, stream>>>(tmpw, w2T, Mm, 1024, 64, decay, nullptr, w0v, nullptr);
  kg_gemm<1><<<dim3(1, 32), 256, 0, stream>>>(mixA, a1T, Mm, 64, 1024, nullptr, tmpa, nullptr, nullptr);
  kg_gemm<5><<<dim3(16, 32), 256, 0, stream>>>(tmpa, a2T, Mm, 1024, 64, aicl, nullptr, a0v, nullptr);
  kg_gemm<3><<<dim3(2, 32), 256, 0, stream>>>(mixG, g1T, Mm, 128, 1024, nullptr, tmpg, nullptr, nullptr);
  kg_gemm<0><<<dim3(16, 32), 256, 0, stream>>>(tmpg, g2T, Mm, 1024, 128, gout, nullptr, nullptr, nullptr);

  // r / k / v projections — one z=3 dispatch (v straight into d_out as v_first)
  kg_gemm_qkv<<<dim3(16, 32, 3), 256, 0, stream>>>(mixR, mixK, mixV, WrT, WkT, WvT,
                                                   rbuf, kbuf, vout);

  // recurrence inputs (+ bf16 packs for k5)
  k4_prep<<<Mm, 256, 0, stream>>>(kbuf, aicl, kkv, kav, awh, bwh, khb);
  // WKV7 scan — 256 blocks (2 halves x 128 bh) x 8 waves
  k5_wkv7<<<256, 512, 0, stream>>>(rbuf, decay, vout, awh, bwh, khb, obuf);
  // GN + bonus + gate
  k6_out<<<Mm, 256, 0, stream>>>(obuf, rbuf, kbuf, vout, rkv, gnw, gnb, gout, og);
  // o-projection + residual -> x2
  kg_gemm<7><<<dim3(16, 32), 256, 0, stream>>>(og, WoT, Mm, 1024, 1024, x2, nullptr, nullptr, xln);
  // FFN
  k8_ffnmix<<<Mm, 256, 0, stream>>>(x2, lnfw, lnfb, fxk, kf);
  kg_gemm2<4><<<dim3(32, 32), 256, 0, stream>>>(kf, Wf1T, Mm, 4096, 1024, nullptr, hbuf, nullptr, nullptr);
  kg_gemm<7><<<dim3(16, 32), 256, 0, stream>>>(hbuf, Wf2T, Mm, 1024, 4096, outx, nullptr, nullptr, x2);
}

// Round 5
// 619.324 us; speedup vs baseline: 1.1259x; 1.0278x over previous
//
#include <hip/hip_runtime.h>

// ---------------- constants ----------------
#define Bb 8
#define Tt 512
#define Cc 1024
#define Hh 16
#define Nh 64
#define Mm 4096            // B*T
#define BTC 4194304        // M*C
#define DEV __device__ __forceinline__

typedef __attribute__((ext_vector_type(8))) short short8;
typedef __attribute__((ext_vector_type(4))) float f32x4;

DEV unsigned short f2bf(float f) {
  unsigned int u = __builtin_bit_cast(unsigned int, f);
  u += 0x7fffu + ((u >> 16) & 1u);
  return (unsigned short)(u >> 16);
}

// DPP butterfly add — pure VALU. 0xB1=quad xor1, 0x4E=quad xor2,
// 0x124=row_ror:4, 0x128=row_ror:8 (within 16-lane DPP row).
template <int CTRL>
DEV float dppadd(float x) {
  int xi = __builtin_bit_cast(int, x);
  int yi = __builtin_amdgcn_update_dpp(0, xi, CTRL, 0xF, 0xF, true);
  return x + __builtin_bit_cast(float, yi);
}

// ---------------- merged transpose f32 (K x N) -> bf16 (N x K) ----------------
struct TDesc { const float* in; unsigned short* out; int K, N, bstart, nbx; };
struct TPack { TDesc d[12]; };

__global__ __launch_bounds__(256) void kt_transpose_multi(TPack p) {
  __shared__ float tile[32][33];
  const int bid = blockIdx.x;
  int i = 0;
  #pragma unroll
  for (int j = 1; j < 12; ++j) if (bid >= p.d[j].bstart) i = j;
  const float* in = p.d[i].in;
  unsigned short* out = p.d[i].out;
  const int K = p.d[i].K, N = p.d[i].N;
  const int local = bid - p.d[i].bstart;
  const int byq = local / p.d[i].nbx;
  const int bx = (local - byq * p.d[i].nbx) * 32;
  const int by = byq * 32;
  int tx = threadIdx.x, ty = threadIdx.y;
  #pragma unroll
  for (int q = ty; q < 32; q += 8) {
    int kk = by + q, nn = bx + tx;
    tile[q][tx] = (kk < K && nn < N) ? in[(size_t)kk * N + nn] : 0.f;
  }
  __syncthreads();
  #pragma unroll
  for (int q = ty; q < 32; q += 8) {
    int nn = bx + q, kk = by + tx;
    if (nn < N && kk < K) out[(size_t)nn * K + kk] = f2bf(tile[tx][q]);
  }
}

// ---------------- block row stats (1024 elems over 256 threads) ----------------
DEV void row_stats(float v0, float v1, float v2, float v3, float* red,
                   float& mu, float& rs, float eps) {
  float s = v0 + v1 + v2 + v3;
  float q = v0 * v0 + v1 * v1 + v2 * v2 + v3 * v3;
  #pragma unroll
  for (int o = 32; o; o >>= 1) { s += __shfl_down(s, o); q += __shfl_down(q, o); }
  int w = threadIdx.x >> 6;
  __syncthreads();
  if ((threadIdx.x & 63) == 0) { red[w] = s; red[4 + w] = q; }
  __syncthreads();
  s = red[0] + red[1] + red[2] + red[3];
  q = red[4] + red[5] + red[6] + red[7];
  mu = s * (1.f / 1024.f);
  float var = q * (1.f / 1024.f) - mu * mu;
  rs = rsqrtf(var + eps);
}

// ---------------- K1: pre-LN + attn-LN + time-shift mixes ----------------
__global__ __launch_bounds__(256) void k1_mix(
    const float* __restrict__ x,
    const float* __restrict__ lnpw, const float* __restrict__ lnpb,
    const float* __restrict__ lnaw, const float* __restrict__ lnab,
    const float* __restrict__ cr, const float* __restrict__ cw,
    const float* __restrict__ ck, const float* __restrict__ cv,
    const float* __restrict__ ca, const float* __restrict__ cg,
    float* __restrict__ xln,
    unsigned short* __restrict__ mR, unsigned short* __restrict__ mW,
    unsigned short* __restrict__ mK, unsigned short* __restrict__ mV,
    unsigned short* __restrict__ mA, unsigned short* __restrict__ mG) {
  __shared__ float red[8];
  const int row = blockIdx.x;
  const int t = row & (Tt - 1);
  const int tid = threadIdx.x;
  const int c = tid * 4;
  const size_t base = (size_t)row * Cc + c;
  float a0 = x[base], a1 = x[base + 1], a2 = x[base + 2], a3 = x[base + 3];
  float mu, rs;
  row_stats(a0, a1, a2, a3, red, mu, rs, 1e-5f);
  float pw0 = lnpw[c], pw1 = lnpw[c + 1], pw2 = lnpw[c + 2], pw3 = lnpw[c + 3];
  float pb0 = lnpb[c], pb1 = lnpb[c + 1], pb2 = lnpb[c + 2], pb3 = lnpb[c + 3];
  float l0 = (a0 - mu) * rs * pw0 + pb0, l1 = (a1 - mu) * rs * pw1 + pb1;
  float l2 = (a2 - mu) * rs * pw2 + pb2, l3 = (a3 - mu) * rs * pw3 + pb3;
  float4 st; st.x = l0; st.y = l1; st.z = l2; st.w = l3;
  *(float4*)(xln + base) = st;
  row_stats(l0, l1, l2, l3, red, mu, rs, 1e-5f);
  float aw0 = lnaw[c], aw1 = lnaw[c + 1], aw2 = lnaw[c + 2], aw3 = lnaw[c + 3];
  float ab0 = lnab[c], ab1 = lnab[c + 1], ab2 = lnab[c + 2], ab3 = lnab[c + 3];
  float n0 = (l0 - mu) * rs * aw0 + ab0, n1 = (l1 - mu) * rs * aw1 + ab1;
  float n2 = (l2 - mu) * rs * aw2 + ab2, n3 = (l3 - mu) * rs * aw3 + ab3;
  float p0 = 0.f, p1 = 0.f, p2 = 0.f, p3 = 0.f;
  if (t > 0) {  // uniform over block
    const size_t pb_ = base - Cc;
    float q0 = x[pb_], q1 = x[pb_ + 1], q2 = x[pb_ + 2], q3 = x[pb_ + 3];
    row_stats(q0, q1, q2, q3, red, mu, rs, 1e-5f);
    float e0 = (q0 - mu) * rs * pw0 + pb0, e1 = (q1 - mu) * rs * pw1 + pb1;
    float e2 = (q2 - mu) * rs * pw2 + pb2, e3 = (q3 - mu) * rs * pw3 + pb3;
    row_stats(e0, e1, e2, e3, red, mu, rs, 1e-5f);
    p0 = (e0 - mu) * rs * aw0 + ab0; p1 = (e1 - mu) * rs * aw1 + ab1;
    p2 = (e2 - mu) * rs * aw2 + ab2; p3 = (e3 - mu) * rs * aw3 + ab3;
  }
  float d0 = p0 - n0, d1 = p1 - n1, d2 = p2 - n2, d3 = p3 - n3;
  #define EMIT(cf, dst) { \
    float f0 = cf[c], f1 = cf[c + 1], f2 = cf[c + 2], f3 = cf[c + 3]; \
    ushort4 u; u.x = f2bf(n0 + d0 * f0); u.y = f2bf(n1 + d1 * f1); \
    u.z = f2bf(n2 + d2 * f2); u.w = f2bf(n3 + d3 * f3); \
    *(ushort4*)(dst + base) = u; }
  EMIT(cr, mR) EMIT(cw, mW) EMIT(ck, mK) EMIT(cv, mV) EMIT(ca, mA) EMIT(cg, mG)
  #undef EMIT
}

// ---------------- bf16 MFMA GEMM bodies ----------------
// A: (M,K) bf16 row-major; Bt: (N,K) bf16 row-major.
// MODE: 0 f32 | 1 bf16 | 2 tanh->bf16 | 3 sigmoid->bf16 | 4 relu^2->bf16
//       5 sigmoid(z+bias[col])->f32 | 6 exp(-sigmoid(z+bias[col])*e^-.5)->f32 | 7 z+res->f32
DEV void gll16(const unsigned short* g, unsigned short* l) {
  __builtin_amdgcn_global_load_lds(
      (const __attribute__((address_space(1))) void*)g,
      (__attribute__((address_space(3))) void*)l, 16, 0, 0);
}

template <int MODE>
DEV void gemm_epi(float z, size_t oi, int col,
                  float* outF, unsigned short* outB,
                  const float* bias, const float* res) {
  if constexpr (MODE == 0) outF[oi] = z;
  else if constexpr (MODE == 1) outB[oi] = f2bf(z);
  else if constexpr (MODE == 2) outB[oi] = f2bf(tanhf(z));
  else if constexpr (MODE == 3) outB[oi] = f2bf(1.f / (1.f + expf(-z)));
  else if constexpr (MODE == 4) { float m = fmaxf(z, 0.f); outB[oi] = f2bf(m * m); }
  else if constexpr (MODE == 5) { z += bias[col]; outF[oi] = 1.f / (1.f + expf(-z)); }
  else if constexpr (MODE == 6) {
    z += bias[col];
    float sg = 1.f / (1.f + expf(-z));
    outF[oi] = expf(-0.6065306597126334f * sg);
  } else { outF[oi] = z + res[oi]; }
}

// runtime-mode epilogue for z-batched LoRA kernels (modes 0,1,2,3,5,6)
DEV void gemm_epi_rt(int mode, float z, size_t oi, int col,
                     float* outF, unsigned short* outB, const float* bias) {
  if (mode == 0) outF[oi] = z;
  else if (mode == 1) outB[oi] = f2bf(z);
  else if (mode == 2) outB[oi] = f2bf(tanhf(z));
  else if (mode == 3) outB[oi] = f2bf(1.f / (1.f + expf(-z)));
  else if (mode == 5) { z += bias[col]; outF[oi] = 1.f / (1.f + expf(-z)); }
  else { z += bias[col]; float sg = 1.f / (1.f + expf(-z));
         outF[oi] = expf(-0.6065306597126334f * sg); }
}

// 128M x 64N tile body, runtime mode (for z-batched small GEMMs)
DEV void gemm_body_rt(const unsigned short* A, const unsigned short* Bt,
                      int Nn, int K,
                      float* outF, unsigned short* outB, const float* bias,
                      unsigned short* lsA, unsigned short* lsB,
                      int m0, int n0, int mode) {
  const int tid = threadIdx.x;
  const int lane = tid & 63;
  const int wave = tid >> 6;
  const int wy = wave >> 1, wx = wave & 1;
  const int sl4 = lane >> 2;
  const int sc = (lane & 3) << 3;
  f32x4 acc[4][2];
  #pragma unroll
  for (int i = 0; i < 4; ++i)
    #pragma unroll
    for (int j = 0; j < 2; ++j) { f32x4 z = {0.f, 0.f, 0.f, 0.f}; acc[i][j] = z; }
  const int fr = lane & 15;
  const int fk = (lane >> 4) << 3;
  for (int k0 = 0; k0 < K; k0 += 32) {
    #pragma unroll
    for (int j = 0; j < 2; ++j) {
      const int rb = (wave + j * 4) * 16;
      gll16(A + (size_t)(m0 + rb + sl4) * K + k0 + sc, lsA + rb * 32);
    }
    {
      const int rb = wave * 16;
      int br = n0 + rb + sl4;
      br = br < Nn ? br : Nn - 1;
      gll16(Bt + (size_t)br * K + k0 + sc, lsB + rb * 32);
    }
    __syncthreads();
    short8 af[4], bf[2];
    #pragma unroll
    for (int mt = 0; mt < 4; ++mt)
      af[mt] = *(const short8*)(lsA + (wy * 64 + mt * 16 + fr) * 32 + fk);
    #pragma unroll
    for (int nt = 0; nt < 2; ++nt)
      bf[nt] = *(const short8*)(lsB + (wx * 32 + nt * 16 + fr) * 32 + fk);
    #pragma unroll
    for (int mt = 0; mt < 4; ++mt)
      #pragma unroll
      for (int nt = 0; nt < 2; ++nt)
        acc[mt][nt] = __builtin_amdgcn_mfma_f32_16x16x32_bf16(af[mt], bf[nt], acc[mt][nt], 0, 0, 0);
    __syncthreads();
  }
  const int rbase = (lane >> 4) << 2;
  const int cbase = lane & 15;
  #pragma unroll
  for (int mt = 0; mt < 4; ++mt)
    #pragma unroll
    for (int nt = 0; nt < 2; ++nt)
      #pragma unroll
      for (int rr = 0; rr < 4; ++rr) {
        int row = m0 + wy * 64 + mt * 16 + rbase + rr;
        int col = n0 + wx * 32 + nt * 16 + cbase;
        if (col < Nn)
          gemm_epi_rt(mode, acc[mt][nt][rr], (size_t)row * Nn + col, col, outF, outB, bias);
      }
}

// stage-1 LoRA batch: z=0 w1(tanh), z=1 a1(plain), z=2/3 g1(sigmoid) cols 0-63/64-127
__global__ __launch_bounds__(256) void kg_lora1(
    const unsigned short* __restrict__ mW, const unsigned short* __restrict__ mA,
    const unsigned short* __restrict__ mG,
    const unsigned short* __restrict__ w1T, const unsigned short* __restrict__ a1T,
    const unsigned short* __restrict__ g1T,
    unsigned short* __restrict__ tmpw, unsigned short* __restrict__ tmpa,
    unsigned short* __restrict__ tmpg) {
  __shared__ unsigned short lsA[128 * 32];
  __shared__ unsigned short lsB[64 * 32];
  const int z = blockIdx.z;
  const unsigned short* A  = z == 0 ? mW : z == 1 ? mA : mG;
  const unsigned short* Bt = z == 0 ? w1T : z == 1 ? a1T : g1T;
  unsigned short* outB     = z == 0 ? tmpw : z == 1 ? tmpa : tmpg;
  const int Nn = z < 2 ? 64 : 128;
  const int n0 = z < 2 ? 0 : (z - 2) * 64;
  const int mode = z == 0 ? 2 : z == 1 ? 1 : 3;
  gemm_body_rt(A, Bt, Nn, 1024, nullptr, outB, nullptr, lsA, lsB,
               blockIdx.y * 128, n0, mode);
}

// stage-2 LoRA batch: z=0 decay(mode6,K=64), z=1 aicl(mode5,K=64), z=2 gout(mode0,K=128)
__global__ __launch_bounds__(256) void kg_lora2(
    const unsigned short* __restrict__ tmpw, const unsigned short* __restrict__ tmpa,
    const unsigned short* __restrict__ tmpg,
    const unsigned short* __restrict__ w2T, const unsigned short* __restrict__ a2T,
    const unsigned short* __restrict__ g2T,
    float* __restrict__ decay, float* __restrict__ aicl, float* __restrict__ gout,
    const float* __restrict__ w0v, const float* __restrict__ a0v) {
  __shared__ unsigned short lsA[128 * 32];
  __shared__ unsigned short lsB[64 * 32];
  const int z = blockIdx.z;
  const unsigned short* A  = z == 0 ? tmpw : z == 1 ? tmpa : tmpg;
  const unsigned short* Bt = z == 0 ? w2T : z == 1 ? a2T : g2T;
  float* outF              = z == 0 ? decay : z == 1 ? aicl : gout;
  const float* bias        = z == 0 ? w0v : z == 1 ? a0v : nullptr;
  const int K = z < 2 ? 64 : 128;
  const int mode = z == 0 ? 6 : z == 1 ? 5 : 0;
  gemm_body_rt(A, Bt, 1024, K, outF, nullptr, bias, lsA, lsB,
               blockIdx.y * 128, blockIdx.x * 64, mode);
}

// 128M x 128N tile body (exact m97 structure)
template <int MODE>
DEV void gemm2_body(const unsigned short* A, const unsigned short* Bt,
                    int Nn, int K,
                    float* outF, unsigned short* outB,
                    const float* bias, const float* res,
                    unsigned short* lsA, unsigned short* lsB,
                    int m0, int n0) {
  const int tid = threadIdx.x;
  const int lane = tid & 63;
  const int wave = tid >> 6;
  const int wy = wave >> 1, wx = wave & 1;
  const int sl4 = lane >> 2;
  const int sc = (lane & 3) << 3;
  f32x4 acc[4][4];
  #pragma unroll
  for (int i = 0; i < 4; ++i)
    #pragma unroll
    for (int j = 0; j < 4; ++j) { f32x4 z = {0.f, 0.f, 0.f, 0.f}; acc[i][j] = z; }
  const int fr = lane & 15;
  const int fk = (lane >> 4) << 3;
  for (int k0 = 0; k0 < K; k0 += 32) {
    #pragma unroll
    for (int j = 0; j < 2; ++j) {
      const int rb = (wave + j * 4) * 16;
      gll16(A + (size_t)(m0 + rb + sl4) * K + k0 + sc, lsA + rb * 32);
      int br = n0 + rb + sl4;
      br = br < Nn ? br : Nn - 1;
      gll16(Bt + (size_t)br * K + k0 + sc, lsB + rb * 32);
    }
    __syncthreads();
    short8 af[4], bf[4];
    #pragma unroll
    for (int mt = 0; mt < 4; ++mt)
      af[mt] = *(const short8*)(lsA + (wy * 64 + mt * 16 + fr) * 32 + fk);
    #pragma unroll
    for (int nt = 0; nt < 4; ++nt)
      bf[nt] = *(const short8*)(lsB + (wx * 64 + nt * 16 + fr) * 32 + fk);
    #pragma unroll
    for (int mt = 0; mt < 4; ++mt)
      #pragma unroll
      for (int nt = 0; nt < 4; ++nt)
        acc[mt][nt] = __builtin_amdgcn_mfma_f32_16x16x32_bf16(af[mt], bf[nt], acc[mt][nt], 0, 0, 0);
    __syncthreads();
  }
  const int rbase = (lane >> 4) << 2;
  const int cbase = lane & 15;
  #pragma unroll
  for (int mt = 0; mt < 4; ++mt)
    #pragma unroll
    for (int nt = 0; nt < 4; ++nt)
      #pragma unroll
      for (int rr = 0; rr < 4; ++rr) {
        int row = m0 + wy * 64 + mt * 16 + rbase + rr;
        int col = n0 + wx * 64 + nt * 16 + cbase;
        if (col < Nn)
          gemm_epi<MODE>(acc[mt][nt][rr], (size_t)row * Nn + col, col, outF, outB, bias, res);
      }
}

template <int MODE>
__global__ __launch_bounds__(256) void kg_gemm2(
    const unsigned short* __restrict__ A, const unsigned short* __restrict__ Bt,
    int M, int Nn, int K,
    float* __restrict__ outF, unsigned short* __restrict__ outB,
    const float* __restrict__ bias, const float* __restrict__ res) {
  __shared__ unsigned short lsA[128 * 32];
  __shared__ unsigned short lsB[128 * 32];
  gemm2_body<MODE>(A, Bt, Nn, K, outF, outB, bias, res, lsA, lsB,
                   blockIdx.y * 128, blockIdx.x * 128);
}

// r/k/v projections batched (z selects), 128x128 tile: grid (8,32,3) = 768 blocks
__global__ __launch_bounds__(256) void kg_gemm2_qkv(
    const unsigned short* __restrict__ A0, const unsigned short* __restrict__ A1,
    const unsigned short* __restrict__ A2,
    const unsigned short* __restrict__ B0, const unsigned short* __restrict__ B1,
    const unsigned short* __restrict__ B2,
    float* __restrict__ O0, float* __restrict__ O1, float* __restrict__ O2) {
  __shared__ unsigned short lsA[128 * 32];
  __shared__ unsigned short lsB[128 * 32];
  const int z = blockIdx.z;
  const unsigned short* A = z == 0 ? A0 : z == 1 ? A1 : A2;
  const unsigned short* Bt = z == 0 ? B0 : z == 1 ? B1 : B2;
  float* outF = z == 0 ? O0 : z == 1 ? O1 : O2;
  gemm2_body<0>(A, Bt, 1024, 1024, outF, nullptr, nullptr, nullptr, lsA, lsB,
                blockIdx.y * 128, blockIdx.x * 128);
}

// ---------------- K4: kk-normalize, a/b vectors, k update (in place) ----------------
__global__ __launch_bounds__(256) void k4_prep(
    float* __restrict__ k, const float* __restrict__ a,
    const float* __restrict__ kkc, const float* __restrict__ kac,
    float* __restrict__ aw, float* __restrict__ bw) {
  const int row = blockIdx.x, tid = threadIdx.x;
  const int c = tid * 4;
  const size_t base = (size_t)row * Cc + c;
  float k0 = k[base], k1 = k[base + 1], k2 = k[base + 2], k3 = k[base + 3];
  float a0 = a[base], a1 = a[base + 1], a2 = a[base + 2], a3 = a[base + 3];
  float h0 = k0 * kkc[c], h1 = k1 * kkc[c + 1], h2 = k2 * kkc[c + 2], h3 = k3 * kkc[c + 3];
  float ss = h0 * h0 + h1 * h1 + h2 * h2 + h3 * h3;
  #pragma unroll
  for (int m = 8; m; m >>= 1) ss += __shfl_xor(ss, m);
  float inv = 1.f / fmaxf(sqrtf(ss), 1e-12f);
  h0 *= inv; h1 *= inv; h2 *= inv; h3 *= inv;
  float4 v4;
  v4.x = -h0; v4.y = -h1; v4.z = -h2; v4.w = -h3;
  *(float4*)(aw + base) = v4;
  v4.x = h0 * a0; v4.y = h1 * a1; v4.z = h2 * a2; v4.w = h3 * a3;
  *(float4*)(bw + base) = v4;
  v4.x = k0 * (1.f + (a0 - 1.f) * kac[c]);
  v4.y = k1 * (1.f + (a1 - 1.f) * kac[c + 1]);
  v4.z = k2 * (1.f + (a2 - 1.f) * kac[c + 2]);
  v4.w = k3 * (1.f + (a3 - 1.f) * kac[c + 3]);
  *(float4*)(k + base) = v4;
}

// ---------------- K5: WKV7 — R2-proven: 8-wave blocks, shared staging ----------------
// 256 blocks = (half, bh) x 512 threads (8 waves); wave w owns rows
// half*32 + w*4 .. +3. Lane = (rw = lane>>4, cg = lane&15): 4 cols/lane, S[4];
// 16-lane reduce = 4 serial DPPs. One LDS staging copy per block; CS=8 double
// buffer; one barrier/chunk. Measured 114.6us (R2). R4's bf16-operand variant
// measured 119.2 (unpack VALU ate the LDS-byte saving) — reverted.
#define CS 8
__global__ __launch_bounds__(512, 2) void k5_wkv7(
    const float* __restrict__ r, const float* __restrict__ dec,
    const float* __restrict__ k, const float* __restrict__ v,
    const float* __restrict__ aw, const float* __restrict__ bw,
    float* __restrict__ o) {
  const int blk = blockIdx.x;              // 0..255
  const int bh = blk & 127, half = blk >> 7;
  const int b = bh >> 4, h = bh & 15;
  const int tid = threadIdx.x;
  const int lane = tid & 63;
  const int w = tid >> 6;                  // wave 0..7
  const int cg = lane & 15;                // column group (4 cols)
  const int rw = lane >> 4;                // row within wave's 4
  const int row = half * 32 + w * 4 + rw;  // state row i (0..63)
  const int cb = cg << 2;                  // column base j0

  __shared__ float buf[2][6 * CS * 64];    // 2 x 12 KB

  float S[4];
  #pragma unroll
  for (int j = 0; j < 4; ++j) S[j] = 0.f;

  const size_t base = (size_t)b * Tt * Cc + (size_t)h * Nh;

  const float* sptr = w == 0 ? aw : w == 1 ? dec : w == 2 ? bw
                    : w == 3 ? k  : w == 4 ? r   : v;
  const int srow = lane >> 4;              // t-offset within chunk (0..3)
  const int scol = (lane & 15) << 2;       // col (0..60 step 4)

  uint4 R0, R1;
  #define LOADC(cstart) if (w < 6) { \
    const size_t g0 = base + (size_t)((cstart) + srow) * Cc + scol; \
    R0 = *(const uint4*)(sptr + g0); \
    R1 = *(const uint4*)(sptr + g0 + 4 * Cc); }

  LOADC(0)

  #pragma unroll 1
  for (int c = 0; c < Tt / CS; ++c) {
    float* bp = buf[c & 1];
    if (w < 6) {
      *(uint4*)(bp + w * 512 + (lane << 2)) = R0;        // t 0..3
      *(uint4*)(bp + w * 512 + 256 + (lane << 2)) = R1;  // t 4..7
    }
    const int cn = (c + 1 < Tt / CS) ? (c + 1) : c;
    LOADC(cn * CS)
    __syncthreads();

    float4 Aq[2], Dq[2], Bq[2], Kq[2], Rq[2];
    float Vv[2];
    #define LOADOPS(slot, ss) { \
      const float* sp_ = bp + (ss) * 64; \
      Aq[slot] = *(const float4*)(sp_ + cb); \
      Dq[slot] = *(const float4*)(sp_ + 512 + cb); \
      Bq[slot] = *(const float4*)(sp_ + 1024 + cb); \
      Kq[slot] = *(const float4*)(sp_ + 1536 + cb); \
      Rq[slot] = *(const float4*)(sp_ + 2048 + cb); \
      Vv[slot] = sp_[2560 + row]; }

    LOADOPS(0, 0)
    #pragma unroll
    for (int s = 0; s < CS; ++s) {
      const int cu = s & 1, nx = cu ^ 1;
      if (s + 1 < CS) LOADOPS(nx, s + 1)     // prefetch next step's operands

      float4 a4 = Aq[cu];
      float sa = fmaf(S[1], a4.y, S[0] * a4.x) + fmaf(S[3], a4.w, S[2] * a4.z);
      sa = dppadd<0xB1>(sa);
      sa = dppadd<0x4E>(sa);
      sa = dppadd<0x124>(sa);
      sa = dppadd<0x128>(sa);

      const float vv = Vv[cu];
      float4 d4 = Dq[cu], b4 = Bq[cu], k4 = Kq[cu], r4 = Rq[cu];
      S[0] = fmaf(S[0], d4.x, fmaf(vv, k4.x, sa * b4.x));
      float oo = S[0] * r4.x;
      S[1] = fmaf(S[1], d4.y, fmaf(vv, k4.y, sa * b4.y));
      oo = fmaf(S[1], r4.y, oo);
      S[2] = fmaf(S[2], d4.z, fmaf(vv, k4.z, sa * b4.z));
      oo = fmaf(S[2], r4.z, oo);
      S[3] = fmaf(S[3], d4.w, fmaf(vv, k4.w, sa * b4.w));
      oo = fmaf(S[3], r4.w, oo);

      oo = dppadd<0xB1>(oo);
      oo = dppadd<0x4E>(oo);
      oo = dppadd<0x124>(oo);
      oo = dppadd<0x128>(oo);
      if (cg == 0) o[base + (size_t)(c * CS + s) * Cc + row] = oo;
    }
    #undef LOADOPS
  }
  #undef LOADC
}

// ---------------- K6: head GroupNorm + rk bonus + gate ----------------
__global__ __launch_bounds__(256) void k6_out(
    const float* __restrict__ o, const float* __restrict__ r, const float* __restrict__ k,
    const float* __restrict__ v, const float* __restrict__ rk,
    const float* __restrict__ gnw, const float* __restrict__ gnb,
    const float* __restrict__ g, unsigned short* __restrict__ og) {
  const int row = blockIdx.x, tid = threadIdx.x;
  const int c = tid * 4;
  const size_t base = (size_t)row * Cc + c;
  float o0 = o[base], o1 = o[base + 1], o2 = o[base + 2], o3 = o[base + 3];
  float r0 = r[base], r1 = r[base + 1], r2 = r[base + 2], r3 = r[base + 3];
  float k0 = k[base], k1 = k[base + 1], k2 = k[base + 2], k3 = k[base + 3];
  float s = o0 + o1 + o2 + o3;
  float q = o0 * o0 + o1 * o1 + o2 * o2 + o3 * o3;
  float bs = r0 * k0 * rk[c] + r1 * k1 * rk[c + 1] + r2 * k2 * rk[c + 2] + r3 * k3 * rk[c + 3];
  #pragma unroll
  for (int m = 8; m; m >>= 1) {
    s += __shfl_xor(s, m); q += __shfl_xor(q, m); bs += __shfl_xor(bs, m);
  }
  float mu = s * (1.f / 64.f);
  float var = q * (1.f / 64.f) - mu * mu;
  float rs = rsqrtf(var + 64e-5f);
  float v0 = v[base], v1 = v[base + 1], v2 = v[base + 2], v3 = v[base + 3];
  float z0 = (o0 - mu) * rs * gnw[c] + gnb[c] + bs * v0;
  float z1 = (o1 - mu) * rs * gnw[c + 1] + gnb[c + 1] + bs * v1;
  float z2 = (o2 - mu) * rs * gnw[c + 2] + gnb[c + 2] + bs * v2;
  float z3 = (o3 - mu) * rs * gnw[c + 3] + gnb[c + 3] + bs * v3;
  ushort4 u;
  u.x = f2bf(z0 * g[base]); u.y = f2bf(z1 * g[base + 1]);
  u.z = f2bf(z2 * g[base + 2]); u.w = f2bf(z3 * g[base + 3]);
  *(ushort4*)(og + base) = u;
}

// ---------------- K8: FFN LN + time-shift mix ----------------
__global__ __launch_bounds__(256) void k8_ffnmix(
    const float* __restrict__ x2, const float* __restrict__ lnw, const float* __restrict__ lnb,
    const float* __restrict__ fxk, unsigned short* __restrict__ kf) {
  __shared__ float red[8];
  const int row = blockIdx.x;
  const int t = row & (Tt - 1);
  const int tid = threadIdx.x;
  const int c = tid * 4;
  const size_t base = (size_t)row * Cc + c;
  float a0 = x2[base], a1 = x2[base + 1], a2 = x2[base + 2], a3 = x2[base + 3];
  float mu, rs;
  row_stats(a0, a1, a2, a3, red, mu, rs, 1e-5f);
  float w0 = lnw[c], w1 = lnw[c + 1], w2 = lnw[c + 2], w3 = lnw[c + 3];
  float b0 = lnb[c], b1 = lnb[c + 1], b2 = lnb[c + 2], b3 = lnb[c + 3];
  float f0 = (a0 - mu) * rs * w0 + b0, f1 = (a1 - mu) * rs * w1 + b1;
  float f2 = (a2 - mu) * rs * w2 + b2, f3 = (a3 - mu) * rs * w3 + b3;
  float p0 = 0.f, p1 = 0.f, p2 = 0.f, p3 = 0.f;
  if (t > 0) {
    const size_t pb_ = base - Cc;
    float q0 = x2[pb_], q1 = x2[pb_ + 1], q2 = x2[pb_ + 2], q3 = x2[pb_ + 3];
    row_stats(q0, q1, q2, q3, red, mu, rs, 1e-5f);
    p0 = (q0 - mu) * rs * w0 + b0; p1 = (q1 - mu) * rs * w1 + b1;
    p2 = (q2 - mu) * rs * w2 + b2; p3 = (q3 - mu) * rs * w3 + b3;
  }
  ushort4 u;
  u.x = f2bf(f0 + (p0 - f0) * fxk[c]);
  u.y = f2bf(f1 + (p1 - f1) * fxk[c + 1]);
  u.z = f2bf(f2 + (p2 - f2) * fxk[c + 2]);
  u.w = f2bf(f3 + (p3 - f3) * fxk[c + 3]);
  *(ushort4*)(kf + base) = u;
}

// ---------------- host ----------------
extern "C" void kernel_launch(void* const* d_in, const int* in_sizes, int n_in,
                              void* d_out, int out_size, void* d_ws, size_t ws_size,
                              hipStream_t stream) {
  (void)in_sizes; (void)n_in; (void)out_size; (void)ws_size;
  const float* x    = (const float*)d_in[0];
  const float* lnpw = (const float*)d_in[2];
  const float* lnpb = (const float*)d_in[3];
  const float* lnaw = (const float*)d_in[4];
  const float* lnab = (const float*)d_in[5];
  const float* lnfw = (const float*)d_in[6];
  const float* lnfb = (const float*)d_in[7];
  const float* cxr  = (const float*)d_in[8];
  const float* cxw  = (const float*)d_in[9];
  const float* cxk  = (const float*)d_in[10];
  const float* cxv  = (const float*)d_in[11];
  const float* cxa  = (const float*)d_in[12];
  const float* cxg  = (const float*)d_in[13];
  const float* w0v  = (const float*)d_in[14];
  const float* w1m  = (const float*)d_in[15];
  const float* w2m  = (const float*)d_in[16];
  const float* a0v  = (const float*)d_in[17];
  const float* a1m  = (const float*)d_in[18];
  const float* a2m  = (const float*)d_in[19];
  const float* g1m  = (const float*)d_in[20];
  const float* g2m  = (const float*)d_in[21];
  const float* kkv  = (const float*)d_in[22];
  const float* kav  = (const float*)d_in[23];
  const float* rkv  = (const float*)d_in[24];
  const float* Wr   = (const float*)d_in[25];
  const float* Wk   = (const float*)d_in[26];
  const float* Wv   = (const float*)d_in[27];
  const float* Wo   = (const float*)d_in[28];
  const float* gnw  = (const float*)d_in[29];
  const float* gnb  = (const float*)d_in[30];
  const float* fxk  = (const float*)d_in[31];
  const float* Wf1  = (const float*)d_in[32];
  const float* Wf2  = (const float*)d_in[33];

  char* ws = (char*)d_ws;
  float* outx = (float*)d_out;          // final x (B,T,C)
  float* vout = outx + BTC;             // v_first = v (B,T,C)

  // workspace layout (aliases noted)
  size_t off = 0;
  unsigned short* WrT  = (unsigned short*)(ws + off); off += 2097152;
  unsigned short* WkT  = (unsigned short*)(ws + off); off += 2097152;
  unsigned short* WvT  = (unsigned short*)(ws + off); off += 2097152;
  unsigned short* WoT  = (unsigned short*)(ws + off); off += 2097152;
  unsigned short* Wf1T = (unsigned short*)(ws + off); off += 8388608;
  unsigned short* Wf2T = (unsigned short*)(ws + off); off += 8388608;
  unsigned short* w1T  = (unsigned short*)(ws + off); off += 131072;
  unsigned short* w2T  = (unsigned short*)(ws + off); off += 131072;
  unsigned short* a1T  = (unsigned short*)(ws + off); off += 131072;
  unsigned short* a2T  = (unsigned short*)(ws + off); off += 131072;
  unsigned short* g1T  = (unsigned short*)(ws + off); off += 262144;
  unsigned short* g2T  = (unsigned short*)(ws + off); off += 262144;
  float* xln = (float*)(ws + off); off += 16777216;
  unsigned short* mixR = (unsigned short*)(ws + off);          // 6 x 8388608
  unsigned short* mixW = (unsigned short*)(ws + off + 8388608);
  unsigned short* mixK = (unsigned short*)(ws + off + 16777216);
  unsigned short* mixV = (unsigned short*)(ws + off + 25165824);
  unsigned short* mixA = (unsigned short*)(ws + off + 33554432);
  unsigned short* mixG = (unsigned short*)(ws + off + 41943040);
  unsigned short* hbuf = (unsigned short*)(ws + off);          // alias mix (dead by then)
  off += 50331648;
  unsigned short* tmpw = (unsigned short*)(ws + off); off += 524288;
  unsigned short* tmpa = (unsigned short*)(ws + off); off += 524288;
  unsigned short* tmpg = (unsigned short*)(ws + off); off += 1048576;
  float* decay = (float*)(ws + off);
  unsigned short* og = (unsigned short*)(ws + off);            // alias decay (dead after K5)
  off += 16777216;
  float* aicl = (float*)(ws + off);
  float* obuf = (float*)(ws + off);                            // alias aicl (dead after K4)
  off += 16777216;
  float* gout = (float*)(ws + off); off += 16777216;
  float* rbuf = (float*)(ws + off);
  float* x2   = (float*)(ws + off);                            // alias rbuf (dead after K6)
  off += 16777216;
  float* kbuf = (float*)(ws + off); off += 16777216;
  float* awb  = (float*)(ws + off);
  unsigned short* kf = (unsigned short*)(ws + off);            // alias awb (dead after K5)
  off += 16777216;
  float* bwb  = (float*)(ws + off); off += 16777216;           // total ~187 MB

  dim3 tb(32, 8);
  // weight prep: f32 (K,N) -> bf16 (N,K) — ALL 12 jobs in one dispatch
  TPack tp;
  tp.d[0]  = TDesc{Wr,  WrT,  1024, 1024, 0,     32};
  tp.d[1]  = TDesc{Wk,  WkT,  1024, 1024, 1024,  32};
  tp.d[2]  = TDesc{Wv,  WvT,  1024, 1024, 2048,  32};
  tp.d[3]  = TDesc{Wo,  WoT,  1024, 1024, 3072,  32};
  tp.d[4]  = TDesc{Wf1, Wf1T, 1024, 4096, 4096,  128};
  tp.d[5]  = TDesc{Wf2, Wf2T, 4096, 1024, 8192,  32};
  tp.d[6]  = TDesc{w1m, w1T,  1024, 64,   12288, 2};
  tp.d[7]  = TDesc{w2m, w2T,  64,   1024, 12352, 32};
  tp.d[8]  = TDesc{a1m, a1T,  1024, 64,   12416, 2};
  tp.d[9]  = TDesc{a2m, a2T,  64,   1024, 12480, 32};
  tp.d[10] = TDesc{g1m, g1T,  1024, 128,  12544, 4};
  tp.d[11] = TDesc{g2m, g2T,  128,  1024, 12672, 32};
  kt_transpose_multi<<<12800, tb, 0, stream>>>(tp);

  // K1: pre-LN + attn-LN + shift mixes
  k1_mix<<<Mm, 256, 0, stream>>>(x, lnpw, lnpb, lnaw, lnab, cxr, cxw, cxk, cxv, cxa, cxg,
                                 xln, mixR, mixW, mixK, mixV, mixA, mixG);

  // LoRA chains — 2 z-batched dispatches (was 6)
  kg_lora1<<<dim3(1, 32, 4), 256, 0, stream>>>(mixW, mixA, mixG, w1T, a1T, g1T,
                                               tmpw, tmpa, tmpg);
  kg_lora2<<<dim3(16, 32, 3), 256, 0, stream>>>(tmpw, tmpa, tmpg, w2T, a2T, g2T,
                                                decay, aicl, gout, w0v, a0v);

  // r / k / v projections — one z=3 dispatch, 128x128 tile (768 blocks = 3/CU)
  kg_gemm2_qkv<<<dim3(8, 32, 3), 256, 0, stream>>>(mixR, mixK, mixV, WrT, WkT, WvT,
                                                   rbuf, kbuf, vout);

  // recurrence inputs
  k4_prep<<<Mm, 256, 0, stream>>>(kbuf, aicl, kkv, kav, awb, bwb);
  // WKV7 scan — R2-proven config
  k5_wkv7<<<256, 512, 0, stream>>>(rbuf, decay, kbuf, vout, awb, bwb, obuf);
  // GN + bonus + gate
  k6_out<<<Mm, 256, 0, stream>>>(obuf, rbuf, kbuf, vout, rkv, gnw, gnb, gout, og);
  // o-projection + residual -> x2 (128x128 tile)
  kg_gemm2<7><<<dim3(8, 32), 256, 0, stream>>>(og, WoT, Mm, 1024, 1024, x2, nullptr, nullptr, xln);
  // FFN
  k8_ffnmix<<<Mm, 256, 0, stream>>>(x2, lnfw, lnfb, fxk, kf);
  kg_gemm2<4><<<dim3(32, 32), 256, 0, stream>>>(kf, Wf1T, Mm, 4096, 1024, nullptr, hbuf, nullptr, nullptr);
  kg_gemm2<7><<<dim3(8, 32), 256, 0, stream>>>(hbuf, Wf2T, Mm, 1024, 4096, outx, nullptr, nullptr, x2);
}

// Round 6
// 585.753 us; speedup vs baseline: 1.1905x; 1.0573x over previous
//
#include <hip/hip_runtime.h>

// ---------------- constants ----------------
#define Bb 8
#define Tt 512
#define Cc 1024
#define Hh 16
#define Nh 64
#define Mm 4096            // B*T
#define BTC 4194304        // M*C
#define DEV __device__ __forceinline__

typedef __attribute__((ext_vector_type(8))) short short8;
typedef __attribute__((ext_vector_type(4))) float f32x4;

DEV unsigned short f2bf(float f) {
  unsigned int u = __builtin_bit_cast(unsigned int, f);
  u += 0x7fffu + ((u >> 16) & 1u);
  return (unsigned short)(u >> 16);
}

// DPP butterfly add — pure VALU. 0xB1=quad xor1, 0x4E=quad xor2,
// 0x124=row_ror:4, 0x128=row_ror:8 (within 16-lane DPP row).
template <int CTRL>
DEV float dppadd(float x) {
  int xi = __builtin_bit_cast(int, x);
  int yi = __builtin_amdgcn_update_dpp(0, xi, CTRL, 0xF, 0xF, true);
  return x + __builtin_bit_cast(float, yi);
}

// ---------------- merged transpose f32 (K x N) -> bf16 (N x K) ----------------
struct TDesc { const float* in; unsigned short* out; int K, N, bstart, nbx; };
struct TPack { TDesc d[12]; };

__global__ __launch_bounds__(256) void kt_transpose_multi(TPack p) {
  __shared__ float tile[32][33];
  const int bid = blockIdx.x;
  int i = 0;
  #pragma unroll
  for (int j = 1; j < 12; ++j) if (bid >= p.d[j].bstart) i = j;
  const float* in = p.d[i].in;
  unsigned short* out = p.d[i].out;
  const int K = p.d[i].K, N = p.d[i].N;
  const int local = bid - p.d[i].bstart;
  const int byq = local / p.d[i].nbx;
  const int bx = (local - byq * p.d[i].nbx) * 32;
  const int by = byq * 32;
  int tx = threadIdx.x, ty = threadIdx.y;
  #pragma unroll
  for (int q = ty; q < 32; q += 8) {
    int kk = by + q, nn = bx + tx;
    tile[q][tx] = (kk < K && nn < N) ? in[(size_t)kk * N + nn] : 0.f;
  }
  __syncthreads();
  #pragma unroll
  for (int q = ty; q < 32; q += 8) {
    int nn = bx + q, kk = by + tx;
    if (nn < N && kk < K) out[(size_t)nn * K + kk] = f2bf(tile[tx][q]);
  }
}

// ---------------- block row stats (1024 elems over 256 threads) ----------------
DEV void row_stats(float v0, float v1, float v2, float v3, float* red,
                   float& mu, float& rs, float eps) {
  float s = v0 + v1 + v2 + v3;
  float q = v0 * v0 + v1 * v1 + v2 * v2 + v3 * v3;
  #pragma unroll
  for (int o = 32; o; o >>= 1) { s += __shfl_down(s, o); q += __shfl_down(q, o); }
  int w = threadIdx.x >> 6;
  __syncthreads();
  if ((threadIdx.x & 63) == 0) { red[w] = s; red[4 + w] = q; }
  __syncthreads();
  s = red[0] + red[1] + red[2] + red[3];
  q = red[4] + red[5] + red[6] + red[7];
  mu = s * (1.f / 1024.f);
  float var = q * (1.f / 1024.f) - mu * mu;
  rs = rsqrtf(var + eps);
}

// ---------------- K1: pre-LN + attn-LN + time-shift mixes ----------------
__global__ __launch_bounds__(256) void k1_mix(
    const float* __restrict__ x,
    const float* __restrict__ lnpw, const float* __restrict__ lnpb,
    const float* __restrict__ lnaw, const float* __restrict__ lnab,
    const float* __restrict__ cr, const float* __restrict__ cw,
    const float* __restrict__ ck, const float* __restrict__ cv,
    const float* __restrict__ ca, const float* __restrict__ cg,
    float* __restrict__ xln,
    unsigned short* __restrict__ mR, unsigned short* __restrict__ mW,
    unsigned short* __restrict__ mK, unsigned short* __restrict__ mV,
    unsigned short* __restrict__ mA, unsigned short* __restrict__ mG) {
  __shared__ float red[8];
  const int row = blockIdx.x;
  const int t = row & (Tt - 1);
  const int tid = threadIdx.x;
  const int c = tid * 4;
  const size_t base = (size_t)row * Cc + c;
  float a0 = x[base], a1 = x[base + 1], a2 = x[base + 2], a3 = x[base + 3];
  float mu, rs;
  row_stats(a0, a1, a2, a3, red, mu, rs, 1e-5f);
  float pw0 = lnpw[c], pw1 = lnpw[c + 1], pw2 = lnpw[c + 2], pw3 = lnpw[c + 3];
  float pb0 = lnpb[c], pb1 = lnpb[c + 1], pb2 = lnpb[c + 2], pb3 = lnpb[c + 3];
  float l0 = (a0 - mu) * rs * pw0 + pb0, l1 = (a1 - mu) * rs * pw1 + pb1;
  float l2 = (a2 - mu) * rs * pw2 + pb2, l3 = (a3 - mu) * rs * pw3 + pb3;
  float4 st; st.x = l0; st.y = l1; st.z = l2; st.w = l3;
  *(float4*)(xln + base) = st;
  row_stats(l0, l1, l2, l3, red, mu, rs, 1e-5f);
  float aw0 = lnaw[c], aw1 = lnaw[c + 1], aw2 = lnaw[c + 2], aw3 = lnaw[c + 3];
  float ab0 = lnab[c], ab1 = lnab[c + 1], ab2 = lnab[c + 2], ab3 = lnab[c + 3];
  float n0 = (l0 - mu) * rs * aw0 + ab0, n1 = (l1 - mu) * rs * aw1 + ab1;
  float n2 = (l2 - mu) * rs * aw2 + ab2, n3 = (l3 - mu) * rs * aw3 + ab3;
  float p0 = 0.f, p1 = 0.f, p2 = 0.f, p3 = 0.f;
  if (t > 0) {  // uniform over block
    const size_t pb_ = base - Cc;
    float q0 = x[pb_], q1 = x[pb_ + 1], q2 = x[pb_ + 2], q3 = x[pb_ + 3];
    row_stats(q0, q1, q2, q3, red, mu, rs, 1e-5f);
    float e0 = (q0 - mu) * rs * pw0 + pb0, e1 = (q1 - mu) * rs * pw1 + pb1;
    float e2 = (q2 - mu) * rs * pw2 + pb2, e3 = (q3 - mu) * rs * pw3 + pb3;
    row_stats(e0, e1, e2, e3, red, mu, rs, 1e-5f);
    p0 = (e0 - mu) * rs * aw0 + ab0; p1 = (e1 - mu) * rs * aw1 + ab1;
    p2 = (e2 - mu) * rs * aw2 + ab2; p3 = (e3 - mu) * rs * aw3 + ab3;
  }
  float d0 = p0 - n0, d1 = p1 - n1, d2 = p2 - n2, d3 = p3 - n3;
  #define EMIT(cf, dst) { \
    float f0 = cf[c], f1 = cf[c + 1], f2 = cf[c + 2], f3 = cf[c + 3]; \
    ushort4 u; u.x = f2bf(n0 + d0 * f0); u.y = f2bf(n1 + d1 * f1); \
    u.z = f2bf(n2 + d2 * f2); u.w = f2bf(n3 + d3 * f3); \
    *(ushort4*)(dst + base) = u; }
  EMIT(cr, mR) EMIT(cw, mW) EMIT(ck, mK) EMIT(cv, mV) EMIT(ca, mA) EMIT(cg, mG)
  #undef EMIT
}

// ---------------- bf16 MFMA GEMM bodies ----------------
// A: (M,K) bf16 row-major; Bt: (N,K) bf16 row-major.
// MODE: 0 f32 | 1 bf16 | 2 tanh->bf16 | 3 sigmoid->bf16 | 4 relu^2->bf16
//       5 sigmoid(z+bias[col])->f32 | 6 exp(-sigmoid(z+bias[col])*e^-.5)->f32 | 7 z+res->f32
DEV void gll16(const unsigned short* g, unsigned short* l) {
  __builtin_amdgcn_global_load_lds(
      (const __attribute__((address_space(1))) void*)g,
      (__attribute__((address_space(3))) void*)l, 16, 0, 0);
}

template <int MODE>
DEV void gemm_epi(float z, size_t oi, int col,
                  float* outF, unsigned short* outB,
                  const float* bias, const float* res) {
  if constexpr (MODE == 0) outF[oi] = z;
  else if constexpr (MODE == 1) outB[oi] = f2bf(z);
  else if constexpr (MODE == 2) outB[oi] = f2bf(tanhf(z));
  else if constexpr (MODE == 3) outB[oi] = f2bf(1.f / (1.f + expf(-z)));
  else if constexpr (MODE == 4) { float m = fmaxf(z, 0.f); outB[oi] = f2bf(m * m); }
  else if constexpr (MODE == 5) { z += bias[col]; outF[oi] = 1.f / (1.f + expf(-z)); }
  else if constexpr (MODE == 6) {
    z += bias[col];
    float sg = 1.f / (1.f + expf(-z));
    outF[oi] = expf(-0.6065306597126334f * sg);
  } else { outF[oi] = z + res[oi]; }
}

// runtime-mode epilogue for z-batched LoRA kernels (modes 0,1,2,3,5,6)
DEV void gemm_epi_rt(int mode, float z, size_t oi, int col,
                     float* outF, unsigned short* outB, const float* bias) {
  if (mode == 0) outF[oi] = z;
  else if (mode == 1) outB[oi] = f2bf(z);
  else if (mode == 2) outB[oi] = f2bf(tanhf(z));
  else if (mode == 3) outB[oi] = f2bf(1.f / (1.f + expf(-z)));
  else if (mode == 5) { z += bias[col]; outF[oi] = 1.f / (1.f + expf(-z)); }
  else { z += bias[col]; float sg = 1.f / (1.f + expf(-z));
         outF[oi] = expf(-0.6065306597126334f * sg); }
}

// ---- 128M x 64N tile, compile-time MODE (Wo / FFN2: 512 blocks = 2/CU so the
// vmcnt(0) barrier drain of one block hides behind the other's MFMA; R5's
// 128x128 = 1 block/CU exposed the drain — reverted) ----
template <int MODE>
__global__ __launch_bounds__(256) void kg_gemm64(
    const unsigned short* __restrict__ A, const unsigned short* __restrict__ Bt,
    int M, int Nn, int K,
    float* __restrict__ outF, unsigned short* __restrict__ outB,
    const float* __restrict__ bias, const float* __restrict__ res) {
  __shared__ unsigned short lsA[128 * 32];
  __shared__ unsigned short lsB[64 * 32];
  const int tid = threadIdx.x;
  const int lane = tid & 63;
  const int wave = tid >> 6;
  const int wy = wave >> 1, wx = wave & 1;
  const int m0 = blockIdx.y * 128;
  const int n0 = blockIdx.x * 64;
  const int sl4 = lane >> 2;
  const int sc = (lane & 3) << 3;
  f32x4 acc[4][2];
  #pragma unroll
  for (int i = 0; i < 4; ++i)
    #pragma unroll
    for (int j = 0; j < 2; ++j) { f32x4 z = {0.f, 0.f, 0.f, 0.f}; acc[i][j] = z; }
  const int fr = lane & 15;
  const int fk = (lane >> 4) << 3;
  for (int k0 = 0; k0 < K; k0 += 32) {
    #pragma unroll
    for (int j = 0; j < 2; ++j) {
      const int rb = (wave + j * 4) * 16;
      gll16(A + (size_t)(m0 + rb + sl4) * K + k0 + sc, lsA + rb * 32);
    }
    {
      const int rb = wave * 16;
      int br = n0 + rb + sl4;
      br = br < Nn ? br : Nn - 1;
      gll16(Bt + (size_t)br * K + k0 + sc, lsB + rb * 32);
    }
    __syncthreads();
    short8 af[4], bf[2];
    #pragma unroll
    for (int mt = 0; mt < 4; ++mt)
      af[mt] = *(const short8*)(lsA + (wy * 64 + mt * 16 + fr) * 32 + fk);
    #pragma unroll
    for (int nt = 0; nt < 2; ++nt)
      bf[nt] = *(const short8*)(lsB + (wx * 32 + nt * 16 + fr) * 32 + fk);
    #pragma unroll
    for (int mt = 0; mt < 4; ++mt)
      #pragma unroll
      for (int nt = 0; nt < 2; ++nt)
        acc[mt][nt] = __builtin_amdgcn_mfma_f32_16x16x32_bf16(af[mt], bf[nt], acc[mt][nt], 0, 0, 0);
    __syncthreads();
  }
  const int rbase = (lane >> 4) << 2;
  const int cbase = lane & 15;
  #pragma unroll
  for (int mt = 0; mt < 4; ++mt)
    #pragma unroll
    for (int nt = 0; nt < 2; ++nt)
      #pragma unroll
      for (int rr = 0; rr < 4; ++rr) {
        int row = m0 + wy * 64 + mt * 16 + rbase + rr;
        int col = n0 + wx * 32 + nt * 16 + cbase;
        if (col < Nn)
          gemm_epi<MODE>(acc[mt][nt][rr], (size_t)row * Nn + col, col, outF, outB, bias, res);
      }
}

// 128M x 64N tile body, runtime mode (for z-batched small GEMMs)
DEV void gemm_body_rt(const unsigned short* A, const unsigned short* Bt,
                      int Nn, int K,
                      float* outF, unsigned short* outB, const float* bias,
                      unsigned short* lsA, unsigned short* lsB,
                      int m0, int n0, int mode) {
  const int tid = threadIdx.x;
  const int lane = tid & 63;
  const int wave = tid >> 6;
  const int wy = wave >> 1, wx = wave & 1;
  const int sl4 = lane >> 2;
  const int sc = (lane & 3) << 3;
  f32x4 acc[4][2];
  #pragma unroll
  for (int i = 0; i < 4; ++i)
    #pragma unroll
    for (int j = 0; j < 2; ++j) { f32x4 z = {0.f, 0.f, 0.f, 0.f}; acc[i][j] = z; }
  const int fr = lane & 15;
  const int fk = (lane >> 4) << 3;
  for (int k0 = 0; k0 < K; k0 += 32) {
    #pragma unroll
    for (int j = 0; j < 2; ++j) {
      const int rb = (wave + j * 4) * 16;
      gll16(A + (size_t)(m0 + rb + sl4) * K + k0 + sc, lsA + rb * 32);
    }
    {
      const int rb = wave * 16;
      int br = n0 + rb + sl4;
      br = br < Nn ? br : Nn - 1;
      gll16(Bt + (size_t)br * K + k0 + sc, lsB + rb * 32);
    }
    __syncthreads();
    short8 af[4], bf[2];
    #pragma unroll
    for (int mt = 0; mt < 4; ++mt)
      af[mt] = *(const short8*)(lsA + (wy * 64 + mt * 16 + fr) * 32 + fk);
    #pragma unroll
    for (int nt = 0; nt < 2; ++nt)
      bf[nt] = *(const short8*)(lsB + (wx * 32 + nt * 16 + fr) * 32 + fk);
    #pragma unroll
    for (int mt = 0; mt < 4; ++mt)
      #pragma unroll
      for (int nt = 0; nt < 2; ++nt)
        acc[mt][nt] = __builtin_amdgcn_mfma_f32_16x16x32_bf16(af[mt], bf[nt], acc[mt][nt], 0, 0, 0);
    __syncthreads();
  }
  const int rbase = (lane >> 4) << 2;
  const int cbase = lane & 15;
  #pragma unroll
  for (int mt = 0; mt < 4; ++mt)
    #pragma unroll
    for (int nt = 0; nt < 2; ++nt)
      #pragma unroll
      for (int rr = 0; rr < 4; ++rr) {
        int row = m0 + wy * 64 + mt * 16 + rbase + rr;
        int col = n0 + wx * 32 + nt * 16 + cbase;
        if (col < Nn)
          gemm_epi_rt(mode, acc[mt][nt][rr], (size_t)row * Nn + col, col, outF, outB, bias);
      }
}

// stage-1 LoRA batch: z=0 w1(tanh), z=1 a1(plain), z=2/3 g1(sigmoid) cols 0-63/64-127
__global__ __launch_bounds__(256) void kg_lora1(
    const unsigned short* __restrict__ mW, const unsigned short* __restrict__ mA,
    const unsigned short* __restrict__ mG,
    const unsigned short* __restrict__ w1T, const unsigned short* __restrict__ a1T,
    const unsigned short* __restrict__ g1T,
    unsigned short* __restrict__ tmpw, unsigned short* __restrict__ tmpa,
    unsigned short* __restrict__ tmpg) {
  __shared__ unsigned short lsA[128 * 32];
  __shared__ unsigned short lsB[64 * 32];
  const int z = blockIdx.z;
  const unsigned short* A  = z == 0 ? mW : z == 1 ? mA : mG;
  const unsigned short* Bt = z == 0 ? w1T : z == 1 ? a1T : g1T;
  unsigned short* outB     = z == 0 ? tmpw : z == 1 ? tmpa : tmpg;
  const int Nn = z < 2 ? 64 : 128;
  const int n0 = z < 2 ? 0 : (z - 2) * 64;
  const int mode = z == 0 ? 2 : z == 1 ? 1 : 3;
  gemm_body_rt(A, Bt, Nn, 1024, nullptr, outB, nullptr, lsA, lsB,
               blockIdx.y * 128, n0, mode);
}

// stage-2 LoRA batch: z=0 decay(mode6,K=64), z=1 aicl(mode5,K=64), z=2 gout(mode0,K=128)
__global__ __launch_bounds__(256) void kg_lora2(
    const unsigned short* __restrict__ tmpw, const unsigned short* __restrict__ tmpa,
    const unsigned short* __restrict__ tmpg,
    const unsigned short* __restrict__ w2T, const unsigned short* __restrict__ a2T,
    const unsigned short* __restrict__ g2T,
    float* __restrict__ decay, float* __restrict__ aicl, float* __restrict__ gout,
    const float* __restrict__ w0v, const float* __restrict__ a0v) {
  __shared__ unsigned short lsA[128 * 32];
  __shared__ unsigned short lsB[64 * 32];
  const int z = blockIdx.z;
  const unsigned short* A  = z == 0 ? tmpw : z == 1 ? tmpa : tmpg;
  const unsigned short* Bt = z == 0 ? w2T : z == 1 ? a2T : g2T;
  float* outF              = z == 0 ? decay : z == 1 ? aicl : gout;
  const float* bias        = z == 0 ? w0v : z == 1 ? a0v : nullptr;
  const int K = z < 2 ? 64 : 128;
  const int mode = z == 0 ? 6 : z == 1 ? 5 : 0;
  gemm_body_rt(A, Bt, 1024, K, outF, nullptr, bias, lsA, lsB,
               blockIdx.y * 128, blockIdx.x * 64, mode);
}

// 128M x 128N tile body (exact m97 structure)
template <int MODE>
DEV void gemm2_body(const unsigned short* A, const unsigned short* Bt,
                    int Nn, int K,
                    float* outF, unsigned short* outB,
                    const float* bias, const float* res,
                    unsigned short* lsA, unsigned short* lsB,
                    int m0, int n0) {
  const int tid = threadIdx.x;
  const int lane = tid & 63;
  const int wave = tid >> 6;
  const int wy = wave >> 1, wx = wave & 1;
  const int sl4 = lane >> 2;
  const int sc = (lane & 3) << 3;
  f32x4 acc[4][4];
  #pragma unroll
  for (int i = 0; i < 4; ++i)
    #pragma unroll
    for (int j = 0; j < 4; ++j) { f32x4 z = {0.f, 0.f, 0.f, 0.f}; acc[i][j] = z; }
  const int fr = lane & 15;
  const int fk = (lane >> 4) << 3;
  for (int k0 = 0; k0 < K; k0 += 32) {
    #pragma unroll
    for (int j = 0; j < 2; ++j) {
      const int rb = (wave + j * 4) * 16;
      gll16(A + (size_t)(m0 + rb + sl4) * K + k0 + sc, lsA + rb * 32);
      int br = n0 + rb + sl4;
      br = br < Nn ? br : Nn - 1;
      gll16(Bt + (size_t)br * K + k0 + sc, lsB + rb * 32);
    }
    __syncthreads();
    short8 af[4], bf[4];
    #pragma unroll
    for (int mt = 0; mt < 4; ++mt)
      af[mt] = *(const short8*)(lsA + (wy * 64 + mt * 16 + fr) * 32 + fk);
    #pragma unroll
    for (int nt = 0; nt < 4; ++nt)
      bf[nt] = *(const short8*)(lsB + (wx * 64 + nt * 16 + fr) * 32 + fk);
    #pragma unroll
    for (int mt = 0; mt < 4; ++mt)
      #pragma unroll
      for (int nt = 0; nt < 4; ++nt)
        acc[mt][nt] = __builtin_amdgcn_mfma_f32_16x16x32_bf16(af[mt], bf[nt], acc[mt][nt], 0, 0, 0);
    __syncthreads();
  }
  const int rbase = (lane >> 4) << 2;
  const int cbase = lane & 15;
  #pragma unroll
  for (int mt = 0; mt < 4; ++mt)
    #pragma unroll
    for (int nt = 0; nt < 4; ++nt)
      #pragma unroll
      for (int rr = 0; rr < 4; ++rr) {
        int row = m0 + wy * 64 + mt * 16 + rbase + rr;
        int col = n0 + wx * 64 + nt * 16 + cbase;
        if (col < Nn)
          gemm_epi<MODE>(acc[mt][nt][rr], (size_t)row * Nn + col, col, outF, outB, bias, res);
      }
}

template <int MODE>
__global__ __launch_bounds__(256) void kg_gemm2(
    const unsigned short* __restrict__ A, const unsigned short* __restrict__ Bt,
    int M, int Nn, int K,
    float* __restrict__ outF, unsigned short* __restrict__ outB,
    const float* __restrict__ bias, const float* __restrict__ res) {
  __shared__ unsigned short lsA[128 * 32];
  __shared__ unsigned short lsB[128 * 32];
  gemm2_body<MODE>(A, Bt, Nn, K, outF, outB, bias, res, lsA, lsB,
                   blockIdx.y * 128, blockIdx.x * 128);
}

// ---------------- QKV projections + fused K4 (z selects r/k/v) ----------------
// 128x128 tile, grid (8,32,3)=768 blocks (3/CU). z==1 (k-projection) fuses the
// old k4_prep: a 128-col tile covers 2 FULL heads, and for a given (row, head)
// the 64 head-cols live in 4 acc regs x the 16 lanes sharing lane>>4 — so the
// kk-norm reduction is 4 FMAs + the proven 4-DPP 16-lane sum, no LDS. Deletes
// k4's 80MB round-trip. Numerically identical to k4 up to f32 sum order.
__global__ __launch_bounds__(256) void kg_qkv_fused(
    const unsigned short* __restrict__ A0, const unsigned short* __restrict__ A1,
    const unsigned short* __restrict__ A2,
    const unsigned short* __restrict__ B0, const unsigned short* __restrict__ B1,
    const unsigned short* __restrict__ B2,
    float* __restrict__ rbuf, float* __restrict__ kbuf, float* __restrict__ vout,
    const float* __restrict__ aicl,
    const float* __restrict__ kkc, const float* __restrict__ kac,
    float* __restrict__ awb, float* __restrict__ bwb) {
  __shared__ unsigned short lsA[128 * 32];
  __shared__ unsigned short lsB[128 * 32];
  const int z = blockIdx.z;
  const unsigned short* A = z == 0 ? A0 : z == 1 ? A1 : A2;
  const unsigned short* Bt = z == 0 ? B0 : z == 1 ? B1 : B2;
  const int tid = threadIdx.x;
  const int lane = tid & 63;
  const int wave = tid >> 6;
  const int wy = wave >> 1, wx = wave & 1;
  const int m0 = blockIdx.y * 128;
  const int n0 = blockIdx.x * 128;
  const int sl4 = lane >> 2;
  const int sc = (lane & 3) << 3;
  f32x4 acc[4][4];
  #pragma unroll
  for (int i = 0; i < 4; ++i)
    #pragma unroll
    for (int j = 0; j < 4; ++j) { f32x4 zz = {0.f, 0.f, 0.f, 0.f}; acc[i][j] = zz; }
  const int fr = lane & 15;
  const int fk = (lane >> 4) << 3;
  for (int k0 = 0; k0 < 1024; k0 += 32) {
    #pragma unroll
    for (int j = 0; j < 2; ++j) {
      const int rb = (wave + j * 4) * 16;
      gll16(A + (size_t)(m0 + rb + sl4) * 1024 + k0 + sc, lsA + rb * 32);
      gll16(Bt + (size_t)(n0 + rb + sl4) * 1024 + k0 + sc, lsB + rb * 32);
    }
    __syncthreads();
    short8 af[4], bf[4];
    #pragma unroll
    for (int mt = 0; mt < 4; ++mt)
      af[mt] = *(const short8*)(lsA + (wy * 64 + mt * 16 + fr) * 32 + fk);
    #pragma unroll
    for (int nt = 0; nt < 4; ++nt)
      bf[nt] = *(const short8*)(lsB + (wx * 64 + nt * 16 + fr) * 32 + fk);
    #pragma unroll
    for (int mt = 0; mt < 4; ++mt)
      #pragma unroll
      for (int nt = 0; nt < 4; ++nt)
        acc[mt][nt] = __builtin_amdgcn_mfma_f32_16x16x32_bf16(af[mt], bf[nt], acc[mt][nt], 0, 0, 0);
    __syncthreads();
  }
  const int rbase = (lane >> 4) << 2;
  const int cbase = lane & 15;
  if (z != 1) {
    float* outF = z == 0 ? rbuf : vout;
    #pragma unroll
    for (int mt = 0; mt < 4; ++mt)
      #pragma unroll
      for (int nt = 0; nt < 4; ++nt)
        #pragma unroll
        for (int rr = 0; rr < 4; ++rr) {
          int row = m0 + wy * 64 + mt * 16 + rbase + rr;
          int col = n0 + wx * 64 + nt * 16 + cbase;
          outF[(size_t)row * Cc + col] = acc[mt][nt][rr];
        }
  } else {
    // fused k4: per-(row,head) kk-normalize + a/b vectors + k update
    float kkc4[4], kac4[4];
    #pragma unroll
    for (int nt = 0; nt < 4; ++nt) {
      int col = n0 + wx * 64 + nt * 16 + cbase;
      kkc4[nt] = kkc[col];
      kac4[nt] = kac[col];
    }
    #pragma unroll
    for (int mt = 0; mt < 4; ++mt)
      #pragma unroll
      for (int rr = 0; rr < 4; ++rr) {
        int row = m0 + wy * 64 + mt * 16 + rbase + rr;
        float h0 = acc[mt][0][rr] * kkc4[0];
        float h1 = acc[mt][1][rr] * kkc4[1];
        float h2 = acc[mt][2][rr] * kkc4[2];
        float h3 = acc[mt][3][rr] * kkc4[3];
        float ss = (h0 * h0 + h1 * h1) + (h2 * h2 + h3 * h3);
        ss = dppadd<0xB1>(ss);
        ss = dppadd<0x4E>(ss);
        ss = dppadd<0x124>(ss);
        ss = dppadd<0x128>(ss);
        float inv = 1.f / fmaxf(sqrtf(ss), 1e-12f);
        #pragma unroll
        for (int nt = 0; nt < 4; ++nt) {
          int col = n0 + wx * 64 + nt * 16 + cbase;
          size_t oi = (size_t)row * Cc + col;
          float kv = acc[mt][nt][rr];
          float hn = kv * kkc4[nt] * inv;
          float av = aicl[oi];
          awb[oi] = -hn;
          bwb[oi] = hn * av;
          kbuf[oi] = kv * (1.f + (av - 1.f) * kac4[nt]);
        }
      }
  }
}

// ---------------- K5: WKV7 — R2-proven: 8-wave blocks, shared staging ----------------
// 256 blocks = (half, bh) x 512 threads (8 waves); wave w owns rows
// half*32 + w*4 .. +3. Lane = (rw = lane>>4, cg = lane&15): 4 cols/lane, S[4];
// 16-lane reduce = 4 serial DPPs. One LDS staging copy per block; CS=8 double
// buffer; one barrier/chunk. Measured 114.6-116.1us across R2/R5.
#define CS 8
__global__ __launch_bounds__(512, 2) void k5_wkv7(
    const float* __restrict__ r, const float* __restrict__ dec,
    const float* __restrict__ k, const float* __restrict__ v,
    const float* __restrict__ aw, const float* __restrict__ bw,
    float* __restrict__ o) {
  const int blk = blockIdx.x;              // 0..255
  const int bh = blk & 127, half = blk >> 7;
  const int b = bh >> 4, h = bh & 15;
  const int tid = threadIdx.x;
  const int lane = tid & 63;
  const int w = tid >> 6;                  // wave 0..7
  const int cg = lane & 15;                // column group (4 cols)
  const int rw = lane >> 4;                // row within wave's 4
  const int row = half * 32 + w * 4 + rw;  // state row i (0..63)
  const int cb = cg << 2;                  // column base j0

  __shared__ float buf[2][6 * CS * 64];    // 2 x 12 KB

  float S[4];
  #pragma unroll
  for (int j = 0; j < 4; ++j) S[j] = 0.f;

  const size_t base = (size_t)b * Tt * Cc + (size_t)h * Nh;

  const float* sptr = w == 0 ? aw : w == 1 ? dec : w == 2 ? bw
                    : w == 3 ? k  : w == 4 ? r   : v;
  const int srow = lane >> 4;              // t-offset within chunk (0..3)
  const int scol = (lane & 15) << 2;       // col (0..60 step 4)

  uint4 R0, R1;
  #define LOADC(cstart) if (w < 6) { \
    const size_t g0 = base + (size_t)((cstart) + srow) * Cc + scol; \
    R0 = *(const uint4*)(sptr + g0); \
    R1 = *(const uint4*)(sptr + g0 + 4 * Cc); }

  LOADC(0)

  #pragma unroll 1
  for (int c = 0; c < Tt / CS; ++c) {
    float* bp = buf[c & 1];
    if (w < 6) {
      *(uint4*)(bp + w * 512 + (lane << 2)) = R0;        // t 0..3
      *(uint4*)(bp + w * 512 + 256 + (lane << 2)) = R1;  // t 4..7
    }
    const int cn = (c + 1 < Tt / CS) ? (c + 1) : c;
    LOADC(cn * CS)
    __syncthreads();

    float4 Aq[2], Dq[2], Bq[2], Kq[2], Rq[2];
    float Vv[2];
    #define LOADOPS(slot, ss) { \
      const float* sp_ = bp + (ss) * 64; \
      Aq[slot] = *(const float4*)(sp_ + cb); \
      Dq[slot] = *(const float4*)(sp_ + 512 + cb); \
      Bq[slot] = *(const float4*)(sp_ + 1024 + cb); \
      Kq[slot] = *(const float4*)(sp_ + 1536 + cb); \
      Rq[slot] = *(const float4*)(sp_ + 2048 + cb); \
      Vv[slot] = sp_[2560 + row]; }

    LOADOPS(0, 0)
    #pragma unroll
    for (int s = 0; s < CS; ++s) {
      const int cu = s & 1, nx = cu ^ 1;
      if (s + 1 < CS) LOADOPS(nx, s + 1)     // prefetch next step's operands

      float4 a4 = Aq[cu];
      float sa = fmaf(S[1], a4.y, S[0] * a4.x) + fmaf(S[3], a4.w, S[2] * a4.z);
      sa = dppadd<0xB1>(sa);
      sa = dppadd<0x4E>(sa);
      sa = dppadd<0x124>(sa);
      sa = dppadd<0x128>(sa);

      const float vv = Vv[cu];
      float4 d4 = Dq[cu], b4 = Bq[cu], k4 = Kq[cu], r4 = Rq[cu];
      S[0] = fmaf(S[0], d4.x, fmaf(vv, k4.x, sa * b4.x));
      float oo = S[0] * r4.x;
      S[1] = fmaf(S[1], d4.y, fmaf(vv, k4.y, sa * b4.y));
      oo = fmaf(S[1], r4.y, oo);
      S[2] = fmaf(S[2], d4.z, fmaf(vv, k4.z, sa * b4.z));
      oo = fmaf(S[2], r4.z, oo);
      S[3] = fmaf(S[3], d4.w, fmaf(vv, k4.w, sa * b4.w));
      oo = fmaf(S[3], r4.w, oo);

      oo = dppadd<0xB1>(oo);
      oo = dppadd<0x4E>(oo);
      oo = dppadd<0x124>(oo);
      oo = dppadd<0x128>(oo);
      if (cg == 0) o[base + (size_t)(c * CS + s) * Cc + row] = oo;
    }
    #undef LOADOPS
  }
  #undef LOADC
}

// ---------------- K6: head GroupNorm + rk bonus + gate ----------------
__global__ __launch_bounds__(256) void k6_out(
    const float* __restrict__ o, const float* __restrict__ r, const float* __restrict__ k,
    const float* __restrict__ v, const float* __restrict__ rk,
    const float* __restrict__ gnw, const float* __restrict__ gnb,
    const float* __restrict__ g, unsigned short* __restrict__ og) {
  const int row = blockIdx.x, tid = threadIdx.x;
  const int c = tid * 4;
  const size_t base = (size_t)row * Cc + c;
  float o0 = o[base], o1 = o[base + 1], o2 = o[base + 2], o3 = o[base + 3];
  float r0 = r[base], r1 = r[base + 1], r2 = r[base + 2], r3 = r[base + 3];
  float k0 = k[base], k1 = k[base + 1], k2 = k[base + 2], k3 = k[base + 3];
  float s = o0 + o1 + o2 + o3;
  float q = o0 * o0 + o1 * o1 + o2 * o2 + o3 * o3;
  float bs = r0 * k0 * rk[c] + r1 * k1 * rk[c + 1] + r2 * k2 * rk[c + 2] + r3 * k3 * rk[c + 3];
  #pragma unroll
  for (int m = 8; m; m >>= 1) {
    s += __shfl_xor(s, m); q += __shfl_xor(q, m); bs += __shfl_xor(bs, m);
  }
  float mu = s * (1.f / 64.f);
  float var = q * (1.f / 64.f) - mu * mu;
  float rs = rsqrtf(var + 64e-5f);
  float v0 = v[base], v1 = v[base + 1], v2 = v[base + 2], v3 = v[base + 3];
  float z0 = (o0 - mu) * rs * gnw[c] + gnb[c] + bs * v0;
  float z1 = (o1 - mu) * rs * gnw[c + 1] + gnb[c + 1] + bs * v1;
  float z2 = (o2 - mu) * rs * gnw[c + 2] + gnb[c + 2] + bs * v2;
  float z3 = (o3 - mu) * rs * gnw[c + 3] + gnb[c + 3] + bs * v3;
  ushort4 u;
  u.x = f2bf(z0 * g[base]); u.y = f2bf(z1 * g[base + 1]);
  u.z = f2bf(z2 * g[base + 2]); u.w = f2bf(z3 * g[base + 3]);
  *(ushort4*)(og + base) = u;
}

// ---------------- K8: FFN LN + time-shift mix ----------------
__global__ __launch_bounds__(256) void k8_ffnmix(
    const float* __restrict__ x2, const float* __restrict__ lnw, const float* __restrict__ lnb,
    const float* __restrict__ fxk, unsigned short* __restrict__ kf) {
  __shared__ float red[8];
  const int row = blockIdx.x;
  const int t = row & (Tt - 1);
  const int tid = threadIdx.x;
  const int c = tid * 4;
  const size_t base = (size_t)row * Cc + c;
  float a0 = x2[base], a1 = x2[base + 1], a2 = x2[base + 2], a3 = x2[base + 3];
  float mu, rs;
  row_stats(a0, a1, a2, a3, red, mu, rs, 1e-5f);
  float w0 = lnw[c], w1 = lnw[c + 1], w2 = lnw[c + 2], w3 = lnw[c + 3];
  float b0 = lnb[c], b1 = lnb[c + 1], b2 = lnb[c + 2], b3 = lnb[c + 3];
  float f0 = (a0 - mu) * rs * w0 + b0, f1 = (a1 - mu) * rs * w1 + b1;
  float f2 = (a2 - mu) * rs * w2 + b2, f3 = (a3 - mu) * rs * w3 + b3;
  float p0 = 0.f, p1 = 0.f, p2 = 0.f, p3 = 0.f;
  if (t > 0) {
    const size_t pb_ = base - Cc;
    float q0 = x2[pb_], q1 = x2[pb_ + 1], q2 = x2[pb_ + 2], q3 = x2[pb_ + 3];
    row_stats(q0, q1, q2, q3, red, mu, rs, 1e-5f);
    p0 = (q0 - mu) * rs * w0 + b0; p1 = (q1 - mu) * rs * w1 + b1;
    p2 = (q2 - mu) * rs * w2 + b2; p3 = (q3 - mu) * rs * w3 + b3;
  }
  ushort4 u;
  u.x = f2bf(f0 + (p0 - f0) * fxk[c]);
  u.y = f2bf(f1 + (p1 - f1) * fxk[c + 1]);
  u.z = f2bf(f2 + (p2 - f2) * fxk[c + 2]);
  u.w = f2bf(f3 + (p3 - f3) * fxk[c + 3]);
  *(ushort4*)(kf + base) = u;
}

// ---------------- host ----------------
extern "C" void kernel_launch(void* const* d_in, const int* in_sizes, int n_in,
                              void* d_out, int out_size, void* d_ws, size_t ws_size,
                              hipStream_t stream) {
  (void)in_sizes; (void)n_in; (void)out_size; (void)ws_size;
  const float* x    = (const float*)d_in[0];
  const float* lnpw = (const float*)d_in[2];
  const float* lnpb = (const float*)d_in[3];
  const float* lnaw = (const float*)d_in[4];
  const float* lnab = (const float*)d_in[5];
  const float* lnfw = (const float*)d_in[6];
  const float* lnfb = (const float*)d_in[7];
  const float* cxr  = (const float*)d_in[8];
  const float* cxw  = (const float*)d_in[9];
  const float* cxk  = (const float*)d_in[10];
  const float* cxv  = (const float*)d_in[11];
  const float* cxa  = (const float*)d_in[12];
  const float* cxg  = (const float*)d_in[13];
  const float* w0v  = (const float*)d_in[14];
  const float* w1m  = (const float*)d_in[15];
  const float* w2m  = (const float*)d_in[16];
  const float* a0v  = (const float*)d_in[17];
  const float* a1m  = (const float*)d_in[18];
  const float* a2m  = (const float*)d_in[19];
  const float* g1m  = (const float*)d_in[20];
  const float* g2m  = (const float*)d_in[21];
  const float* kkv  = (const float*)d_in[22];
  const float* kav  = (const float*)d_in[23];
  const float* rkv  = (const float*)d_in[24];
  const float* Wr   = (const float*)d_in[25];
  const float* Wk   = (const float*)d_in[26];
  const float* Wv   = (const float*)d_in[27];
  const float* Wo   = (const float*)d_in[28];
  const float* gnw  = (const float*)d_in[29];
  const float* gnb  = (const float*)d_in[30];
  const float* fxk  = (const float*)d_in[31];
  const float* Wf1  = (const float*)d_in[32];
  const float* Wf2  = (const float*)d_in[33];

  char* ws = (char*)d_ws;
  float* outx = (float*)d_out;          // final x (B,T,C)
  float* vout = outx + BTC;             // v_first = v (B,T,C)

  // workspace layout (aliases noted)
  size_t off = 0;
  unsigned short* WrT  = (unsigned short*)(ws + off); off += 2097152;
  unsigned short* WkT  = (unsigned short*)(ws + off); off += 2097152;
  unsigned short* WvT  = (unsigned short*)(ws + off); off += 2097152;
  unsigned short* WoT  = (unsigned short*)(ws + off); off += 2097152;
  unsigned short* Wf1T = (unsigned short*)(ws + off); off += 8388608;
  unsigned short* Wf2T = (unsigned short*)(ws + off); off += 8388608;
  unsigned short* w1T  = (unsigned short*)(ws + off); off += 131072;
  unsigned short* w2T  = (unsigned short*)(ws + off); off += 131072;
  unsigned short* a1T  = (unsigned short*)(ws + off); off += 131072;
  unsigned short* a2T  = (unsigned short*)(ws + off); off += 131072;
  unsigned short* g1T  = (unsigned short*)(ws + off); off += 262144;
  unsigned short* g2T  = (unsigned short*)(ws + off); off += 262144;
  float* xln = (float*)(ws + off); off += 16777216;
  unsigned short* mixR = (unsigned short*)(ws + off);          // 6 x 8388608
  unsigned short* mixW = (unsigned short*)(ws + off + 8388608);
  unsigned short* mixK = (unsigned short*)(ws + off + 16777216);
  unsigned short* mixV = (unsigned short*)(ws + off + 25165824);
  unsigned short* mixA = (unsigned short*)(ws + off + 33554432);
  unsigned short* mixG = (unsigned short*)(ws + off + 41943040);
  unsigned short* hbuf = (unsigned short*)(ws + off);          // alias mix (dead by then)
  off += 50331648;
  unsigned short* tmpw = (unsigned short*)(ws + off); off += 524288;
  unsigned short* tmpa = (unsigned short*)(ws + off); off += 524288;
  unsigned short* tmpg = (unsigned short*)(ws + off); off += 1048576;
  float* decay = (float*)(ws + off);
  unsigned short* og = (unsigned short*)(ws + off);            // alias decay (dead after K5)
  off += 16777216;
  float* aicl = (float*)(ws + off);
  float* obuf = (float*)(ws + off);                            // alias aicl (dead after qkv_fused)
  off += 16777216;
  float* gout = (float*)(ws + off); off += 16777216;
  float* rbuf = (float*)(ws + off);
  float* x2   = (float*)(ws + off);                            // alias rbuf (dead after K6)
  off += 16777216;
  float* kbuf = (float*)(ws + off); off += 16777216;
  float* awb  = (float*)(ws + off);
  unsigned short* kf = (unsigned short*)(ws + off);            // alias awb (dead after K5)
  off += 16777216;
  float* bwb  = (float*)(ws + off); off += 16777216;           // total ~187 MB

  dim3 tb(32, 8);
  // weight prep: f32 (K,N) -> bf16 (N,K) — ALL 12 jobs in one dispatch
  TPack tp;
  tp.d[0]  = TDesc{Wr,  WrT,  1024, 1024, 0,     32};
  tp.d[1]  = TDesc{Wk,  WkT,  1024, 1024, 1024,  32};
  tp.d[2]  = TDesc{Wv,  WvT,  1024, 1024, 2048,  32};
  tp.d[3]  = TDesc{Wo,  WoT,  1024, 1024, 3072,  32};
  tp.d[4]  = TDesc{Wf1, Wf1T, 1024, 4096, 4096,  128};
  tp.d[5]  = TDesc{Wf2, Wf2T, 4096, 1024, 8192,  32};
  tp.d[6]  = TDesc{w1m, w1T,  1024, 64,   12288, 2};
  tp.d[7]  = TDesc{w2m, w2T,  64,   1024, 12352, 32};
  tp.d[8]  = TDesc{a1m, a1T,  1024, 64,   12416, 2};
  tp.d[9]  = TDesc{a2m, a2T,  64,   1024, 12480, 32};
  tp.d[10] = TDesc{g1m, g1T,  1024, 128,  12544, 4};
  tp.d[11] = TDesc{g2m, g2T,  128,  1024, 12672, 32};
  kt_transpose_multi<<<12800, tb, 0, stream>>>(tp);

  // K1: pre-LN + attn-LN + shift mixes
  k1_mix<<<Mm, 256, 0, stream>>>(x, lnpw, lnpb, lnaw, lnab, cxr, cxw, cxk, cxv, cxa, cxg,
                                 xln, mixR, mixW, mixK, mixV, mixA, mixG);

  // LoRA chains — 2 z-batched dispatches
  kg_lora1<<<dim3(1, 32, 4), 256, 0, stream>>>(mixW, mixA, mixG, w1T, a1T, g1T,
                                               tmpw, tmpa, tmpg);
  kg_lora2<<<dim3(16, 32, 3), 256, 0, stream>>>(tmpw, tmpa, tmpg, w2T, a2T, g2T,
                                                decay, aicl, gout, w0v, a0v);

  // r / k / v projections + fused k4 (needs aicl -> after lora2)
  kg_qkv_fused<<<dim3(8, 32, 3), 256, 0, stream>>>(mixR, mixK, mixV, WrT, WkT, WvT,
                                                   rbuf, kbuf, vout,
                                                   aicl, kkv, kav, awb, bwb);

  // WKV7 scan — R2-proven config
  k5_wkv7<<<256, 512, 0, stream>>>(rbuf, decay, kbuf, vout, awb, bwb, obuf);
  // GN + bonus + gate
  k6_out<<<Mm, 256, 0, stream>>>(obuf, rbuf, kbuf, vout, rkv, gnw, gnb, gout, og);
  // o-projection + residual -> x2 (128x64: 512 blocks = 2/CU)
  kg_gemm64<7><<<dim3(16, 32), 256, 0, stream>>>(og, WoT, Mm, 1024, 1024, x2, nullptr, nullptr, xln);
  // FFN
  k8_ffnmix<<<Mm, 256, 0, stream>>>(x2, lnfw, lnfb, fxk, kf);
  kg_gemm2<4><<<dim3(32, 32), 256, 0, stream>>>(kf, Wf1T, Mm, 4096, 1024, nullptr, hbuf, nullptr, nullptr);
  kg_gemm64<7><<<dim3(16, 32), 256, 0, stream>>>(hbuf, Wf2T, Mm, 1024, 4096, outx, nullptr, nullptr, x2);
}

// Round 7
// 580.581 us; speedup vs baseline: 1.2011x; 1.0089x over previous
//
#include <hip/hip_runtime.h>

// ---------------- constants ----------------
#define Bb 8
#define Tt 512
#define Cc 1024
#define Hh 16
#define Nh 64
#define Mm 4096            // B*T
#define BTC 4194304        // M*C
#define DEV __device__ __forceinline__

typedef __attribute__((ext_vector_type(8))) short short8;
typedef __attribute__((ext_vector_type(4))) float f32x4;

DEV unsigned short f2bf(float f) {
  unsigned int u = __builtin_bit_cast(unsigned int, f);
  u += 0x7fffu + ((u >> 16) & 1u);
  return (unsigned short)(u >> 16);
}

// DPP butterfly add — pure VALU. 0xB1=quad xor1, 0x4E=quad xor2,
// 0x124=row_ror:4, 0x128=row_ror:8 (within 16-lane DPP row).
template <int CTRL>
DEV float dppadd(float x) {
  int xi = __builtin_bit_cast(int, x);
  int yi = __builtin_amdgcn_update_dpp(0, xi, CTRL, 0xF, 0xF, true);
  return x + __builtin_bit_cast(float, yi);
}

// ---------------- merged transpose f32 (K x N) -> bf16 (N x K) ----------------
struct TDesc { const float* in; unsigned short* out; int K, N, bstart, nbx; };
struct TPack { TDesc d[12]; };

__global__ __launch_bounds__(256) void kt_transpose_multi(TPack p) {
  __shared__ float tile[32][33];
  const int bid = blockIdx.x;
  int i = 0;
  #pragma unroll
  for (int j = 1; j < 12; ++j) if (bid >= p.d[j].bstart) i = j;
  const float* in = p.d[i].in;
  unsigned short* out = p.d[i].out;
  const int K = p.d[i].K, N = p.d[i].N;
  const int local = bid - p.d[i].bstart;
  const int byq = local / p.d[i].nbx;
  const int bx = (local - byq * p.d[i].nbx) * 32;
  const int by = byq * 32;
  int tx = threadIdx.x, ty = threadIdx.y;
  #pragma unroll
  for (int q = ty; q < 32; q += 8) {
    int kk = by + q, nn = bx + tx;
    tile[q][tx] = (kk < K && nn < N) ? in[(size_t)kk * N + nn] : 0.f;
  }
  __syncthreads();
  #pragma unroll
  for (int q = ty; q < 32; q += 8) {
    int nn = bx + q, kk = by + tx;
    if (nn < N && kk < K) out[(size_t)nn * K + kk] = f2bf(tile[tx][q]);
  }
}

// ---------------- block row stats (1024 elems over 256 threads) ----------------
DEV void row_stats(float v0, float v1, float v2, float v3, float* red,
                   float& mu, float& rs, float eps) {
  float s = v0 + v1 + v2 + v3;
  float q = v0 * v0 + v1 * v1 + v2 * v2 + v3 * v3;
  #pragma unroll
  for (int o = 32; o; o >>= 1) { s += __shfl_down(s, o); q += __shfl_down(q, o); }
  int w = threadIdx.x >> 6;
  __syncthreads();
  if ((threadIdx.x & 63) == 0) { red[w] = s; red[4 + w] = q; }
  __syncthreads();
  s = red[0] + red[1] + red[2] + red[3];
  q = red[4] + red[5] + red[6] + red[7];
  mu = s * (1.f / 1024.f);
  float var = q * (1.f / 1024.f) - mu * mu;
  rs = rsqrtf(var + eps);
}

// ---------------- K1: pre-LN + attn-LN + time-shift mixes ----------------
__global__ __launch_bounds__(256) void k1_mix(
    const float* __restrict__ x,
    const float* __restrict__ lnpw, const float* __restrict__ lnpb,
    const float* __restrict__ lnaw, const float* __restrict__ lnab,
    const float* __restrict__ cr, const float* __restrict__ cw,
    const float* __restrict__ ck, const float* __restrict__ cv,
    const float* __restrict__ ca, const float* __restrict__ cg,
    float* __restrict__ xln,
    unsigned short* __restrict__ mR, unsigned short* __restrict__ mW,
    unsigned short* __restrict__ mK, unsigned short* __restrict__ mV,
    unsigned short* __restrict__ mA, unsigned short* __restrict__ mG) {
  __shared__ float red[8];
  const int row = blockIdx.x;
  const int t = row & (Tt - 1);
  const int tid = threadIdx.x;
  const int c = tid * 4;
  const size_t base = (size_t)row * Cc + c;
  float a0 = x[base], a1 = x[base + 1], a2 = x[base + 2], a3 = x[base + 3];
  float mu, rs;
  row_stats(a0, a1, a2, a3, red, mu, rs, 1e-5f);
  float pw0 = lnpw[c], pw1 = lnpw[c + 1], pw2 = lnpw[c + 2], pw3 = lnpw[c + 3];
  float pb0 = lnpb[c], pb1 = lnpb[c + 1], pb2 = lnpb[c + 2], pb3 = lnpb[c + 3];
  float l0 = (a0 - mu) * rs * pw0 + pb0, l1 = (a1 - mu) * rs * pw1 + pb1;
  float l2 = (a2 - mu) * rs * pw2 + pb2, l3 = (a3 - mu) * rs * pw3 + pb3;
  float4 st; st.x = l0; st.y = l1; st.z = l2; st.w = l3;
  *(float4*)(xln + base) = st;
  row_stats(l0, l1, l2, l3, red, mu, rs, 1e-5f);
  float aw0 = lnaw[c], aw1 = lnaw[c + 1], aw2 = lnaw[c + 2], aw3 = lnaw[c + 3];
  float ab0 = lnab[c], ab1 = lnab[c + 1], ab2 = lnab[c + 2], ab3 = lnab[c + 3];
  float n0 = (l0 - mu) * rs * aw0 + ab0, n1 = (l1 - mu) * rs * aw1 + ab1;
  float n2 = (l2 - mu) * rs * aw2 + ab2, n3 = (l3 - mu) * rs * aw3 + ab3;
  float p0 = 0.f, p1 = 0.f, p2 = 0.f, p3 = 0.f;
  if (t > 0) {  // uniform over block
    const size_t pb_ = base - Cc;
    float q0 = x[pb_], q1 = x[pb_ + 1], q2 = x[pb_ + 2], q3 = x[pb_ + 3];
    row_stats(q0, q1, q2, q3, red, mu, rs, 1e-5f);
    float e0 = (q0 - mu) * rs * pw0 + pb0, e1 = (q1 - mu) * rs * pw1 + pb1;
    float e2 = (q2 - mu) * rs * pw2 + pb2, e3 = (q3 - mu) * rs * pw3 + pb3;
    row_stats(e0, e1, e2, e3, red, mu, rs, 1e-5f);
    p0 = (e0 - mu) * rs * aw0 + ab0; p1 = (e1 - mu) * rs * aw1 + ab1;
    p2 = (e2 - mu) * rs * aw2 + ab2; p3 = (e3 - mu) * rs * aw3 + ab3;
  }
  float d0 = p0 - n0, d1 = p1 - n1, d2 = p2 - n2, d3 = p3 - n3;
  #define EMIT(cf, dst) { \
    float f0 = cf[c], f1 = cf[c + 1], f2 = cf[c + 2], f3 = cf[c + 3]; \
    ushort4 u; u.x = f2bf(n0 + d0 * f0); u.y = f2bf(n1 + d1 * f1); \
    u.z = f2bf(n2 + d2 * f2); u.w = f2bf(n3 + d3 * f3); \
    *(ushort4*)(dst + base) = u; }
  EMIT(cr, mR) EMIT(cw, mW) EMIT(ck, mK) EMIT(cv, mV) EMIT(ca, mA) EMIT(cg, mG)
  #undef EMIT
}

// ---------------- bf16 MFMA GEMM bodies ----------------
// A: (M,K) bf16 row-major; Bt: (N,K) bf16 row-major.
// MODE: 0 f32 | 1 bf16 | 2 tanh->bf16 | 3 sigmoid->bf16 | 4 relu^2->bf16
//       5 sigmoid(z+bias[col])->f32 | 6 exp(-sigmoid(z+bias[col])*e^-.5)->f32 | 7 z+res->f32
DEV void gll16(const unsigned short* g, unsigned short* l) {
  __builtin_amdgcn_global_load_lds(
      (const __attribute__((address_space(1))) void*)g,
      (__attribute__((address_space(3))) void*)l, 16, 0, 0);
}

template <int MODE>
DEV void gemm_epi(float z, size_t oi, int col,
                  float* outF, unsigned short* outB,
                  const float* bias, const float* res) {
  if constexpr (MODE == 0) outF[oi] = z;
  else if constexpr (MODE == 1) outB[oi] = f2bf(z);
  else if constexpr (MODE == 2) outB[oi] = f2bf(tanhf(z));
  else if constexpr (MODE == 3) outB[oi] = f2bf(1.f / (1.f + expf(-z)));
  else if constexpr (MODE == 4) { float m = fmaxf(z, 0.f); outB[oi] = f2bf(m * m); }
  else if constexpr (MODE == 5) { z += bias[col]; outF[oi] = 1.f / (1.f + expf(-z)); }
  else if constexpr (MODE == 6) {
    z += bias[col];
    float sg = 1.f / (1.f + expf(-z));
    outF[oi] = expf(-0.6065306597126334f * sg);
  } else { outF[oi] = z + res[oi]; }
}

// runtime-mode epilogue for z-batched LoRA kernels (modes 0,1,2,3,5,6)
DEV void gemm_epi_rt(int mode, float z, size_t oi, int col,
                     float* outF, unsigned short* outB, const float* bias) {
  if (mode == 0) outF[oi] = z;
  else if (mode == 1) outB[oi] = f2bf(z);
  else if (mode == 2) outB[oi] = f2bf(tanhf(z));
  else if (mode == 3) outB[oi] = f2bf(1.f / (1.f + expf(-z)));
  else if (mode == 5) { z += bias[col]; outF[oi] = 1.f / (1.f + expf(-z)); }
  else { z += bias[col]; float sg = 1.f / (1.f + expf(-z));
         outF[oi] = expf(-0.6065306597126334f * sg); }
}

// ---- 128M x 64N tile, compile-time MODE (Wo: 512 blocks = 2/CU) ----
template <int MODE>
__global__ __launch_bounds__(256) void kg_gemm64(
    const unsigned short* __restrict__ A, const unsigned short* __restrict__ Bt,
    int M, int Nn, int K,
    float* __restrict__ outF, unsigned short* __restrict__ outB,
    const float* __restrict__ bias, const float* __restrict__ res) {
  __shared__ unsigned short lsA[128 * 32];
  __shared__ unsigned short lsB[64 * 32];
  const int tid = threadIdx.x;
  const int lane = tid & 63;
  const int wave = tid >> 6;
  const int wy = wave >> 1, wx = wave & 1;
  const int m0 = blockIdx.y * 128;
  const int n0 = blockIdx.x * 64;
  const int sl4 = lane >> 2;
  const int sc = (lane & 3) << 3;
  f32x4 acc[4][2];
  #pragma unroll
  for (int i = 0; i < 4; ++i)
    #pragma unroll
    for (int j = 0; j < 2; ++j) { f32x4 z = {0.f, 0.f, 0.f, 0.f}; acc[i][j] = z; }
  const int fr = lane & 15;
  const int fk = (lane >> 4) << 3;
  for (int k0 = 0; k0 < K; k0 += 32) {
    #pragma unroll
    for (int j = 0; j < 2; ++j) {
      const int rb = (wave + j * 4) * 16;
      gll16(A + (size_t)(m0 + rb + sl4) * K + k0 + sc, lsA + rb * 32);
    }
    {
      const int rb = wave * 16;
      int br = n0 + rb + sl4;
      br = br < Nn ? br : Nn - 1;
      gll16(Bt + (size_t)br * K + k0 + sc, lsB + rb * 32);
    }
    __syncthreads();
    short8 af[4], bf[2];
    #pragma unroll
    for (int mt = 0; mt < 4; ++mt)
      af[mt] = *(const short8*)(lsA + (wy * 64 + mt * 16 + fr) * 32 + fk);
    #pragma unroll
    for (int nt = 0; nt < 2; ++nt)
      bf[nt] = *(const short8*)(lsB + (wx * 32 + nt * 16 + fr) * 32 + fk);
    #pragma unroll
    for (int mt = 0; mt < 4; ++mt)
      #pragma unroll
      for (int nt = 0; nt < 2; ++nt)
        acc[mt][nt] = __builtin_amdgcn_mfma_f32_16x16x32_bf16(af[mt], bf[nt], acc[mt][nt], 0, 0, 0);
    __syncthreads();
  }
  const int rbase = (lane >> 4) << 2;
  const int cbase = lane & 15;
  #pragma unroll
  for (int mt = 0; mt < 4; ++mt)
    #pragma unroll
    for (int nt = 0; nt < 2; ++nt)
      #pragma unroll
      for (int rr = 0; rr < 4; ++rr) {
        int row = m0 + wy * 64 + mt * 16 + rbase + rr;
        int col = n0 + wx * 32 + nt * 16 + cbase;
        if (col < Nn)
          gemm_epi<MODE>(acc[mt][nt][rr], (size_t)row * Nn + col, col, outF, outB, bias, res);
      }
}

// 128M x 64N tile body, runtime mode (for z-batched small GEMMs)
DEV void gemm_body_rt(const unsigned short* A, const unsigned short* Bt,
                      int Nn, int K,
                      float* outF, unsigned short* outB, const float* bias,
                      unsigned short* lsA, unsigned short* lsB,
                      int m0, int n0, int mode) {
  const int tid = threadIdx.x;
  const int lane = tid & 63;
  const int wave = tid >> 6;
  const int wy = wave >> 1, wx = wave & 1;
  const int sl4 = lane >> 2;
  const int sc = (lane & 3) << 3;
  f32x4 acc[4][2];
  #pragma unroll
  for (int i = 0; i < 4; ++i)
    #pragma unroll
    for (int j = 0; j < 2; ++j) { f32x4 z = {0.f, 0.f, 0.f, 0.f}; acc[i][j] = z; }
  const int fr = lane & 15;
  const int fk = (lane >> 4) << 3;
  for (int k0 = 0; k0 < K; k0 += 32) {
    #pragma unroll
    for (int j = 0; j < 2; ++j) {
      const int rb = (wave + j * 4) * 16;
      gll16(A + (size_t)(m0 + rb + sl4) * K + k0 + sc, lsA + rb * 32);
    }
    {
      const int rb = wave * 16;
      int br = n0 + rb + sl4;
      br = br < Nn ? br : Nn - 1;
      gll16(Bt + (size_t)br * K + k0 + sc, lsB + rb * 32);
    }
    __syncthreads();
    short8 af[4], bf[2];
    #pragma unroll
    for (int mt = 0; mt < 4; ++mt)
      af[mt] = *(const short8*)(lsA + (wy * 64 + mt * 16 + fr) * 32 + fk);
    #pragma unroll
    for (int nt = 0; nt < 2; ++nt)
      bf[nt] = *(const short8*)(lsB + (wx * 32 + nt * 16 + fr) * 32 + fk);
    #pragma unroll
    for (int mt = 0; mt < 4; ++mt)
      #pragma unroll
      for (int nt = 0; nt < 2; ++nt)
        acc[mt][nt] = __builtin_amdgcn_mfma_f32_16x16x32_bf16(af[mt], bf[nt], acc[mt][nt], 0, 0, 0);
    __syncthreads();
  }
  const int rbase = (lane >> 4) << 2;
  const int cbase = lane & 15;
  #pragma unroll
  for (int mt = 0; mt < 4; ++mt)
    #pragma unroll
    for (int nt = 0; nt < 2; ++nt)
      #pragma unroll
      for (int rr = 0; rr < 4; ++rr) {
        int row = m0 + wy * 64 + mt * 16 + rbase + rr;
        int col = n0 + wx * 32 + nt * 16 + cbase;
        if (col < Nn)
          gemm_epi_rt(mode, acc[mt][nt][rr], (size_t)row * Nn + col, col, outF, outB, bias);
      }
}

// stage-1 LoRA batch: z=0 w1(tanh), z=1 a1(plain), z=2/3 g1(sigmoid) cols 0-63/64-127
__global__ __launch_bounds__(256) void kg_lora1(
    const unsigned short* __restrict__ mW, const unsigned short* __restrict__ mA,
    const unsigned short* __restrict__ mG,
    const unsigned short* __restrict__ w1T, const unsigned short* __restrict__ a1T,
    const unsigned short* __restrict__ g1T,
    unsigned short* __restrict__ tmpw, unsigned short* __restrict__ tmpa,
    unsigned short* __restrict__ tmpg) {
  __shared__ unsigned short lsA[128 * 32];
  __shared__ unsigned short lsB[64 * 32];
  const int z = blockIdx.z;
  const unsigned short* A  = z == 0 ? mW : z == 1 ? mA : mG;
  const unsigned short* Bt = z == 0 ? w1T : z == 1 ? a1T : g1T;
  unsigned short* outB     = z == 0 ? tmpw : z == 1 ? tmpa : tmpg;
  const int Nn = z < 2 ? 64 : 128;
  const int n0 = z < 2 ? 0 : (z - 2) * 64;
  const int mode = z == 0 ? 2 : z == 1 ? 1 : 3;
  gemm_body_rt(A, Bt, Nn, 1024, nullptr, outB, nullptr, lsA, lsB,
               blockIdx.y * 128, n0, mode);
}

// stage-2 LoRA batch: z=0 decay(mode6,K=64), z=1 aicl(mode5,K=64), z=2 gout(mode0,K=128)
__global__ __launch_bounds__(256) void kg_lora2(
    const unsigned short* __restrict__ tmpw, const unsigned short* __restrict__ tmpa,
    const unsigned short* __restrict__ tmpg,
    const unsigned short* __restrict__ w2T, const unsigned short* __restrict__ a2T,
    const unsigned short* __restrict__ g2T,
    float* __restrict__ decay, float* __restrict__ aicl, float* __restrict__ gout,
    const float* __restrict__ w0v, const float* __restrict__ a0v) {
  __shared__ unsigned short lsA[128 * 32];
  __shared__ unsigned short lsB[64 * 32];
  const int z = blockIdx.z;
  const unsigned short* A  = z == 0 ? tmpw : z == 1 ? tmpa : tmpg;
  const unsigned short* Bt = z == 0 ? w2T : z == 1 ? a2T : g2T;
  float* outF              = z == 0 ? decay : z == 1 ? aicl : gout;
  const float* bias        = z == 0 ? w0v : z == 1 ? a0v : nullptr;
  const int K = z < 2 ? 64 : 128;
  const int mode = z == 0 ? 6 : z == 1 ? 5 : 0;
  gemm_body_rt(A, Bt, 1024, K, outF, nullptr, bias, lsA, lsB,
               blockIdx.y * 128, blockIdx.x * 64, mode);
}

// 128M x 128N tile body (exact m97 structure)
template <int MODE>
DEV void gemm2_body(const unsigned short* A, const unsigned short* Bt,
                    int Nn, int K,
                    float* outF, unsigned short* outB,
                    const float* bias, const float* res,
                    unsigned short* lsA, unsigned short* lsB,
                    int m0, int n0) {
  const int tid = threadIdx.x;
  const int lane = tid & 63;
  const int wave = tid >> 6;
  const int wy = wave >> 1, wx = wave & 1;
  const int sl4 = lane >> 2;
  const int sc = (lane & 3) << 3;
  f32x4 acc[4][4];
  #pragma unroll
  for (int i = 0; i < 4; ++i)
    #pragma unroll
    for (int j = 0; j < 4; ++j) { f32x4 z = {0.f, 0.f, 0.f, 0.f}; acc[i][j] = z; }
  const int fr = lane & 15;
  const int fk = (lane >> 4) << 3;
  for (int k0 = 0; k0 < K; k0 += 32) {
    #pragma unroll
    for (int j = 0; j < 2; ++j) {
      const int rb = (wave + j * 4) * 16;
      gll16(A + (size_t)(m0 + rb + sl4) * K + k0 + sc, lsA + rb * 32);
      int br = n0 + rb + sl4;
      br = br < Nn ? br : Nn - 1;
      gll16(Bt + (size_t)br * K + k0 + sc, lsB + rb * 32);
    }
    __syncthreads();
    short8 af[4], bf[4];
    #pragma unroll
    for (int mt = 0; mt < 4; ++mt)
      af[mt] = *(const short8*)(lsA + (wy * 64 + mt * 16 + fr) * 32 + fk);
    #pragma unroll
    for (int nt = 0; nt < 4; ++nt)
      bf[nt] = *(const short8*)(lsB + (wx * 64 + nt * 16 + fr) * 32 + fk);
    #pragma unroll
    for (int mt = 0; mt < 4; ++mt)
      #pragma unroll
      for (int nt = 0; nt < 4; ++nt)
        acc[mt][nt] = __builtin_amdgcn_mfma_f32_16x16x32_bf16(af[mt], bf[nt], acc[mt][nt], 0, 0, 0);
    __syncthreads();
  }
  const int rbase = (lane >> 4) << 2;
  const int cbase = lane & 15;
  #pragma unroll
  for (int mt = 0; mt < 4; ++mt)
    #pragma unroll
    for (int nt = 0; nt < 4; ++nt)
      #pragma unroll
      for (int rr = 0; rr < 4; ++rr) {
        int row = m0 + wy * 64 + mt * 16 + rbase + rr;
        int col = n0 + wx * 64 + nt * 16 + cbase;
        if (col < Nn)
          gemm_epi<MODE>(acc[mt][nt][rr], (size_t)row * Nn + col, col, outF, outB, bias, res);
      }
}

template <int MODE>
__global__ __launch_bounds__(256) void kg_gemm2(
    const unsigned short* __restrict__ A, const unsigned short* __restrict__ Bt,
    int M, int Nn, int K,
    float* __restrict__ outF, unsigned short* __restrict__ outB,
    const float* __restrict__ bias, const float* __restrict__ res) {
  __shared__ unsigned short lsA[128 * 32];
  __shared__ unsigned short lsB[128 * 32];
  gemm2_body<MODE>(A, Bt, Nn, K, outF, outB, bias, res, lsA, lsB,
                   blockIdx.y * 128, blockIdx.x * 128);
}

// ---- FFN2 split-K: 128x128 tile, z = K-half. N=1024 at 128^2 alone would be
// 256 blocks = 1/CU (drain pathology, R5); split-K z=2 gives 512 blocks = 2/CU
// at the measured-optimal tile (m103: 128^2 = 912 TF vs 128x64-class lower).
// Each z accumulates K/2 into its own f32 partial; k9_add sums + residual.
__global__ __launch_bounds__(256) void kg_ffn2_sk(
    const unsigned short* __restrict__ A, const unsigned short* __restrict__ Bt,
    float* __restrict__ p0, float* __restrict__ p1) {
  __shared__ unsigned short lsA[128 * 32];
  __shared__ unsigned short lsB[128 * 32];
  const int Kstride = 4096, Klen = 2048;
  const int kbase = blockIdx.z * Klen;
  float* outF = blockIdx.z == 0 ? p0 : p1;
  const int tid = threadIdx.x;
  const int lane = tid & 63;
  const int wave = tid >> 6;
  const int wy = wave >> 1, wx = wave & 1;
  const int m0 = blockIdx.y * 128;
  const int n0 = blockIdx.x * 128;
  const int sl4 = lane >> 2;
  const int sc = (lane & 3) << 3;
  f32x4 acc[4][4];
  #pragma unroll
  for (int i = 0; i < 4; ++i)
    #pragma unroll
    for (int j = 0; j < 4; ++j) { f32x4 z = {0.f, 0.f, 0.f, 0.f}; acc[i][j] = z; }
  const int fr = lane & 15;
  const int fk = (lane >> 4) << 3;
  for (int k0 = kbase; k0 < kbase + Klen; k0 += 32) {
    #pragma unroll
    for (int j = 0; j < 2; ++j) {
      const int rb = (wave + j * 4) * 16;
      gll16(A + (size_t)(m0 + rb + sl4) * Kstride + k0 + sc, lsA + rb * 32);
      gll16(Bt + (size_t)(n0 + rb + sl4) * Kstride + k0 + sc, lsB + rb * 32);
    }
    __syncthreads();
    short8 af[4], bf[4];
    #pragma unroll
    for (int mt = 0; mt < 4; ++mt)
      af[mt] = *(const short8*)(lsA + (wy * 64 + mt * 16 + fr) * 32 + fk);
    #pragma unroll
    for (int nt = 0; nt < 4; ++nt)
      bf[nt] = *(const short8*)(lsB + (wx * 64 + nt * 16 + fr) * 32 + fk);
    #pragma unroll
    for (int mt = 0; mt < 4; ++mt)
      #pragma unroll
      for (int nt = 0; nt < 4; ++nt)
        acc[mt][nt] = __builtin_amdgcn_mfma_f32_16x16x32_bf16(af[mt], bf[nt], acc[mt][nt], 0, 0, 0);
    __syncthreads();
  }
  const int rbase = (lane >> 4) << 2;
  const int cbase = lane & 15;
  #pragma unroll
  for (int mt = 0; mt < 4; ++mt)
    #pragma unroll
    for (int nt = 0; nt < 4; ++nt)
      #pragma unroll
      for (int rr = 0; rr < 4; ++rr) {
        int row = m0 + wy * 64 + mt * 16 + rbase + rr;
        int col = n0 + wx * 64 + nt * 16 + cbase;
        outF[(size_t)row * Cc + col] = acc[mt][nt][rr];
      }
}

// final: outx = p0 + p1 + x2
__global__ __launch_bounds__(256) void k9_add(
    const float* __restrict__ p0, const float* __restrict__ p1,
    const float* __restrict__ x2, float* __restrict__ outx) {
  const size_t i = ((size_t)blockIdx.x * 256 + threadIdx.x) * 4;
  float4 a = *(const float4*)(p0 + i);
  float4 b = *(const float4*)(p1 + i);
  float4 c = *(const float4*)(x2 + i);
  float4 o;
  o.x = a.x + b.x + c.x; o.y = a.y + b.y + c.y;
  o.z = a.z + b.z + c.z; o.w = a.w + b.w + c.w;
  *(float4*)(outx + i) = o;
}

// ---------------- QKV projections + fused K4 (z selects r/k/v) ----------------
// 128x128 tile, grid (8,32,3)=768 blocks (3/CU). z==1 (k-projection) fuses the
// old k4_prep: per-(row,head) kk-norm via 4 FMAs + 4-DPP 16-lane sum, no LDS.
__global__ __launch_bounds__(256) void kg_qkv_fused(
    const unsigned short* __restrict__ A0, const unsigned short* __restrict__ A1,
    const unsigned short* __restrict__ A2,
    const unsigned short* __restrict__ B0, const unsigned short* __restrict__ B1,
    const unsigned short* __restrict__ B2,
    float* __restrict__ rbuf, float* __restrict__ kbuf, float* __restrict__ vout,
    const float* __restrict__ aicl,
    const float* __restrict__ kkc, const float* __restrict__ kac,
    float* __restrict__ awb, float* __restrict__ bwb) {
  __shared__ unsigned short lsA[128 * 32];
  __shared__ unsigned short lsB[128 * 32];
  const int z = blockIdx.z;
  const unsigned short* A = z == 0 ? A0 : z == 1 ? A1 : A2;
  const unsigned short* Bt = z == 0 ? B0 : z == 1 ? B1 : B2;
  const int tid = threadIdx.x;
  const int lane = tid & 63;
  const int wave = tid >> 6;
  const int wy = wave >> 1, wx = wave & 1;
  const int m0 = blockIdx.y * 128;
  const int n0 = blockIdx.x * 128;
  const int sl4 = lane >> 2;
  const int sc = (lane & 3) << 3;
  f32x4 acc[4][4];
  #pragma unroll
  for (int i = 0; i < 4; ++i)
    #pragma unroll
    for (int j = 0; j < 4; ++j) { f32x4 zz = {0.f, 0.f, 0.f, 0.f}; acc[i][j] = zz; }
  const int fr = lane & 15;
  const int fk = (lane >> 4) << 3;
  for (int k0 = 0; k0 < 1024; k0 += 32) {
    #pragma unroll
    for (int j = 0; j < 2; ++j) {
      const int rb = (wave + j * 4) * 16;
      gll16(A + (size_t)(m0 + rb + sl4) * 1024 + k0 + sc, lsA + rb * 32);
      gll16(Bt + (size_t)(n0 + rb + sl4) * 1024 + k0 + sc, lsB + rb * 32);
    }
    __syncthreads();
    short8 af[4], bf[4];
    #pragma unroll
    for (int mt = 0; mt < 4; ++mt)
      af[mt] = *(const short8*)(lsA + (wy * 64 + mt * 16 + fr) * 32 + fk);
    #pragma unroll
    for (int nt = 0; nt < 4; ++nt)
      bf[nt] = *(const short8*)(lsB + (wx * 64 + nt * 16 + fr) * 32 + fk);
    #pragma unroll
    for (int mt = 0; mt < 4; ++mt)
      #pragma unroll
      for (int nt = 0; nt < 4; ++nt)
        acc[mt][nt] = __builtin_amdgcn_mfma_f32_16x16x32_bf16(af[mt], bf[nt], acc[mt][nt], 0, 0, 0);
    __syncthreads();
  }
  const int rbase = (lane >> 4) << 2;
  const int cbase = lane & 15;
  if (z != 1) {
    float* outF = z == 0 ? rbuf : vout;
    #pragma unroll
    for (int mt = 0; mt < 4; ++mt)
      #pragma unroll
      for (int nt = 0; nt < 4; ++nt)
        #pragma unroll
        for (int rr = 0; rr < 4; ++rr) {
          int row = m0 + wy * 64 + mt * 16 + rbase + rr;
          int col = n0 + wx * 64 + nt * 16 + cbase;
          outF[(size_t)row * Cc + col] = acc[mt][nt][rr];
        }
  } else {
    // fused k4: per-(row,head) kk-normalize + a/b vectors + k update
    float kkc4[4], kac4[4];
    #pragma unroll
    for (int nt = 0; nt < 4; ++nt) {
      int col = n0 + wx * 64 + nt * 16 + cbase;
      kkc4[nt] = kkc[col];
      kac4[nt] = kac[col];
    }
    #pragma unroll
    for (int mt = 0; mt < 4; ++mt)
      #pragma unroll
      for (int rr = 0; rr < 4; ++rr) {
        int row = m0 + wy * 64 + mt * 16 + rbase + rr;
        float h0 = acc[mt][0][rr] * kkc4[0];
        float h1 = acc[mt][1][rr] * kkc4[1];
        float h2 = acc[mt][2][rr] * kkc4[2];
        float h3 = acc[mt][3][rr] * kkc4[3];
        float ss = (h0 * h0 + h1 * h1) + (h2 * h2 + h3 * h3);
        ss = dppadd<0xB1>(ss);
        ss = dppadd<0x4E>(ss);
        ss = dppadd<0x124>(ss);
        ss = dppadd<0x128>(ss);
        float inv = 1.f / fmaxf(sqrtf(ss), 1e-12f);
        #pragma unroll
        for (int nt = 0; nt < 4; ++nt) {
          int col = n0 + wx * 64 + nt * 16 + cbase;
          size_t oi = (size_t)row * Cc + col;
          float kv = acc[mt][nt][rr];
          float hn = kv * kkc4[nt] * inv;
          float av = aicl[oi];
          awb[oi] = -hn;
          bwb[oi] = hn * av;
          kbuf[oi] = kv * (1.f + (av - 1.f) * kac4[nt]);
        }
      }
  }
}

// ---------------- K5: WKV7 — R2-proven: 8-wave blocks, shared staging ----------------
// 256 blocks = (half, bh) x 512 threads (8 waves); wave w owns rows
// half*32 + w*4 .. +3. Lane = (rw = lane>>4, cg = lane&15), S[4];
// 16-lane reduce = 4 serial DPPs. CS=8 double buffer, one barrier/chunk.
// Measured 114.6-116.1us across R2/R5/R6.
#define CS 8
__global__ __launch_bounds__(512, 2) void k5_wkv7(
    const float* __restrict__ r, const float* __restrict__ dec,
    const float* __restrict__ k, const float* __restrict__ v,
    const float* __restrict__ aw, const float* __restrict__ bw,
    float* __restrict__ o) {
  const int blk = blockIdx.x;              // 0..255
  const int bh = blk & 127, half = blk >> 7;
  const int b = bh >> 4, h = bh & 15;
  const int tid = threadIdx.x;
  const int lane = tid & 63;
  const int w = tid >> 6;                  // wave 0..7
  const int cg = lane & 15;                // column group (4 cols)
  const int rw = lane >> 4;                // row within wave's 4
  const int row = half * 32 + w * 4 + rw;  // state row i (0..63)
  const int cb = cg << 2;                  // column base j0

  __shared__ float buf[2][6 * CS * 64];    // 2 x 12 KB

  float S[4];
  #pragma unroll
  for (int j = 0; j < 4; ++j) S[j] = 0.f;

  const size_t base = (size_t)b * Tt * Cc + (size_t)h * Nh;

  const float* sptr = w == 0 ? aw : w == 1 ? dec : w == 2 ? bw
                    : w == 3 ? k  : w == 4 ? r   : v;
  const int srow = lane >> 4;              // t-offset within chunk (0..3)
  const int scol = (lane & 15) << 2;       // col (0..60 step 4)

  uint4 R0, R1;
  #define LOADC(cstart) if (w < 6) { \
    const size_t g0 = base + (size_t)((cstart) + srow) * Cc + scol; \
    R0 = *(const uint4*)(sptr + g0); \
    R1 = *(const uint4*)(sptr + g0 + 4 * Cc); }

  LOADC(0)

  #pragma unroll 1
  for (int c = 0; c < Tt / CS; ++c) {
    float* bp = buf[c & 1];
    if (w < 6) {
      *(uint4*)(bp + w * 512 + (lane << 2)) = R0;        // t 0..3
      *(uint4*)(bp + w * 512 + 256 + (lane << 2)) = R1;  // t 4..7
    }
    const int cn = (c + 1 < Tt / CS) ? (c + 1) : c;
    LOADC(cn * CS)
    __syncthreads();

    float4 Aq[2], Dq[2], Bq[2], Kq[2], Rq[2];
    float Vv[2];
    #define LOADOPS(slot, ss) { \
      const float* sp_ = bp + (ss) * 64; \
      Aq[slot] = *(const float4*)(sp_ + cb); \
      Dq[slot] = *(const float4*)(sp_ + 512 + cb); \
      Bq[slot] = *(const float4*)(sp_ + 1024 + cb); \
      Kq[slot] = *(const float4*)(sp_ + 1536 + cb); \
      Rq[slot] = *(const float4*)(sp_ + 2048 + cb); \
      Vv[slot] = sp_[2560 + row]; }

    LOADOPS(0, 0)
    #pragma unroll
    for (int s = 0; s < CS; ++s) {
      const int cu = s & 1, nx = cu ^ 1;
      if (s + 1 < CS) LOADOPS(nx, s + 1)     // prefetch next step's operands

      float4 a4 = Aq[cu];
      float sa = fmaf(S[1], a4.y, S[0] * a4.x) + fmaf(S[3], a4.w, S[2] * a4.z);
      sa = dppadd<0xB1>(sa);
      sa = dppadd<0x4E>(sa);
      sa = dppadd<0x124>(sa);
      sa = dppadd<0x128>(sa);

      const float vv = Vv[cu];
      float4 d4 = Dq[cu], b4 = Bq[cu], k4 = Kq[cu], r4 = Rq[cu];
      S[0] = fmaf(S[0], d4.x, fmaf(vv, k4.x, sa * b4.x));
      float oo = S[0] * r4.x;
      S[1] = fmaf(S[1], d4.y, fmaf(vv, k4.y, sa * b4.y));
      oo = fmaf(S[1], r4.y, oo);
      S[2] = fmaf(S[2], d4.z, fmaf(vv, k4.z, sa * b4.z));
      oo = fmaf(S[2], r4.z, oo);
      S[3] = fmaf(S[3], d4.w, fmaf(vv, k4.w, sa * b4.w));
      oo = fmaf(S[3], r4.w, oo);

      oo = dppadd<0xB1>(oo);
      oo = dppadd<0x4E>(oo);
      oo = dppadd<0x124>(oo);
      oo = dppadd<0x128>(oo);
      if (cg == 0) o[base + (size_t)(c * CS + s) * Cc + row] = oo;
    }
    #undef LOADOPS
  }
  #undef LOADC
}

// ---------------- K6: head GroupNorm + rk bonus + gate ----------------
__global__ __launch_bounds__(256) void k6_out(
    const float* __restrict__ o, const float* __restrict__ r, const float* __restrict__ k,
    const float* __restrict__ v, const float* __restrict__ rk,
    const float* __restrict__ gnw, const float* __restrict__ gnb,
    const float* __restrict__ g, unsigned short* __restrict__ og) {
  const int row = blockIdx.x, tid = threadIdx.x;
  const int c = tid * 4;
  const size_t base = (size_t)row * Cc + c;
  float o0 = o[base], o1 = o[base + 1], o2 = o[base + 2], o3 = o[base + 3];
  float r0 = r[base], r1 = r[base + 1], r2 = r[base + 2], r3 = r[base + 3];
  float k0 = k[base], k1 = k[base + 1], k2 = k[base + 2], k3 = k[base + 3];
  float s = o0 + o1 + o2 + o3;
  float q = o0 * o0 + o1 * o1 + o2 * o2 + o3 * o3;
  float bs = r0 * k0 * rk[c] + r1 * k1 * rk[c + 1] + r2 * k2 * rk[c + 2] + r3 * k3 * rk[c + 3];
  #pragma unroll
  for (int m = 8; m; m >>= 1) {
    s += __shfl_xor(s, m); q += __shfl_xor(q, m); bs += __shfl_xor(bs, m);
  }
  float mu = s * (1.f / 64.f);
  float var = q * (1.f / 64.f) - mu * mu;
  float rs = rsqrtf(var + 64e-5f);
  float v0 = v[base], v1 = v[base + 1], v2 = v[base + 2], v3 = v[base + 3];
  float z0 = (o0 - mu) * rs * gnw[c] + gnb[c] + bs * v0;
  float z1 = (o1 - mu) * rs * gnw[c + 1] + gnb[c + 1] + bs * v1;
  float z2 = (o2 - mu) * rs * gnw[c + 2] + gnb[c + 2] + bs * v2;
  float z3 = (o3 - mu) * rs * gnw[c + 3] + gnb[c + 3] + bs * v3;
  ushort4 u;
  u.x = f2bf(z0 * g[base]); u.y = f2bf(z1 * g[base + 1]);
  u.z = f2bf(z2 * g[base + 2]); u.w = f2bf(z3 * g[base + 3]);
  *(ushort4*)(og + base) = u;
}

// ---------------- K8: FFN LN + time-shift mix ----------------
__global__ __launch_bounds__(256) void k8_ffnmix(
    const float* __restrict__ x2, const float* __restrict__ lnw, const float* __restrict__ lnb,
    const float* __restrict__ fxk, unsigned short* __restrict__ kf) {
  __shared__ float red[8];
  const int row = blockIdx.x;
  const int t = row & (Tt - 1);
  const int tid = threadIdx.x;
  const int c = tid * 4;
  const size_t base = (size_t)row * Cc + c;
  float a0 = x2[base], a1 = x2[base + 1], a2 = x2[base + 2], a3 = x2[base + 3];
  float mu, rs;
  row_stats(a0, a1, a2, a3, red, mu, rs, 1e-5f);
  float w0 = lnw[c], w1 = lnw[c + 1], w2 = lnw[c + 2], w3 = lnw[c + 3];
  float b0 = lnb[c], b1 = lnb[c + 1], b2 = lnb[c + 2], b3 = lnb[c + 3];
  float f0 = (a0 - mu) * rs * w0 + b0, f1 = (a1 - mu) * rs * w1 + b1;
  float f2 = (a2 - mu) * rs * w2 + b2, f3 = (a3 - mu) * rs * w3 + b3;
  float p0 = 0.f, p1 = 0.f, p2 = 0.f, p3 = 0.f;
  if (t > 0) {
    const size_t pb_ = base - Cc;
    float q0 = x2[pb_], q1 = x2[pb_ + 1], q2 = x2[pb_ + 2], q3 = x2[pb_ + 3];
    row_stats(q0, q1, q2, q3, red, mu, rs, 1e-5f);
    p0 = (q0 - mu) * rs * w0 + b0; p1 = (q1 - mu) * rs * w1 + b1;
    p2 = (q2 - mu) * rs * w2 + b2; p3 = (q3 - mu) * rs * w3 + b3;
  }
  ushort4 u;
  u.x = f2bf(f0 + (p0 - f0) * fxk[c]);
  u.y = f2bf(f1 + (p1 - f1) * fxk[c + 1]);
  u.z = f2bf(f2 + (p2 - f2) * fxk[c + 2]);
  u.w = f2bf(f3 + (p3 - f3) * fxk[c + 3]);
  *(ushort4*)(kf + base) = u;
}

// ---------------- host ----------------
extern "C" void kernel_launch(void* const* d_in, const int* in_sizes, int n_in,
                              void* d_out, int out_size, void* d_ws, size_t ws_size,
                              hipStream_t stream) {
  (void)in_sizes; (void)n_in; (void)out_size; (void)ws_size;
  const float* x    = (const float*)d_in[0];
  const float* lnpw = (const float*)d_in[2];
  const float* lnpb = (const float*)d_in[3];
  const float* lnaw = (const float*)d_in[4];
  const float* lnab = (const float*)d_in[5];
  const float* lnfw = (const float*)d_in[6];
  const float* lnfb = (const float*)d_in[7];
  const float* cxr  = (const float*)d_in[8];
  const float* cxw  = (const float*)d_in[9];
  const float* cxk  = (const float*)d_in[10];
  const float* cxv  = (const float*)d_in[11];
  const float* cxa  = (const float*)d_in[12];
  const float* cxg  = (const float*)d_in[13];
  const float* w0v  = (const float*)d_in[14];
  const float* w1m  = (const float*)d_in[15];
  const float* w2m  = (const float*)d_in[16];
  const float* a0v  = (const float*)d_in[17];
  const float* a1m  = (const float*)d_in[18];
  const float* a2m  = (const float*)d_in[19];
  const float* g1m  = (const float*)d_in[20];
  const float* g2m  = (const float*)d_in[21];
  const float* kkv  = (const float*)d_in[22];
  const float* kav  = (const float*)d_in[23];
  const float* rkv  = (const float*)d_in[24];
  const float* Wr   = (const float*)d_in[25];
  const float* Wk   = (const float*)d_in[26];
  const float* Wv   = (const float*)d_in[27];
  const float* Wo   = (const float*)d_in[28];
  const float* gnw  = (const float*)d_in[29];
  const float* gnb  = (const float*)d_in[30];
  const float* fxk  = (const float*)d_in[31];
  const float* Wf1  = (const float*)d_in[32];
  const float* Wf2  = (const float*)d_in[33];

  char* ws = (char*)d_ws;
  float* outx = (float*)d_out;          // final x (B,T,C)
  float* vout = outx + BTC;             // v_first = v (B,T,C)

  // workspace layout (aliases noted)
  size_t off = 0;
  unsigned short* WrT  = (unsigned short*)(ws + off); off += 2097152;
  unsigned short* WkT  = (unsigned short*)(ws + off); off += 2097152;
  unsigned short* WvT  = (unsigned short*)(ws + off); off += 2097152;
  unsigned short* WoT  = (unsigned short*)(ws + off); off += 2097152;
  unsigned short* Wf1T = (unsigned short*)(ws + off); off += 8388608;
  unsigned short* Wf2T = (unsigned short*)(ws + off); off += 8388608;
  unsigned short* w1T  = (unsigned short*)(ws + off); off += 131072;
  unsigned short* w2T  = (unsigned short*)(ws + off); off += 131072;
  unsigned short* a1T  = (unsigned short*)(ws + off); off += 131072;
  unsigned short* a2T  = (unsigned short*)(ws + off); off += 131072;
  unsigned short* g1T  = (unsigned short*)(ws + off); off += 262144;
  unsigned short* g2T  = (unsigned short*)(ws + off); off += 262144;
  float* xln = (float*)(ws + off); off += 16777216;
  unsigned short* mixR = (unsigned short*)(ws + off);          // 6 x 8388608
  unsigned short* mixW = (unsigned short*)(ws + off + 8388608);
  unsigned short* mixK = (unsigned short*)(ws + off + 16777216);
  unsigned short* mixV = (unsigned short*)(ws + off + 25165824);
  unsigned short* mixA = (unsigned short*)(ws + off + 33554432);
  unsigned short* mixG = (unsigned short*)(ws + off + 41943040);
  unsigned short* hbuf = (unsigned short*)(ws + off);          // alias mix (dead by then)
  off += 50331648;
  unsigned short* tmpw = (unsigned short*)(ws + off); off += 524288;
  unsigned short* tmpa = (unsigned short*)(ws + off); off += 524288;
  unsigned short* tmpg = (unsigned short*)(ws + off); off += 1048576;
  float* decay = (float*)(ws + off);
  unsigned short* og = (unsigned short*)(ws + off);            // alias decay (dead after K5)
  off += 16777216;
  float* aicl = (float*)(ws + off);
  float* obuf = (float*)(ws + off);                            // alias aicl; p0 after k6
  off += 16777216;
  float* gout = (float*)(ws + off); off += 16777216;           // p1 after k6
  float* rbuf = (float*)(ws + off);
  float* x2   = (float*)(ws + off);                            // alias rbuf (dead after K6)
  off += 16777216;
  float* kbuf = (float*)(ws + off); off += 16777216;
  float* awb  = (float*)(ws + off);
  unsigned short* kf = (unsigned short*)(ws + off);            // alias awb (dead after K5)
  off += 16777216;
  float* bwb  = (float*)(ws + off); off += 16777216;           // total ~187 MB

  dim3 tb(32, 8);
  // weight prep: f32 (K,N) -> bf16 (N,K) — ALL 12 jobs in one dispatch
  TPack tp;
  tp.d[0]  = TDesc{Wr,  WrT,  1024, 1024, 0,     32};
  tp.d[1]  = TDesc{Wk,  WkT,  1024, 1024, 1024,  32};
  tp.d[2]  = TDesc{Wv,  WvT,  1024, 1024, 2048,  32};
  tp.d[3]  = TDesc{Wo,  WoT,  1024, 1024, 3072,  32};
  tp.d[4]  = TDesc{Wf1, Wf1T, 1024, 4096, 4096,  128};
  tp.d[5]  = TDesc{Wf2, Wf2T, 4096, 1024, 8192,  32};
  tp.d[6]  = TDesc{w1m, w1T,  1024, 64,   12288, 2};
  tp.d[7]  = TDesc{w2m, w2T,  64,   1024, 12352, 32};
  tp.d[8]  = TDesc{a1m, a1T,  1024, 64,   12416, 2};
  tp.d[9]  = TDesc{a2m, a2T,  64,   1024, 12480, 32};
  tp.d[10] = TDesc{g1m, g1T,  1024, 128,  12544, 4};
  tp.d[11] = TDesc{g2m, g2T,  128,  1024, 12672, 32};
  kt_transpose_multi<<<12800, tb, 0, stream>>>(tp);

  // K1: pre-LN + attn-LN + shift mixes
  k1_mix<<<Mm, 256, 0, stream>>>(x, lnpw, lnpb, lnaw, lnab, cxr, cxw, cxk, cxv, cxa, cxg,
                                 xln, mixR, mixW, mixK, mixV, mixA, mixG);

  // LoRA chains — 2 z-batched dispatches
  kg_lora1<<<dim3(1, 32, 4), 256, 0, stream>>>(mixW, mixA, mixG, w1T, a1T, g1T,
                                               tmpw, tmpa, tmpg);
  kg_lora2<<<dim3(16, 32, 3), 256, 0, stream>>>(tmpw, tmpa, tmpg, w2T, a2T, g2T,
                                                decay, aicl, gout, w0v, a0v);

  // r / k / v projections + fused k4 (needs aicl -> after lora2)
  kg_qkv_fused<<<dim3(8, 32, 3), 256, 0, stream>>>(mixR, mixK, mixV, WrT, WkT, WvT,
                                                   rbuf, kbuf, vout,
                                                   aicl, kkv, kav, awb, bwb);

  // WKV7 scan — R2-proven config
  k5_wkv7<<<256, 512, 0, stream>>>(rbuf, decay, kbuf, vout, awb, bwb, obuf);
  // GN + bonus + gate
  k6_out<<<Mm, 256, 0, stream>>>(obuf, rbuf, kbuf, vout, rkv, gnw, gnb, gout, og);
  // o-projection + residual -> x2 (128x64: 512 blocks = 2/CU)
  kg_gemm64<7><<<dim3(16, 32), 256, 0, stream>>>(og, WoT, Mm, 1024, 1024, x2, nullptr, nullptr, xln);
  // FFN
  k8_ffnmix<<<Mm, 256, 0, stream>>>(x2, lnfw, lnfb, fxk, kf);
  kg_gemm2<4><<<dim3(32, 32), 256, 0, stream>>>(kf, Wf1T, Mm, 4096, 1024, nullptr, hbuf, nullptr, nullptr);
  // FFN2 split-K (z=2, 128^2 tile, 512 blocks = 2/CU) -> partials in obuf/gout
  kg_ffn2_sk<<<dim3(8, 32, 2), 256, 0, stream>>>(hbuf, Wf2T, obuf, gout);
  // outx = p0 + p1 + x2
  k9_add<<<Mm, 256, 0, stream>>>(obuf, gout, x2, outx);
}

// Round 8
// 572.551 us; speedup vs baseline: 1.2179x; 1.0140x over previous
//
#include <hip/hip_runtime.h>

// ---------------- constants ----------------
#define Bb 8
#define Tt 512
#define Cc 1024
#define Hh 16
#define Nh 64
#define Mm 4096            // B*T
#define BTC 4194304        // M*C
#define DEV __device__ __forceinline__

typedef __attribute__((ext_vector_type(8))) short short8;
typedef __attribute__((ext_vector_type(4))) float f32x4;

DEV unsigned short f2bf(float f) {
  unsigned int u = __builtin_bit_cast(unsigned int, f);
  u += 0x7fffu + ((u >> 16) & 1u);
  return (unsigned short)(u >> 16);
}

// DPP butterfly add — pure VALU. 0xB1=quad xor1, 0x4E=quad xor2,
// 0x124=row_ror:4, 0x128=row_ror:8 (within 16-lane DPP row).
template <int CTRL>
DEV float dppadd(float x) {
  int xi = __builtin_bit_cast(int, x);
  int yi = __builtin_amdgcn_update_dpp(0, xi, CTRL, 0xF, 0xF, true);
  return x + __builtin_bit_cast(float, yi);
}

// ---------------- merged transpose f32 (K x N) -> bf16 (N x K) ----------------
struct TDesc { const float* in; unsigned short* out; int K, N, bstart, nbx; };
struct TPack { TDesc d[12]; };

__global__ __launch_bounds__(256) void kt_transpose_multi(TPack p) {
  __shared__ float tile[32][33];
  const int bid = blockIdx.x;
  int i = 0;
  #pragma unroll
  for (int j = 1; j < 12; ++j) if (bid >= p.d[j].bstart) i = j;
  const float* in = p.d[i].in;
  unsigned short* out = p.d[i].out;
  const int K = p.d[i].K, N = p.d[i].N;
  const int local = bid - p.d[i].bstart;
  const int byq = local / p.d[i].nbx;
  const int bx = (local - byq * p.d[i].nbx) * 32;
  const int by = byq * 32;
  int tx = threadIdx.x, ty = threadIdx.y;
  #pragma unroll
  for (int q = ty; q < 32; q += 8) {
    int kk = by + q, nn = bx + tx;
    tile[q][tx] = (kk < K && nn < N) ? in[(size_t)kk * N + nn] : 0.f;
  }
  __syncthreads();
  #pragma unroll
  for (int q = ty; q < 32; q += 8) {
    int nn = bx + q, kk = by + tx;
    if (nn < N && kk < K) out[(size_t)nn * K + kk] = f2bf(tile[tx][q]);
  }
}

// ---------------- block row stats (1024 elems over 256 threads) ----------------
DEV void row_stats(float v0, float v1, float v2, float v3, float* red,
                   float& mu, float& rs, float eps) {
  float s = v0 + v1 + v2 + v3;
  float q = v0 * v0 + v1 * v1 + v2 * v2 + v3 * v3;
  #pragma unroll
  for (int o = 32; o; o >>= 1) { s += __shfl_down(s, o); q += __shfl_down(q, o); }
  int w = threadIdx.x >> 6;
  __syncthreads();
  if ((threadIdx.x & 63) == 0) { red[w] = s; red[4 + w] = q; }
  __syncthreads();
  s = red[0] + red[1] + red[2] + red[3];
  q = red[4] + red[5] + red[6] + red[7];
  mu = s * (1.f / 1024.f);
  float var = q * (1.f / 1024.f) - mu * mu;
  rs = rsqrtf(var + eps);
}

// ---------------- K1: pre-LN + attn-LN + time-shift mixes ----------------
__global__ __launch_bounds__(256) void k1_mix(
    const float* __restrict__ x,
    const float* __restrict__ lnpw, const float* __restrict__ lnpb,
    const float* __restrict__ lnaw, const float* __restrict__ lnab,
    const float* __restrict__ cr, const float* __restrict__ cw,
    const float* __restrict__ ck, const float* __restrict__ cv,
    const float* __restrict__ ca, const float* __restrict__ cg,
    float* __restrict__ xln,
    unsigned short* __restrict__ mR, unsigned short* __restrict__ mW,
    unsigned short* __restrict__ mK, unsigned short* __restrict__ mV,
    unsigned short* __restrict__ mA, unsigned short* __restrict__ mG) {
  __shared__ float red[8];
  const int row = blockIdx.x;
  const int t = row & (Tt - 1);
  const int tid = threadIdx.x;
  const int c = tid * 4;
  const size_t base = (size_t)row * Cc + c;
  float a0 = x[base], a1 = x[base + 1], a2 = x[base + 2], a3 = x[base + 3];
  float mu, rs;
  row_stats(a0, a1, a2, a3, red, mu, rs, 1e-5f);
  float pw0 = lnpw[c], pw1 = lnpw[c + 1], pw2 = lnpw[c + 2], pw3 = lnpw[c + 3];
  float pb0 = lnpb[c], pb1 = lnpb[c + 1], pb2 = lnpb[c + 2], pb3 = lnpb[c + 3];
  float l0 = (a0 - mu) * rs * pw0 + pb0, l1 = (a1 - mu) * rs * pw1 + pb1;
  float l2 = (a2 - mu) * rs * pw2 + pb2, l3 = (a3 - mu) * rs * pw3 + pb3;
  float4 st; st.x = l0; st.y = l1; st.z = l2; st.w = l3;
  *(float4*)(xln + base) = st;
  row_stats(l0, l1, l2, l3, red, mu, rs, 1e-5f);
  float aw0 = lnaw[c], aw1 = lnaw[c + 1], aw2 = lnaw[c + 2], aw3 = lnaw[c + 3];
  float ab0 = lnab[c], ab1 = lnab[c + 1], ab2 = lnab[c + 2], ab3 = lnab[c + 3];
  float n0 = (l0 - mu) * rs * aw0 + ab0, n1 = (l1 - mu) * rs * aw1 + ab1;
  float n2 = (l2 - mu) * rs * aw2 + ab2, n3 = (l3 - mu) * rs * aw3 + ab3;
  float p0 = 0.f, p1 = 0.f, p2 = 0.f, p3 = 0.f;
  if (t > 0) {  // uniform over block
    const size_t pb_ = base - Cc;
    float q0 = x[pb_], q1 = x[pb_ + 1], q2 = x[pb_ + 2], q3 = x[pb_ + 3];
    row_stats(q0, q1, q2, q3, red, mu, rs, 1e-5f);
    float e0 = (q0 - mu) * rs * pw0 + pb0, e1 = (q1 - mu) * rs * pw1 + pb1;
    float e2 = (q2 - mu) * rs * pw2 + pb2, e3 = (q3 - mu) * rs * pw3 + pb3;
    row_stats(e0, e1, e2, e3, red, mu, rs, 1e-5f);
    p0 = (e0 - mu) * rs * aw0 + ab0; p1 = (e1 - mu) * rs * aw1 + ab1;
    p2 = (e2 - mu) * rs * aw2 + ab2; p3 = (e3 - mu) * rs * aw3 + ab3;
  }
  float d0 = p0 - n0, d1 = p1 - n1, d2 = p2 - n2, d3 = p3 - n3;
  #define EMIT(cf, dst) { \
    float f0 = cf[c], f1 = cf[c + 1], f2 = cf[c + 2], f3 = cf[c + 3]; \
    ushort4 u; u.x = f2bf(n0 + d0 * f0); u.y = f2bf(n1 + d1 * f1); \
    u.z = f2bf(n2 + d2 * f2); u.w = f2bf(n3 + d3 * f3); \
    *(ushort4*)(dst + base) = u; }
  EMIT(cr, mR) EMIT(cw, mW) EMIT(ck, mK) EMIT(cv, mV) EMIT(ca, mA) EMIT(cg, mG)
  #undef EMIT
}

// ---------------- bf16 MFMA GEMM bodies ----------------
// A: (M,K) bf16 row-major; Bt: (N,K) bf16 row-major.
// MODE: 0 f32 | 1 bf16 | 2 tanh->bf16 | 3 sigmoid->bf16 | 4 relu^2->bf16
//       5 sigmoid(z+bias)->f32 | 6 exp(-sigmoid(z+bias)*e^-.5)->f32 | 7 z+res->f32
//       9 z+res -> outF AND outF2 (Wo: x2 + outx seed for FFN2 atomics)
DEV void gll16(const unsigned short* g, unsigned short* l) {
  __builtin_amdgcn_global_load_lds(
      (const __attribute__((address_space(1))) void*)g,
      (__attribute__((address_space(3))) void*)l, 16, 0, 0);
}

template <int MODE>
DEV void gemm_epi(float z, size_t oi, int col,
                  float* outF, unsigned short* outB,
                  const float* bias, const float* res, float* outF2) {
  if constexpr (MODE == 0) outF[oi] = z;
  else if constexpr (MODE == 1) outB[oi] = f2bf(z);
  else if constexpr (MODE == 2) outB[oi] = f2bf(tanhf(z));
  else if constexpr (MODE == 3) outB[oi] = f2bf(1.f / (1.f + expf(-z)));
  else if constexpr (MODE == 4) { float m = fmaxf(z, 0.f); outB[oi] = f2bf(m * m); }
  else if constexpr (MODE == 5) { z += bias[col]; outF[oi] = 1.f / (1.f + expf(-z)); }
  else if constexpr (MODE == 6) {
    z += bias[col];
    float sg = 1.f / (1.f + expf(-z));
    outF[oi] = expf(-0.6065306597126334f * sg);
  } else if constexpr (MODE == 7) { outF[oi] = z + res[oi]; }
  else { float v = z + res[oi]; outF[oi] = v; outF2[oi] = v; }
}

// runtime-mode epilogue for z-batched LoRA kernels (modes 0,1,2,3,5,6)
DEV void gemm_epi_rt(int mode, float z, size_t oi, int col,
                     float* outF, unsigned short* outB, const float* bias) {
  if (mode == 0) outF[oi] = z;
  else if (mode == 1) outB[oi] = f2bf(z);
  else if (mode == 2) outB[oi] = f2bf(tanhf(z));
  else if (mode == 3) outB[oi] = f2bf(1.f / (1.f + expf(-z)));
  else if (mode == 5) { z += bias[col]; outF[oi] = 1.f / (1.f + expf(-z)); }
  else { z += bias[col]; float sg = 1.f / (1.f + expf(-z));
         outF[oi] = expf(-0.6065306597126334f * sg); }
}

// ---- 128M x 64N tile, compile-time MODE (Wo: 512 blocks = 2/CU) ----
template <int MODE>
__global__ __launch_bounds__(256) void kg_gemm64(
    const unsigned short* __restrict__ A, const unsigned short* __restrict__ Bt,
    int M, int Nn, int K,
    float* __restrict__ outF, unsigned short* __restrict__ outB,
    const float* __restrict__ bias, const float* __restrict__ res,
    float* __restrict__ outF2) {
  __shared__ unsigned short lsA[128 * 32];
  __shared__ unsigned short lsB[64 * 32];
  const int tid = threadIdx.x;
  const int lane = tid & 63;
  const int wave = tid >> 6;
  const int wy = wave >> 1, wx = wave & 1;
  const int m0 = blockIdx.y * 128;
  const int n0 = blockIdx.x * 64;
  const int sl4 = lane >> 2;
  const int sc = (lane & 3) << 3;
  f32x4 acc[4][2];
  #pragma unroll
  for (int i = 0; i < 4; ++i)
    #pragma unroll
    for (int j = 0; j < 2; ++j) { f32x4 z = {0.f, 0.f, 0.f, 0.f}; acc[i][j] = z; }
  const int fr = lane & 15;
  const int fk = (lane >> 4) << 3;
  for (int k0 = 0; k0 < K; k0 += 32) {
    #pragma unroll
    for (int j = 0; j < 2; ++j) {
      const int rb = (wave + j * 4) * 16;
      gll16(A + (size_t)(m0 + rb + sl4) * K + k0 + sc, lsA + rb * 32);
    }
    {
      const int rb = wave * 16;
      int br = n0 + rb + sl4;
      br = br < Nn ? br : Nn - 1;
      gll16(Bt + (size_t)br * K + k0 + sc, lsB + rb * 32);
    }
    __syncthreads();
    short8 af[4], bf[2];
    #pragma unroll
    for (int mt = 0; mt < 4; ++mt)
      af[mt] = *(const short8*)(lsA + (wy * 64 + mt * 16 + fr) * 32 + fk);
    #pragma unroll
    for (int nt = 0; nt < 2; ++nt)
      bf[nt] = *(const short8*)(lsB + (wx * 32 + nt * 16 + fr) * 32 + fk);
    #pragma unroll
    for (int mt = 0; mt < 4; ++mt)
      #pragma unroll
      for (int nt = 0; nt < 2; ++nt)
        acc[mt][nt] = __builtin_amdgcn_mfma_f32_16x16x32_bf16(af[mt], bf[nt], acc[mt][nt], 0, 0, 0);
    __syncthreads();
  }
  const int rbase = (lane >> 4) << 2;
  const int cbase = lane & 15;
  #pragma unroll
  for (int mt = 0; mt < 4; ++mt)
    #pragma unroll
    for (int nt = 0; nt < 2; ++nt)
      #pragma unroll
      for (int rr = 0; rr < 4; ++rr) {
        int row = m0 + wy * 64 + mt * 16 + rbase + rr;
        int col = n0 + wx * 32 + nt * 16 + cbase;
        if (col < Nn)
          gemm_epi<MODE>(acc[mt][nt][rr], (size_t)row * Nn + col, col, outF, outB, bias, res, outF2);
      }
}

// 128M x 64N tile body, runtime mode (for z-batched small GEMMs)
DEV void gemm_body_rt(const unsigned short* A, const unsigned short* Bt,
                      int Nn, int K,
                      float* outF, unsigned short* outB, const float* bias,
                      unsigned short* lsA, unsigned short* lsB,
                      int m0, int n0, int mode) {
  const int tid = threadIdx.x;
  const int lane = tid & 63;
  const int wave = tid >> 6;
  const int wy = wave >> 1, wx = wave & 1;
  const int sl4 = lane >> 2;
  const int sc = (lane & 3) << 3;
  f32x4 acc[4][2];
  #pragma unroll
  for (int i = 0; i < 4; ++i)
    #pragma unroll
    for (int j = 0; j < 2; ++j) { f32x4 z = {0.f, 0.f, 0.f, 0.f}; acc[i][j] = z; }
  const int fr = lane & 15;
  const int fk = (lane >> 4) << 3;
  for (int k0 = 0; k0 < K; k0 += 32) {
    #pragma unroll
    for (int j = 0; j < 2; ++j) {
      const int rb = (wave + j * 4) * 16;
      gll16(A + (size_t)(m0 + rb + sl4) * K + k0 + sc, lsA + rb * 32);
    }
    {
      const int rb = wave * 16;
      int br = n0 + rb + sl4;
      br = br < Nn ? br : Nn - 1;
      gll16(Bt + (size_t)br * K + k0 + sc, lsB + rb * 32);
    }
    __syncthreads();
    short8 af[4], bf[2];
    #pragma unroll
    for (int mt = 0; mt < 4; ++mt)
      af[mt] = *(const short8*)(lsA + (wy * 64 + mt * 16 + fr) * 32 + fk);
    #pragma unroll
    for (int nt = 0; nt < 2; ++nt)
      bf[nt] = *(const short8*)(lsB + (wx * 32 + nt * 16 + fr) * 32 + fk);
    #pragma unroll
    for (int mt = 0; mt < 4; ++mt)
      #pragma unroll
      for (int nt = 0; nt < 2; ++nt)
        acc[mt][nt] = __builtin_amdgcn_mfma_f32_16x16x32_bf16(af[mt], bf[nt], acc[mt][nt], 0, 0, 0);
    __syncthreads();
  }
  const int rbase = (lane >> 4) << 2;
  const int cbase = lane & 15;
  #pragma unroll
  for (int mt = 0; mt < 4; ++mt)
    #pragma unroll
    for (int nt = 0; nt < 2; ++nt)
      #pragma unroll
      for (int rr = 0; rr < 4; ++rr) {
        int row = m0 + wy * 64 + mt * 16 + rbase + rr;
        int col = n0 + wx * 32 + nt * 16 + cbase;
        if (col < Nn)
          gemm_epi_rt(mode, acc[mt][nt][rr], (size_t)row * Nn + col, col, outF, outB, bias);
      }
}

// stage-1 LoRA batch: z=0 w1(tanh), z=1 a1(plain), z=2/3 g1(sigmoid) cols 0-63/64-127
__global__ __launch_bounds__(256) void kg_lora1(
    const unsigned short* __restrict__ mW, const unsigned short* __restrict__ mA,
    const unsigned short* __restrict__ mG,
    const unsigned short* __restrict__ w1T, const unsigned short* __restrict__ a1T,
    const unsigned short* __restrict__ g1T,
    unsigned short* __restrict__ tmpw, unsigned short* __restrict__ tmpa,
    unsigned short* __restrict__ tmpg) {
  __shared__ unsigned short lsA[128 * 32];
  __shared__ unsigned short lsB[64 * 32];
  const int z = blockIdx.z;
  const unsigned short* A  = z == 0 ? mW : z == 1 ? mA : mG;
  const unsigned short* Bt = z == 0 ? w1T : z == 1 ? a1T : g1T;
  unsigned short* outB     = z == 0 ? tmpw : z == 1 ? tmpa : tmpg;
  const int Nn = z < 2 ? 64 : 128;
  const int n0 = z < 2 ? 0 : (z - 2) * 64;
  const int mode = z == 0 ? 2 : z == 1 ? 1 : 3;
  gemm_body_rt(A, Bt, Nn, 1024, nullptr, outB, nullptr, lsA, lsB,
               blockIdx.y * 128, n0, mode);
}

// stage-2 LoRA batch: z=0 decay(mode6,K=64), z=1 aicl(mode5,K=64), z=2 gout(mode0,K=128)
__global__ __launch_bounds__(256) void kg_lora2(
    const unsigned short* __restrict__ tmpw, const unsigned short* __restrict__ tmpa,
    const unsigned short* __restrict__ tmpg,
    const unsigned short* __restrict__ w2T, const unsigned short* __restrict__ a2T,
    const unsigned short* __restrict__ g2T,
    float* __restrict__ decay, float* __restrict__ aicl, float* __restrict__ gout,
    const float* __restrict__ w0v, const float* __restrict__ a0v) {
  __shared__ unsigned short lsA[128 * 32];
  __shared__ unsigned short lsB[64 * 32];
  const int z = blockIdx.z;
  const unsigned short* A  = z == 0 ? tmpw : z == 1 ? tmpa : tmpg;
  const unsigned short* Bt = z == 0 ? w2T : z == 1 ? a2T : g2T;
  float* outF              = z == 0 ? decay : z == 1 ? aicl : gout;
  const float* bias        = z == 0 ? w0v : z == 1 ? a0v : nullptr;
  const int K = z < 2 ? 64 : 128;
  const int mode = z == 0 ? 6 : z == 1 ? 5 : 0;
  gemm_body_rt(A, Bt, 1024, K, outF, nullptr, bias, lsA, lsB,
               blockIdx.y * 128, blockIdx.x * 64, mode);
}

// ---------------- deep-pipeline GEMM: 128M x 256N x 64K, 3-buffer counted vmcnt ----------------
// T3+T4 (counted vmcnt(6): tile t+2's loads stay in flight ACROSS the barrier;
// vmcnt FIFO retires exactly tile t+1's 6) + T2 swizzle (rows are 128B;
// byte ^= (row&7)<<4 -> 16 frag-lanes hit 8 slots = 2-way = free; applied as
// inverse-swizzled GLOBAL source since global_load_lds dest must be linear)
// + T5 setprio around the MFMA cluster. Race-free by construction: staging
// target (t+2)%3 is never the read buffer (t%3) or ready buffer ((t+1)%3).
// 8 waves (2M x 4N), per-wave C = 64x64 (acc[4][4]); LDS 3 x 48KB = 144KB.
// MODE: 4 relu^2->bf16 | 8 atomicAdd f32 into outF (split-K FFN2, pre-seeded)
template <int MODE>
__global__ __launch_bounds__(512, 1) void kg_gemm8p(
    const unsigned short* __restrict__ A, const unsigned short* __restrict__ Bt,
    int Nn, int Kstride, int Klen,
    float* __restrict__ outF, unsigned short* __restrict__ outB) {
  __shared__ unsigned short lds[3 * 24576];   // 3 x 48KB (A 16KB + B 32KB)
  const int tid = threadIdx.x;
  const int lane = tid & 63;
  const int wave = tid >> 6;
  const int wm = wave >> 2, wn = wave & 3;    // 2 x 4 wave grid
  const int m0 = blockIdx.y * 128;
  const int n0 = blockIdx.x * 256;
  const int kbase = blockIdx.z * Klen;
  const int ntile = Klen / 64;
  const int fr = lane & 15;
  const int fkb = (lane >> 4) << 4;           // k byte offset {0,16,32,48}

  // staged source coords: linear LDS byte off -> (row, swizzled col byte)
  int arow[2], acolb[2], brow[4], bcolb[4];
  #pragma unroll
  for (int i = 0; i < 2; ++i) {
    int off = i * 8192 + tid * 16;
    int r = off >> 7;
    arow[i] = r; acolb[i] = (off & 127) ^ ((r & 7) << 4);
  }
  #pragma unroll
  for (int i = 0; i < 4; ++i) {
    int off = i * 8192 + tid * 16;
    int r = off >> 7;
    brow[i] = r; bcolb[i] = (off & 127) ^ ((r & 7) << 4);
  }

  #define STAGE(t_) { \
    int tc = (t_) < ntile ? (t_) : ntile - 1; \
    unsigned short* lb_ = lds + ((t_) % 3) * 24576; \
    const int kk = kbase + tc * 64; \
    _Pragma("unroll") \
    for (int i = 0; i < 2; ++i) \
      gll16(A + (size_t)(m0 + arow[i]) * Kstride + kk + (acolb[i] >> 1), \
            lb_ + i * 4096 + wave * 512); \
    _Pragma("unroll") \
    for (int i = 0; i < 4; ++i) \
      gll16(Bt + (size_t)(n0 + brow[i]) * Kstride + kk + (bcolb[i] >> 1), \
            lb_ + 8192 + i * 4096 + wave * 512); \
  }

  f32x4 acc[4][4];
  #pragma unroll
  for (int i = 0; i < 4; ++i)
    #pragma unroll
    for (int j = 0; j < 4; ++j) { f32x4 z = {0.f, 0.f, 0.f, 0.f}; acc[i][j] = z; }

  STAGE(0)
  STAGE(1)
  asm volatile("s_waitcnt vmcnt(6)" ::: "memory");  // tile 0 landed, tile 1 in flight
  __syncthreads();

  for (int t = 0; t < ntile; ++t) {
    STAGE(t + 2)
    const unsigned short* lb = lds + (t % 3) * 24576;
    #pragma unroll
    for (int ks = 0; ks < 2; ++ks) {
      short8 af[4], bf[4];
      #pragma unroll
      for (int mt = 0; mt < 4; ++mt) {
        int r = wm * 64 + mt * 16 + fr;
        int byt = (ks * 64 + fkb) ^ ((r & 7) << 4);
        af[mt] = *(const short8*)(lb + r * 64 + (byt >> 1));
      }
      #pragma unroll
      for (int nt = 0; nt < 4; ++nt) {
        int r = wn * 64 + nt * 16 + fr;
        int byt = (ks * 64 + fkb) ^ ((r & 7) << 4);
        bf[nt] = *(const short8*)(lb + 8192 + r * 64 + (byt >> 1));
      }
      __builtin_amdgcn_s_setprio(1);
      #pragma unroll
      for (int mt = 0; mt < 4; ++mt)
        #pragma unroll
        for (int nt = 0; nt < 4; ++nt)
          acc[mt][nt] = __builtin_amdgcn_mfma_f32_16x16x32_bf16(af[mt], bf[nt], acc[mt][nt], 0, 0, 0);
      __builtin_amdgcn_s_setprio(0);
    }
    asm volatile("s_waitcnt vmcnt(6)" ::: "memory");  // retire tile t+1's 6 loads
    __syncthreads();
  }
  #undef STAGE

  const int rbase = (lane >> 4) << 2;
  const int cbase = lane & 15;
  #pragma unroll
  for (int mt = 0; mt < 4; ++mt)
    #pragma unroll
    for (int nt = 0; nt < 4; ++nt)
      #pragma unroll
      for (int rr = 0; rr < 4; ++rr) {
        int row = m0 + wm * 64 + mt * 16 + rbase + rr;
        int col = n0 + wn * 64 + nt * 16 + cbase;
        size_t oi = (size_t)row * Nn + col;
        float z = acc[mt][nt][rr];
        if constexpr (MODE == 4) { float m = fmaxf(z, 0.f); outB[oi] = f2bf(m * m); }
        else atomicAdd(outF + oi, z);
      }
}

// ---------------- QKV projections + fused K4 (z selects r/k/v) ----------------
// 128x128 tile, grid (8,32,3)=768 blocks (3/CU). z==1 (k-projection) fuses the
// old k4_prep: per-(row,head) kk-norm via 4 FMAs + 4-DPP 16-lane sum, no LDS.
__global__ __launch_bounds__(256) void kg_qkv_fused(
    const unsigned short* __restrict__ A0, const unsigned short* __restrict__ A1,
    const unsigned short* __restrict__ A2,
    const unsigned short* __restrict__ B0, const unsigned short* __restrict__ B1,
    const unsigned short* __restrict__ B2,
    float* __restrict__ rbuf, float* __restrict__ kbuf, float* __restrict__ vout,
    const float* __restrict__ aicl,
    const float* __restrict__ kkc, const float* __restrict__ kac,
    float* __restrict__ awb, float* __restrict__ bwb) {
  __shared__ unsigned short lsA[128 * 32];
  __shared__ unsigned short lsB[128 * 32];
  const int z = blockIdx.z;
  const unsigned short* A = z == 0 ? A0 : z == 1 ? A1 : A2;
  const unsigned short* Bt = z == 0 ? B0 : z == 1 ? B1 : B2;
  const int tid = threadIdx.x;
  const int lane = tid & 63;
  const int wave = tid >> 6;
  const int wy = wave >> 1, wx = wave & 1;
  const int m0 = blockIdx.y * 128;
  const int n0 = blockIdx.x * 128;
  const int sl4 = lane >> 2;
  const int sc = (lane & 3) << 3;
  f32x4 acc[4][4];
  #pragma unroll
  for (int i = 0; i < 4; ++i)
    #pragma unroll
    for (int j = 0; j < 4; ++j) { f32x4 zz = {0.f, 0.f, 0.f, 0.f}; acc[i][j] = zz; }
  const int fr = lane & 15;
  const int fk = (lane >> 4) << 3;
  for (int k0 = 0; k0 < 1024; k0 += 32) {
    #pragma unroll
    for (int j = 0; j < 2; ++j) {
      const int rb = (wave + j * 4) * 16;
      gll16(A + (size_t)(m0 + rb + sl4) * 1024 + k0 + sc, lsA + rb * 32);
      gll16(Bt + (size_t)(n0 + rb + sl4) * 1024 + k0 + sc, lsB + rb * 32);
    }
    __syncthreads();
    short8 af[4], bf[4];
    #pragma unroll
    for (int mt = 0; mt < 4; ++mt)
      af[mt] = *(const short8*)(lsA + (wy * 64 + mt * 16 + fr) * 32 + fk);
    #pragma unroll
    for (int nt = 0; nt < 4; ++nt)
      bf[nt] = *(const short8*)(lsB + (wx * 64 + nt * 16 + fr) * 32 + fk);
    #pragma unroll
    for (int mt = 0; mt < 4; ++mt)
      #pragma unroll
      for (int nt = 0; nt < 4; ++nt)
        acc[mt][nt] = __builtin_amdgcn_mfma_f32_16x16x32_bf16(af[mt], bf[nt], acc[mt][nt], 0, 0, 0);
    __syncthreads();
  }
  const int rbase = (lane >> 4) << 2;
  const int cbase = lane & 15;
  if (z != 1) {
    float* outF = z == 0 ? rbuf : vout;
    #pragma unroll
    for (int mt = 0; mt < 4; ++mt)
      #pragma unroll
      for (int nt = 0; nt < 4; ++nt)
        #pragma unroll
        for (int rr = 0; rr < 4; ++rr) {
          int row = m0 + wy * 64 + mt * 16 + rbase + rr;
          int col = n0 + wx * 64 + nt * 16 + cbase;
          outF[(size_t)row * Cc + col] = acc[mt][nt][rr];
        }
  } else {
    // fused k4: per-(row,head) kk-normalize + a/b vectors + k update
    float kkc4[4], kac4[4];
    #pragma unroll
    for (int nt = 0; nt < 4; ++nt) {
      int col = n0 + wx * 64 + nt * 16 + cbase;
      kkc4[nt] = kkc[col];
      kac4[nt] = kac[col];
    }
    #pragma unroll
    for (int mt = 0; mt < 4; ++mt)
      #pragma unroll
      for (int rr = 0; rr < 4; ++rr) {
        int row = m0 + wy * 64 + mt * 16 + rbase + rr;
        float h0 = acc[mt][0][rr] * kkc4[0];
        float h1 = acc[mt][1][rr] * kkc4[1];
        float h2 = acc[mt][2][rr] * kkc4[2];
        float h3 = acc[mt][3][rr] * kkc4[3];
        float ss = (h0 * h0 + h1 * h1) + (h2 * h2 + h3 * h3);
        ss = dppadd<0xB1>(ss);
        ss = dppadd<0x4E>(ss);
        ss = dppadd<0x124>(ss);
        ss = dppadd<0x128>(ss);
        float inv = 1.f / fmaxf(sqrtf(ss), 1e-12f);
        #pragma unroll
        for (int nt = 0; nt < 4; ++nt) {
          int col = n0 + wx * 64 + nt * 16 + cbase;
          size_t oi = (size_t)row * Cc + col;
          float kv = acc[mt][nt][rr];
          float hn = kv * kkc4[nt] * inv;
          float av = aicl[oi];
          awb[oi] = -hn;
          bwb[oi] = hn * av;
          kbuf[oi] = kv * (1.f + (av - 1.f) * kac4[nt]);
        }
      }
  }
}

// ---------------- K5: WKV7 — R2-proven: 8-wave blocks, shared staging ----------------
// 256 blocks = (half, bh) x 512 threads (8 waves); wave w owns rows
// half*32 + w*4 .. +3. Lane = (rw = lane>>4, cg = lane&15), S[4];
// 16-lane reduce = 4 serial DPPs. CS=8 double buffer, one barrier/chunk.
// Measured 114.1-116.1us across R2/R5/R6/R7. Per-wave 5xb128+1xb32/step is
// the f32 information floor — do not touch without an algorithm change.
#define CS 8
__global__ __launch_bounds__(512, 2) void k5_wkv7(
    const float* __restrict__ r, const float* __restrict__ dec,
    const float* __restrict__ k, const float* __restrict__ v,
    const float* __restrict__ aw, const float* __restrict__ bw,
    float* __restrict__ o) {
  const int blk = blockIdx.x;              // 0..255
  const int bh = blk & 127, half = blk >> 7;
  const int b = bh >> 4, h = bh & 15;
  const int tid = threadIdx.x;
  const int lane = tid & 63;
  const int w = tid >> 6;                  // wave 0..7
  const int cg = lane & 15;                // column group (4 cols)
  const int rw = lane >> 4;                // row within wave's 4
  const int row = half * 32 + w * 4 + rw;  // state row i (0..63)
  const int cb = cg << 2;                  // column base j0

  __shared__ float buf[2][6 * CS * 64];    // 2 x 12 KB

  float S[4];
  #pragma unroll
  for (int j = 0; j < 4; ++j) S[j] = 0.f;

  const size_t base = (size_t)b * Tt * Cc + (size_t)h * Nh;

  const float* sptr = w == 0 ? aw : w == 1 ? dec : w == 2 ? bw
                    : w == 3 ? k  : w == 4 ? r   : v;
  const int srow = lane >> 4;              // t-offset within chunk (0..3)
  const int scol = (lane & 15) << 2;       // col (0..60 step 4)

  uint4 R0, R1;
  #define LOADC(cstart) if (w < 6) { \
    const size_t g0 = base + (size_t)((cstart) + srow) * Cc + scol; \
    R0 = *(const uint4*)(sptr + g0); \
    R1 = *(const uint4*)(sptr + g0 + 4 * Cc); }

  LOADC(0)

  #pragma unroll 1
  for (int c = 0; c < Tt / CS; ++c) {
    float* bp = buf[c & 1];
    if (w < 6) {
      *(uint4*)(bp + w * 512 + (lane << 2)) = R0;        // t 0..3
      *(uint4*)(bp + w * 512 + 256 + (lane << 2)) = R1;  // t 4..7
    }
    const int cn = (c + 1 < Tt / CS) ? (c + 1) : c;
    LOADC(cn * CS)
    __syncthreads();

    float4 Aq[2], Dq[2], Bq[2], Kq[2], Rq[2];
    float Vv[2];
    #define LOADOPS(slot, ss) { \
      const float* sp_ = bp + (ss) * 64; \
      Aq[slot] = *(const float4*)(sp_ + cb); \
      Dq[slot] = *(const float4*)(sp_ + 512 + cb); \
      Bq[slot] = *(const float4*)(sp_ + 1024 + cb); \
      Kq[slot] = *(const float4*)(sp_ + 1536 + cb); \
      Rq[slot] = *(const float4*)(sp_ + 2048 + cb); \
      Vv[slot] = sp_[2560 + row]; }

    LOADOPS(0, 0)
    #pragma unroll
    for (int s = 0; s < CS; ++s) {
      const int cu = s & 1, nx = cu ^ 1;
      if (s + 1 < CS) LOADOPS(nx, s + 1)     // prefetch next step's operands

      float4 a4 = Aq[cu];
      float sa = fmaf(S[1], a4.y, S[0] * a4.x) + fmaf(S[3], a4.w, S[2] * a4.z);
      sa = dppadd<0xB1>(sa);
      sa = dppadd<0x4E>(sa);
      sa = dppadd<0x124>(sa);
      sa = dppadd<0x128>(sa);

      const float vv = Vv[cu];
      float4 d4 = Dq[cu], b4 = Bq[cu], k4 = Kq[cu], r4 = Rq[cu];
      S[0] = fmaf(S[0], d4.x, fmaf(vv, k4.x, sa * b4.x));
      float oo = S[0] * r4.x;
      S[1] = fmaf(S[1], d4.y, fmaf(vv, k4.y, sa * b4.y));
      oo = fmaf(S[1], r4.y, oo);
      S[2] = fmaf(S[2], d4.z, fmaf(vv, k4.z, sa * b4.z));
      oo = fmaf(S[2], r4.z, oo);
      S[3] = fmaf(S[3], d4.w, fmaf(vv, k4.w, sa * b4.w));
      oo = fmaf(S[3], r4.w, oo);

      oo = dppadd<0xB1>(oo);
      oo = dppadd<0x4E>(oo);
      oo = dppadd<0x124>(oo);
      oo = dppadd<0x128>(oo);
      if (cg == 0) o[base + (size_t)(c * CS + s) * Cc + row] = oo;
    }
    #undef LOADOPS
  }
  #undef LOADC
}

// ---------------- K6: head GroupNorm + rk bonus + gate ----------------
__global__ __launch_bounds__(256) void k6_out(
    const float* __restrict__ o, const float* __restrict__ r, const float* __restrict__ k,
    const float* __restrict__ v, const float* __restrict__ rk,
    const float* __restrict__ gnw, const float* __restrict__ gnb,
    const float* __restrict__ g, unsigned short* __restrict__ og) {
  const int row = blockIdx.x, tid = threadIdx.x;
  const int c = tid * 4;
  const size_t base = (size_t)row * Cc + c;
  float o0 = o[base], o1 = o[base + 1], o2 = o[base + 2], o3 = o[base + 3];
  float r0 = r[base], r1 = r[base + 1], r2 = r[base + 2], r3 = r[base + 3];
  float k0 = k[base], k1 = k[base + 1], k2 = k[base + 2], k3 = k[base + 3];
  float s = o0 + o1 + o2 + o3;
  float q = o0 * o0 + o1 * o1 + o2 * o2 + o3 * o3;
  float bs = r0 * k0 * rk[c] + r1 * k1 * rk[c + 1] + r2 * k2 * rk[c + 2] + r3 * k3 * rk[c + 3];
  #pragma unroll
  for (int m = 8; m; m >>= 1) {
    s += __shfl_xor(s, m); q += __shfl_xor(q, m); bs += __shfl_xor(bs, m);
  }
  float mu = s * (1.f / 64.f);
  float var = q * (1.f / 64.f) - mu * mu;
  float rs = rsqrtf(var + 64e-5f);
  float v0 = v[base], v1 = v[base + 1], v2 = v[base + 2], v3 = v[base + 3];
  float z0 = (o0 - mu) * rs * gnw[c] + gnb[c] + bs * v0;
  float z1 = (o1 - mu) * rs * gnw[c + 1] + gnb[c + 1] + bs * v1;
  float z2 = (o2 - mu) * rs * gnw[c + 2] + gnb[c + 2] + bs * v2;
  float z3 = (o3 - mu) * rs * gnw[c + 3] + gnb[c + 3] + bs * v3;
  ushort4 u;
  u.x = f2bf(z0 * g[base]); u.y = f2bf(z1 * g[base + 1]);
  u.z = f2bf(z2 * g[base + 2]); u.w = f2bf(z3 * g[base + 3]);
  *(ushort4*)(og + base) = u;
}

// ---------------- K8: FFN LN + time-shift mix ----------------
__global__ __launch_bounds__(256) void k8_ffnmix(
    const float* __restrict__ x2, const float* __restrict__ lnw, const float* __restrict__ lnb,
    const float* __restrict__ fxk, unsigned short* __restrict__ kf) {
  __shared__ float red[8];
  const int row = blockIdx.x;
  const int t = row & (Tt - 1);
  const int tid = threadIdx.x;
  const int c = tid * 4;
  const size_t base = (size_t)row * Cc + c;
  float a0 = x2[base], a1 = x2[base + 1], a2 = x2[base + 2], a3 = x2[base + 3];
  float mu, rs;
  row_stats(a0, a1, a2, a3, red, mu, rs, 1e-5f);
  float w0 = lnw[c], w1 = lnw[c + 1], w2 = lnw[c + 2], w3 = lnw[c + 3];
  float b0 = lnb[c], b1 = lnb[c + 1], b2 = lnb[c + 2], b3 = lnb[c + 3];
  float f0 = (a0 - mu) * rs * w0 + b0, f1 = (a1 - mu) * rs * w1 + b1;
  float f2 = (a2 - mu) * rs * w2 + b2, f3 = (a3 - mu) * rs * w3 + b3;
  float p0 = 0.f, p1 = 0.f, p2 = 0.f, p3 = 0.f;
  if (t > 0) {
    const size_t pb_ = base - Cc;
    float q0 = x2[pb_], q1 = x2[pb_ + 1], q2 = x2[pb_ + 2], q3 = x2[pb_ + 3];
    row_stats(q0, q1, q2, q3, red, mu, rs, 1e-5f);
    p0 = (q0 - mu) * rs * w0 + b0; p1 = (q1 - mu) * rs * w1 + b1;
    p2 = (q2 - mu) * rs * w2 + b2; p3 = (q3 - mu) * rs * w3 + b3;
  }
  ushort4 u;
  u.x = f2bf(f0 + (p0 - f0) * fxk[c]);
  u.y = f2bf(f1 + (p1 - f1) * fxk[c + 1]);
  u.z = f2bf(f2 + (p2 - f2) * fxk[c + 2]);
  u.w = f2bf(f3 + (p3 - f3) * fxk[c + 3]);
  *(ushort4*)(kf + base) = u;
}

// ---------------- host ----------------
extern "C" void kernel_launch(void* const* d_in, const int* in_sizes, int n_in,
                              void* d_out, int out_size, void* d_ws, size_t ws_size,
                              hipStream_t stream) {
  (void)in_sizes; (void)n_in; (void)out_size; (void)ws_size;
  const float* x    = (const float*)d_in[0];
  const float* lnpw = (const float*)d_in[2];
  const float* lnpb = (const float*)d_in[3];
  const float* lnaw = (const float*)d_in[4];
  const float* lnab = (const float*)d_in[5];
  const float* lnfw = (const float*)d_in[6];
  const float* lnfb = (const float*)d_in[7];
  const float* cxr  = (const float*)d_in[8];
  const float* cxw  = (const float*)d_in[9];
  const float* cxk  = (const float*)d_in[10];
  const float* cxv  = (const float*)d_in[11];
  const float* cxa  = (const float*)d_in[12];
  const float* cxg  = (const float*)d_in[13];
  const float* w0v  = (const float*)d_in[14];
  const float* w1m  = (const float*)d_in[15];
  const float* w2m  = (const float*)d_in[16];
  const float* a0v  = (const float*)d_in[17];
  const float* a1m  = (const float*)d_in[18];
  const float* a2m  = (const float*)d_in[19];
  const float* g1m  = (const float*)d_in[20];
  const float* g2m  = (const float*)d_in[21];
  const float* kkv  = (const float*)d_in[22];
  const float* kav  = (const float*)d_in[23];
  const float* rkv  = (const float*)d_in[24];
  const float* Wr   = (const float*)d_in[25];
  const float* Wk   = (const float*)d_in[26];
  const float* Wv   = (const float*)d_in[27];
  const float* Wo   = (const float*)d_in[28];
  const float* gnw  = (const float*)d_in[29];
  const float* gnb  = (const float*)d_in[30];
  const float* fxk  = (const float*)d_in[31];
  const float* Wf1  = (const float*)d_in[32];
  const float* Wf2  = (const float*)d_in[33];

  char* ws = (char*)d_ws;
  float* outx = (float*)d_out;          // final x (B,T,C)
  float* vout = outx + BTC;             // v_first = v (B,T,C)

  // workspace layout (aliases noted)
  size_t off = 0;
  unsigned short* WrT  = (unsigned short*)(ws + off); off += 2097152;
  unsigned short* WkT  = (unsigned short*)(ws + off); off += 2097152;
  unsigned short* WvT  = (unsigned short*)(ws + off); off += 2097152;
  unsigned short* WoT  = (unsigned short*)(ws + off); off += 2097152;
  unsigned short* Wf1T = (unsigned short*)(ws + off); off += 8388608;
  unsigned short* Wf2T = (unsigned short*)(ws + off); off += 8388608;
  unsigned short* w1T  = (unsigned short*)(ws + off); off += 131072;
  unsigned short* w2T  = (unsigned short*)(ws + off); off += 131072;
  unsigned short* a1T  = (unsigned short*)(ws + off); off += 131072;
  unsigned short* a2T  = (unsigned short*)(ws + off); off += 131072;
  unsigned short* g1T  = (unsigned short*)(ws + off); off += 262144;
  unsigned short* g2T  = (unsigned short*)(ws + off); off += 262144;
  float* xln = (float*)(ws + off); off += 16777216;
  unsigned short* mixR = (unsigned short*)(ws + off);          // 6 x 8388608
  unsigned short* mixW = (unsigned short*)(ws + off + 8388608);
  unsigned short* mixK = (unsigned short*)(ws + off + 16777216);
  unsigned short* mixV = (unsigned short*)(ws + off + 25165824);
  unsigned short* mixA = (unsigned short*)(ws + off + 33554432);
  unsigned short* mixG = (unsigned short*)(ws + off + 41943040);
  unsigned short* hbuf = (unsigned short*)(ws + off);          // alias mix (dead by then)
  off += 50331648;
  unsigned short* tmpw = (unsigned short*)(ws + off); off += 524288;
  unsigned short* tmpa = (unsigned short*)(ws + off); off += 524288;
  unsigned short* tmpg = (unsigned short*)(ws + off); off += 1048576;
  float* decay = (float*)(ws + off);
  unsigned short* og = (unsigned short*)(ws + off);            // alias decay (dead after K5)
  off += 16777216;
  float* aicl = (float*)(ws + off);
  float* obuf = (float*)(ws + off);                            // alias aicl (dead after qkv_fused)
  off += 16777216;
  float* gout = (float*)(ws + off); off += 16777216;
  float* rbuf = (float*)(ws + off);
  float* x2   = (float*)(ws + off);                            // alias rbuf (dead after K6)
  off += 16777216;
  float* kbuf = (float*)(ws + off); off += 16777216;
  float* awb  = (float*)(ws + off);
  unsigned short* kf = (unsigned short*)(ws + off);            // alias awb (dead after K5)
  off += 16777216;
  float* bwb  = (float*)(ws + off); off += 16777216;           // total ~187 MB

  dim3 tb(32, 8);
  // weight prep: f32 (K,N) -> bf16 (N,K) — ALL 12 jobs in one dispatch
  TPack tp;
  tp.d[0]  = TDesc{Wr,  WrT,  1024, 1024, 0,     32};
  tp.d[1]  = TDesc{Wk,  WkT,  1024, 1024, 1024,  32};
  tp.d[2]  = TDesc{Wv,  WvT,  1024, 1024, 2048,  32};
  tp.d[3]  = TDesc{Wo,  WoT,  1024, 1024, 3072,  32};
  tp.d[4]  = TDesc{Wf1, Wf1T, 1024, 4096, 4096,  128};
  tp.d[5]  = TDesc{Wf2, Wf2T, 4096, 1024, 8192,  32};
  tp.d[6]  = TDesc{w1m, w1T,  1024, 64,   12288, 2};
  tp.d[7]  = TDesc{w2m, w2T,  64,   1024, 12352, 32};
  tp.d[8]  = TDesc{a1m, a1T,  1024, 64,   12416, 2};
  tp.d[9]  = TDesc{a2m, a2T,  64,   1024, 12480, 32};
  tp.d[10] = TDesc{g1m, g1T,  1024, 128,  12544, 4};
  tp.d[11] = TDesc{g2m, g2T,  128,  1024, 12672, 32};
  kt_transpose_multi<<<12800, tb, 0, stream>>>(tp);

  // K1: pre-LN + attn-LN + shift mixes
  k1_mix<<<Mm, 256, 0, stream>>>(x, lnpw, lnpb, lnaw, lnab, cxr, cxw, cxk, cxv, cxa, cxg,
                                 xln, mixR, mixW, mixK, mixV, mixA, mixG);

  // LoRA chains — 2 z-batched dispatches
  kg_lora1<<<dim3(1, 32, 4), 256, 0, stream>>>(mixW, mixA, mixG, w1T, a1T, g1T,
                                               tmpw, tmpa, tmpg);
  kg_lora2<<<dim3(16, 32, 3), 256, 0, stream>>>(tmpw, tmpa, tmpg, w2T, a2T, g2T,
                                                decay, aicl, gout, w0v, a0v);

  // r / k / v projections + fused k4 (needs aicl -> after lora2)
  kg_qkv_fused<<<dim3(8, 32, 3), 256, 0, stream>>>(mixR, mixK, mixV, WrT, WkT, WvT,
                                                   rbuf, kbuf, vout,
                                                   aicl, kkv, kav, awb, bwb);

  // WKV7 scan — R2-proven config
  k5_wkv7<<<256, 512, 0, stream>>>(rbuf, decay, kbuf, vout, awb, bwb, obuf);
  // GN + bonus + gate
  k6_out<<<Mm, 256, 0, stream>>>(obuf, rbuf, kbuf, vout, rkv, gnw, gnb, gout, og);
  // o-projection + residual -> x2 AND outx seed (mode 9; 128x64: 512 blocks = 2/CU)
  kg_gemm64<9><<<dim3(16, 32), 256, 0, stream>>>(og, WoT, Mm, 1024, 1024, x2, nullptr, nullptr, xln, outx);
  // FFN
  k8_ffnmix<<<Mm, 256, 0, stream>>>(x2, lnfw, lnfb, fxk, kf);
  // FFN1: deep-pipeline 128x256 tile, grid (16,32) = 512 blocks, K=1024
  kg_gemm8p<4><<<dim3(16, 32, 1), 512, 0, stream>>>(kf, Wf1T, 4096, 1024, 1024, nullptr, hbuf);
  // FFN2: deep-pipeline split-K z=2 (K=2048 each), atomicAdd into seeded outx
  kg_gemm8p<8><<<dim3(4, 32, 2), 512, 0, stream>>>(hbuf, Wf2T, 1024, 4096, 2048, outx, nullptr);
}

// Round 9
// 556.426 us; speedup vs baseline: 1.2532x; 1.0290x over previous
//
#include <hip/hip_runtime.h>

// ---------------- constants ----------------
#define Bb 8
#define Tt 512
#define Cc 1024
#define Hh 16
#define Nh 64
#define Mm 4096            // B*T
#define BTC 4194304        // M*C
#define DEV __device__ __forceinline__

typedef __attribute__((ext_vector_type(8))) short short8;
typedef __attribute__((ext_vector_type(4))) float f32x4;

DEV unsigned short f2bf(float f) {
  unsigned int u = __builtin_bit_cast(unsigned int, f);
  u += 0x7fffu + ((u >> 16) & 1u);
  return (unsigned short)(u >> 16);
}

// DPP butterfly add — pure VALU. 0xB1=quad xor1, 0x4E=quad xor2,
// 0x124=row_ror:4, 0x128=row_ror:8 (within 16-lane DPP row).
template <int CTRL>
DEV float dppadd(float x) {
  int xi = __builtin_bit_cast(int, x);
  int yi = __builtin_amdgcn_update_dpp(0, xi, CTRL, 0xF, 0xF, true);
  return x + __builtin_bit_cast(float, yi);
}

// ---------------- merged transpose f32 (K x N) -> bf16 (N x K) ----------------
struct TDesc { const float* in; unsigned short* out; int K, N, bstart, nbx; };
struct TPack { TDesc d[12]; };

__global__ __launch_bounds__(256) void kt_transpose_multi(TPack p) {
  __shared__ float tile[32][33];
  const int bid = blockIdx.x;
  int i = 0;
  #pragma unroll
  for (int j = 1; j < 12; ++j) if (bid >= p.d[j].bstart) i = j;
  const float* in = p.d[i].in;
  unsigned short* out = p.d[i].out;
  const int K = p.d[i].K, N = p.d[i].N;
  const int local = bid - p.d[i].bstart;
  const int byq = local / p.d[i].nbx;
  const int bx = (local - byq * p.d[i].nbx) * 32;
  const int by = byq * 32;
  int tx = threadIdx.x, ty = threadIdx.y;
  #pragma unroll
  for (int q = ty; q < 32; q += 8) {
    int kk = by + q, nn = bx + tx;
    tile[q][tx] = (kk < K && nn < N) ? in[(size_t)kk * N + nn] : 0.f;
  }
  __syncthreads();
  #pragma unroll
  for (int q = ty; q < 32; q += 8) {
    int nn = bx + q, kk = by + tx;
    if (nn < N && kk < K) out[(size_t)nn * K + kk] = f2bf(tile[tx][q]);
  }
}

// ---------------- block row stats (1024 elems over 256 threads) ----------------
DEV void row_stats(float v0, float v1, float v2, float v3, float* red,
                   float& mu, float& rs, float eps) {
  float s = v0 + v1 + v2 + v3;
  float q = v0 * v0 + v1 * v1 + v2 * v2 + v3 * v3;
  #pragma unroll
  for (int o = 32; o; o >>= 1) { s += __shfl_down(s, o); q += __shfl_down(q, o); }
  int w = threadIdx.x >> 6;
  __syncthreads();
  if ((threadIdx.x & 63) == 0) { red[w] = s; red[4 + w] = q; }
  __syncthreads();
  s = red[0] + red[1] + red[2] + red[3];
  q = red[4] + red[5] + red[6] + red[7];
  mu = s * (1.f / 1024.f);
  float var = q * (1.f / 1024.f) - mu * mu;
  rs = rsqrtf(var + eps);
}

// ---------------- K1: pre-LN + attn-LN + time-shift mixes ----------------
__global__ __launch_bounds__(256) void k1_mix(
    const float* __restrict__ x,
    const float* __restrict__ lnpw, const float* __restrict__ lnpb,
    const float* __restrict__ lnaw, const float* __restrict__ lnab,
    const float* __restrict__ cr, const float* __restrict__ cw,
    const float* __restrict__ ck, const float* __restrict__ cv,
    const float* __restrict__ ca, const float* __restrict__ cg,
    float* __restrict__ xln,
    unsigned short* __restrict__ mR, unsigned short* __restrict__ mW,
    unsigned short* __restrict__ mK, unsigned short* __restrict__ mV,
    unsigned short* __restrict__ mA, unsigned short* __restrict__ mG) {
  __shared__ float red[8];
  const int row = blockIdx.x;
  const int t = row & (Tt - 1);
  const int tid = threadIdx.x;
  const int c = tid * 4;
  const size_t base = (size_t)row * Cc + c;
  float a0 = x[base], a1 = x[base + 1], a2 = x[base + 2], a3 = x[base + 3];
  float mu, rs;
  row_stats(a0, a1, a2, a3, red, mu, rs, 1e-5f);
  float pw0 = lnpw[c], pw1 = lnpw[c + 1], pw2 = lnpw[c + 2], pw3 = lnpw[c + 3];
  float pb0 = lnpb[c], pb1 = lnpb[c + 1], pb2 = lnpb[c + 2], pb3 = lnpb[c + 3];
  float l0 = (a0 - mu) * rs * pw0 + pb0, l1 = (a1 - mu) * rs * pw1 + pb1;
  float l2 = (a2 - mu) * rs * pw2 + pb2, l3 = (a3 - mu) * rs * pw3 + pb3;
  float4 st; st.x = l0; st.y = l1; st.z = l2; st.w = l3;
  *(float4*)(xln + base) = st;
  row_stats(l0, l1, l2, l3, red, mu, rs, 1e-5f);
  float aw0 = lnaw[c], aw1 = lnaw[c + 1], aw2 = lnaw[c + 2], aw3 = lnaw[c + 3];
  float ab0 = lnab[c], ab1 = lnab[c + 1], ab2 = lnab[c + 2], ab3 = lnab[c + 3];
  float n0 = (l0 - mu) * rs * aw0 + ab0, n1 = (l1 - mu) * rs * aw1 + ab1;
  float n2 = (l2 - mu) * rs * aw2 + ab2, n3 = (l3 - mu) * rs * aw3 + ab3;
  float p0 = 0.f, p1 = 0.f, p2 = 0.f, p3 = 0.f;
  if (t > 0) {  // uniform over block
    const size_t pb_ = base - Cc;
    float q0 = x[pb_], q1 = x[pb_ + 1], q2 = x[pb_ + 2], q3 = x[pb_ + 3];
    row_stats(q0, q1, q2, q3, red, mu, rs, 1e-5f);
    float e0 = (q0 - mu) * rs * pw0 + pb0, e1 = (q1 - mu) * rs * pw1 + pb1;
    float e2 = (q2 - mu) * rs * pw2 + pb2, e3 = (q3 - mu) * rs * pw3 + pb3;
    row_stats(e0, e1, e2, e3, red, mu, rs, 1e-5f);
    p0 = (e0 - mu) * rs * aw0 + ab0; p1 = (e1 - mu) * rs * aw1 + ab1;
    p2 = (e2 - mu) * rs * aw2 + ab2; p3 = (e3 - mu) * rs * aw3 + ab3;
  }
  float d0 = p0 - n0, d1 = p1 - n1, d2 = p2 - n2, d3 = p3 - n3;
  #define EMIT(cf, dst) { \
    float f0 = cf[c], f1 = cf[c + 1], f2 = cf[c + 2], f3 = cf[c + 3]; \
    ushort4 u; u.x = f2bf(n0 + d0 * f0); u.y = f2bf(n1 + d1 * f1); \
    u.z = f2bf(n2 + d2 * f2); u.w = f2bf(n3 + d3 * f3); \
    *(ushort4*)(dst + base) = u; }
  EMIT(cr, mR) EMIT(cw, mW) EMIT(ck, mK) EMIT(cv, mV) EMIT(ca, mA) EMIT(cg, mG)
  #undef EMIT
}

// ---------------- bf16 MFMA GEMM bodies ----------------
// A: (M,K) bf16 row-major; Bt: (N,K) bf16 row-major.
// MODE: 0 f32 | 1 bf16 | 2 tanh->bf16 | 3 sigmoid->bf16 | 4 relu^2->bf16
//       5 sigmoid(z+bias)->f32 | 6 exp(-sigmoid(z+bias)*e^-.5)->f32 | 7 z+res->f32
//       9 z+res -> outF AND outF2 (Wo: x2 + outx seed for FFN2 atomics)
DEV void gll16(const unsigned short* g, unsigned short* l) {
  __builtin_amdgcn_global_load_lds(
      (const __attribute__((address_space(1))) void*)g,
      (__attribute__((address_space(3))) void*)l, 16, 0, 0);
}

template <int MODE>
DEV void gemm_epi(float z, size_t oi, int col,
                  float* outF, unsigned short* outB,
                  const float* bias, const float* res, float* outF2) {
  if constexpr (MODE == 0) outF[oi] = z;
  else if constexpr (MODE == 1) outB[oi] = f2bf(z);
  else if constexpr (MODE == 2) outB[oi] = f2bf(tanhf(z));
  else if constexpr (MODE == 3) outB[oi] = f2bf(1.f / (1.f + expf(-z)));
  else if constexpr (MODE == 4) { float m = fmaxf(z, 0.f); outB[oi] = f2bf(m * m); }
  else if constexpr (MODE == 5) { z += bias[col]; outF[oi] = 1.f / (1.f + expf(-z)); }
  else if constexpr (MODE == 6) {
    z += bias[col];
    float sg = 1.f / (1.f + expf(-z));
    outF[oi] = expf(-0.6065306597126334f * sg);
  } else if constexpr (MODE == 7) { outF[oi] = z + res[oi]; }
  else { float v = z + res[oi]; outF[oi] = v; outF2[oi] = v; }
}

// runtime-mode epilogue for z-batched LoRA kernels (modes 0,1,2,3,5,6)
DEV void gemm_epi_rt(int mode, float z, size_t oi, int col,
                     float* outF, unsigned short* outB, const float* bias) {
  if (mode == 0) outF[oi] = z;
  else if (mode == 1) outB[oi] = f2bf(z);
  else if (mode == 2) outB[oi] = f2bf(tanhf(z));
  else if (mode == 3) outB[oi] = f2bf(1.f / (1.f + expf(-z)));
  else if (mode == 5) { z += bias[col]; outF[oi] = 1.f / (1.f + expf(-z)); }
  else { z += bias[col]; float sg = 1.f / (1.f + expf(-z));
         outF[oi] = expf(-0.6065306597126334f * sg); }
}

// ---- 128M x 64N tile, compile-time MODE (Wo: 512 blocks = 2/CU) ----
template <int MODE>
__global__ __launch_bounds__(256) void kg_gemm64(
    const unsigned short* __restrict__ A, const unsigned short* __restrict__ Bt,
    int M, int Nn, int K,
    float* __restrict__ outF, unsigned short* __restrict__ outB,
    const float* __restrict__ bias, const float* __restrict__ res,
    float* __restrict__ outF2) {
  __shared__ unsigned short lsA[128 * 32];
  __shared__ unsigned short lsB[64 * 32];
  const int tid = threadIdx.x;
  const int lane = tid & 63;
  const int wave = tid >> 6;
  const int wy = wave >> 1, wx = wave & 1;
  const int m0 = blockIdx.y * 128;
  const int n0 = blockIdx.x * 64;
  const int sl4 = lane >> 2;
  const int sc = (lane & 3) << 3;
  f32x4 acc[4][2];
  #pragma unroll
  for (int i = 0; i < 4; ++i)
    #pragma unroll
    for (int j = 0; j < 2; ++j) { f32x4 z = {0.f, 0.f, 0.f, 0.f}; acc[i][j] = z; }
  const int fr = lane & 15;
  const int fk = (lane >> 4) << 3;
  for (int k0 = 0; k0 < K; k0 += 32) {
    #pragma unroll
    for (int j = 0; j < 2; ++j) {
      const int rb = (wave + j * 4) * 16;
      gll16(A + (size_t)(m0 + rb + sl4) * K + k0 + sc, lsA + rb * 32);
    }
    {
      const int rb = wave * 16;
      int br = n0 + rb + sl4;
      br = br < Nn ? br : Nn - 1;
      gll16(Bt + (size_t)br * K + k0 + sc, lsB + rb * 32);
    }
    __syncthreads();
    short8 af[4], bf[2];
    #pragma unroll
    for (int mt = 0; mt < 4; ++mt)
      af[mt] = *(const short8*)(lsA + (wy * 64 + mt * 16 + fr) * 32 + fk);
    #pragma unroll
    for (int nt = 0; nt < 2; ++nt)
      bf[nt] = *(const short8*)(lsB + (wx * 32 + nt * 16 + fr) * 32 + fk);
    #pragma unroll
    for (int mt = 0; mt < 4; ++mt)
      #pragma unroll
      for (int nt = 0; nt < 2; ++nt)
        acc[mt][nt] = __builtin_amdgcn_mfma_f32_16x16x32_bf16(af[mt], bf[nt], acc[mt][nt], 0, 0, 0);
    __syncthreads();
  }
  const int rbase = (lane >> 4) << 2;
  const int cbase = lane & 15;
  #pragma unroll
  for (int mt = 0; mt < 4; ++mt)
    #pragma unroll
    for (int nt = 0; nt < 2; ++nt)
      #pragma unroll
      for (int rr = 0; rr < 4; ++rr) {
        int row = m0 + wy * 64 + mt * 16 + rbase + rr;
        int col = n0 + wx * 32 + nt * 16 + cbase;
        if (col < Nn)
          gemm_epi<MODE>(acc[mt][nt][rr], (size_t)row * Nn + col, col, outF, outB, bias, res, outF2);
      }
}

// 128M x 64N tile body, runtime mode (for z-batched small GEMMs)
DEV void gemm_body_rt(const unsigned short* A, const unsigned short* Bt,
                      int Nn, int K,
                      float* outF, unsigned short* outB, const float* bias,
                      unsigned short* lsA, unsigned short* lsB,
                      int m0, int n0, int mode) {
  const int tid = threadIdx.x;
  const int lane = tid & 63;
  const int wave = tid >> 6;
  const int wy = wave >> 1, wx = wave & 1;
  const int sl4 = lane >> 2;
  const int sc = (lane & 3) << 3;
  f32x4 acc[4][2];
  #pragma unroll
  for (int i = 0; i < 4; ++i)
    #pragma unroll
    for (int j = 0; j < 2; ++j) { f32x4 z = {0.f, 0.f, 0.f, 0.f}; acc[i][j] = z; }
  const int fr = lane & 15;
  const int fk = (lane >> 4) << 3;
  for (int k0 = 0; k0 < K; k0 += 32) {
    #pragma unroll
    for (int j = 0; j < 2; ++j) {
      const int rb = (wave + j * 4) * 16;
      gll16(A + (size_t)(m0 + rb + sl4) * K + k0 + sc, lsA + rb * 32);
    }
    {
      const int rb = wave * 16;
      int br = n0 + rb + sl4;
      br = br < Nn ? br : Nn - 1;
      gll16(Bt + (size_t)br * K + k0 + sc, lsB + rb * 32);
    }
    __syncthreads();
    short8 af[4], bf[2];
    #pragma unroll
    for (int mt = 0; mt < 4; ++mt)
      af[mt] = *(const short8*)(lsA + (wy * 64 + mt * 16 + fr) * 32 + fk);
    #pragma unroll
    for (int nt = 0; nt < 2; ++nt)
      bf[nt] = *(const short8*)(lsB + (wx * 32 + nt * 16 + fr) * 32 + fk);
    #pragma unroll
    for (int mt = 0; mt < 4; ++mt)
      #pragma unroll
      for (int nt = 0; nt < 2; ++nt)
        acc[mt][nt] = __builtin_amdgcn_mfma_f32_16x16x32_bf16(af[mt], bf[nt], acc[mt][nt], 0, 0, 0);
    __syncthreads();
  }
  const int rbase = (lane >> 4) << 2;
  const int cbase = lane & 15;
  #pragma unroll
  for (int mt = 0; mt < 4; ++mt)
    #pragma unroll
    for (int nt = 0; nt < 2; ++nt)
      #pragma unroll
      for (int rr = 0; rr < 4; ++rr) {
        int row = m0 + wy * 64 + mt * 16 + rbase + rr;
        int col = n0 + wx * 32 + nt * 16 + cbase;
        if (col < Nn)
          gemm_epi_rt(mode, acc[mt][nt][rr], (size_t)row * Nn + col, col, outF, outB, bias);
      }
}

// stage-1 LoRA batch: z=0 w1(tanh), z=1 a1(plain), z=2/3 g1(sigmoid) cols 0-63/64-127
__global__ __launch_bounds__(256) void kg_lora1(
    const unsigned short* __restrict__ mW, const unsigned short* __restrict__ mA,
    const unsigned short* __restrict__ mG,
    const unsigned short* __restrict__ w1T, const unsigned short* __restrict__ a1T,
    const unsigned short* __restrict__ g1T,
    unsigned short* __restrict__ tmpw, unsigned short* __restrict__ tmpa,
    unsigned short* __restrict__ tmpg) {
  __shared__ unsigned short lsA[128 * 32];
  __shared__ unsigned short lsB[64 * 32];
  const int z = blockIdx.z;
  const unsigned short* A  = z == 0 ? mW : z == 1 ? mA : mG;
  const unsigned short* Bt = z == 0 ? w1T : z == 1 ? a1T : g1T;
  unsigned short* outB     = z == 0 ? tmpw : z == 1 ? tmpa : tmpg;
  const int Nn = z < 2 ? 64 : 128;
  const int n0 = z < 2 ? 0 : (z - 2) * 64;
  const int mode = z == 0 ? 2 : z == 1 ? 1 : 3;
  gemm_body_rt(A, Bt, Nn, 1024, nullptr, outB, nullptr, lsA, lsB,
               blockIdx.y * 128, n0, mode);
}

// stage-2 LoRA batch: z=0 decay(mode6,K=64), z=1 aicl(mode5,K=64), z=2 gout(mode0,K=128)
__global__ __launch_bounds__(256) void kg_lora2(
    const unsigned short* __restrict__ tmpw, const unsigned short* __restrict__ tmpa,
    const unsigned short* __restrict__ tmpg,
    const unsigned short* __restrict__ w2T, const unsigned short* __restrict__ a2T,
    const unsigned short* __restrict__ g2T,
    float* __restrict__ decay, float* __restrict__ aicl, float* __restrict__ gout,
    const float* __restrict__ w0v, const float* __restrict__ a0v) {
  __shared__ unsigned short lsA[128 * 32];
  __shared__ unsigned short lsB[64 * 32];
  const int z = blockIdx.z;
  const unsigned short* A  = z == 0 ? tmpw : z == 1 ? tmpa : tmpg;
  const unsigned short* Bt = z == 0 ? w2T : z == 1 ? a2T : g2T;
  float* outF              = z == 0 ? decay : z == 1 ? aicl : gout;
  const float* bias        = z == 0 ? w0v : z == 1 ? a0v : nullptr;
  const int K = z < 2 ? 64 : 128;
  const int mode = z == 0 ? 6 : z == 1 ? 5 : 0;
  gemm_body_rt(A, Bt, 1024, K, outF, nullptr, bias, lsA, lsB,
               blockIdx.y * 128, blockIdx.x * 64, mode);
}

// ---------------- deep-pipeline GEMM: 128M x 256N x 64K, 3-buffer counted vmcnt ----------------
// T3+T4 (counted vmcnt(6): tile t+2's loads stay in flight ACROSS the barrier;
// vmcnt FIFO retires exactly tile t+1's 6) + T2 swizzle (rows are 128B;
// byte ^= (row&7)<<4; applied as inverse-swizzled GLOBAL source since
// global_load_lds dest must be linear) + T5 setprio. Race-free: staging
// target (t+2)%3 is never the read buffer (t%3) or ready buffer ((t+1)%3).
// 8 waves (2M x 4N), per-wave C = 64x64 (acc[4][4]); LDS 3 x 48KB = 144KB.
// Verified correct in R8 (FFN1/FFN2, refchecked by harness).
// MODE: 4 relu^2->bf16 | 8 atomicAdd f32 into outF (split-K FFN2, pre-seeded)
template <int MODE>
__global__ __launch_bounds__(512, 1) void kg_gemm8p(
    const unsigned short* __restrict__ A, const unsigned short* __restrict__ Bt,
    int Nn, int Kstride, int Klen,
    float* __restrict__ outF, unsigned short* __restrict__ outB) {
  __shared__ unsigned short lds[3 * 24576];   // 3 x 48KB (A 16KB + B 32KB)
  const int tid = threadIdx.x;
  const int lane = tid & 63;
  const int wave = tid >> 6;
  const int wm = wave >> 2, wn = wave & 3;    // 2 x 4 wave grid
  const int m0 = blockIdx.y * 128;
  const int n0 = blockIdx.x * 256;
  const int kbase = blockIdx.z * Klen;
  const int ntile = Klen / 64;
  const int fr = lane & 15;
  const int fkb = (lane >> 4) << 4;           // k byte offset {0,16,32,48}

  int arow[2], acolb[2], brow[4], bcolb[4];
  #pragma unroll
  for (int i = 0; i < 2; ++i) {
    int off = i * 8192 + tid * 16;
    int r = off >> 7;
    arow[i] = r; acolb[i] = (off & 127) ^ ((r & 7) << 4);
  }
  #pragma unroll
  for (int i = 0; i < 4; ++i) {
    int off = i * 8192 + tid * 16;
    int r = off >> 7;
    brow[i] = r; bcolb[i] = (off & 127) ^ ((r & 7) << 4);
  }

  #define STAGE(t_) { \
    int tc = (t_) < ntile ? (t_) : ntile - 1; \
    unsigned short* lb_ = lds + ((t_) % 3) * 24576; \
    const int kk = kbase + tc * 64; \
    _Pragma("unroll") \
    for (int i = 0; i < 2; ++i) \
      gll16(A + (size_t)(m0 + arow[i]) * Kstride + kk + (acolb[i] >> 1), \
            lb_ + i * 4096 + wave * 512); \
    _Pragma("unroll") \
    for (int i = 0; i < 4; ++i) \
      gll16(Bt + (size_t)(n0 + brow[i]) * Kstride + kk + (bcolb[i] >> 1), \
            lb_ + 8192 + i * 4096 + wave * 512); \
  }

  f32x4 acc[4][4];
  #pragma unroll
  for (int i = 0; i < 4; ++i)
    #pragma unroll
    for (int j = 0; j < 4; ++j) { f32x4 z = {0.f, 0.f, 0.f, 0.f}; acc[i][j] = z; }

  STAGE(0)
  STAGE(1)
  asm volatile("s_waitcnt vmcnt(6)" ::: "memory");  // tile 0 landed, tile 1 in flight
  __syncthreads();

  for (int t = 0; t < ntile; ++t) {
    STAGE(t + 2)
    const unsigned short* lb = lds + (t % 3) * 24576;
    #pragma unroll
    for (int ks = 0; ks < 2; ++ks) {
      short8 af[4], bf[4];
      #pragma unroll
      for (int mt = 0; mt < 4; ++mt) {
        int r = wm * 64 + mt * 16 + fr;
        int byt = (ks * 64 + fkb) ^ ((r & 7) << 4);
        af[mt] = *(const short8*)(lb + r * 64 + (byt >> 1));
      }
      #pragma unroll
      for (int nt = 0; nt < 4; ++nt) {
        int r = wn * 64 + nt * 16 + fr;
        int byt = (ks * 64 + fkb) ^ ((r & 7) << 4);
        bf[nt] = *(const short8*)(lb + 8192 + r * 64 + (byt >> 1));
      }
      __builtin_amdgcn_s_setprio(1);
      #pragma unroll
      for (int mt = 0; mt < 4; ++mt)
        #pragma unroll
        for (int nt = 0; nt < 4; ++nt)
          acc[mt][nt] = __builtin_amdgcn_mfma_f32_16x16x32_bf16(af[mt], bf[nt], acc[mt][nt], 0, 0, 0);
      __builtin_amdgcn_s_setprio(0);
    }
    asm volatile("s_waitcnt vmcnt(6)" ::: "memory");  // retire tile t+1's 6 loads
    __syncthreads();
  }
  #undef STAGE

  const int rbase = (lane >> 4) << 2;
  const int cbase = lane & 15;
  #pragma unroll
  for (int mt = 0; mt < 4; ++mt)
    #pragma unroll
    for (int nt = 0; nt < 4; ++nt)
      #pragma unroll
      for (int rr = 0; rr < 4; ++rr) {
        int row = m0 + wm * 64 + mt * 16 + rbase + rr;
        int col = n0 + wn * 64 + nt * 16 + cbase;
        size_t oi = (size_t)row * Nn + col;
        float z = acc[mt][nt][rr];
        if constexpr (MODE == 4) { float m = fmaxf(z, 0.f); outB[oi] = f2bf(m * m); }
        else atomicAdd(outF + oi, z);
      }
}

// ---------------- QKV + fused K4, deep-pipeline (R9) ----------------
// Same pipeline as kg_gemm8p (R8-verified), z selects r/k/v. Grid (4,32,3) =
// 384 blocks (1/CU at 144KB LDS — counted-vmcnt tolerates 1/CU, unlike the
// 2-barrier drain). z==1 epilogue = fused k4: a wave's 64 cols (wn*64+nt*16+
// cbase) are exactly ONE head (n0, wn*64 both 64-aligned), so the kk-norm is
// the same 4-FMA + 4-DPP 16-lane reduction as the R6-verified 128^2 version.
__global__ __launch_bounds__(512, 1) void kg_qkv8p(
    const unsigned short* __restrict__ A0, const unsigned short* __restrict__ A1,
    const unsigned short* __restrict__ A2,
    const unsigned short* __restrict__ B0, const unsigned short* __restrict__ B1,
    const unsigned short* __restrict__ B2,
    float* __restrict__ rbuf, float* __restrict__ kbuf, float* __restrict__ vout,
    const float* __restrict__ aicl,
    const float* __restrict__ kkc, const float* __restrict__ kac,
    float* __restrict__ awb, float* __restrict__ bwb) {
  __shared__ unsigned short lds[3 * 24576];
  const int z = blockIdx.z;
  const unsigned short* A  = z == 0 ? A0 : z == 1 ? A1 : A2;
  const unsigned short* Bt = z == 0 ? B0 : z == 1 ? B1 : B2;
  const int tid = threadIdx.x;
  const int lane = tid & 63;
  const int wave = tid >> 6;
  const int wm = wave >> 2, wn = wave & 3;
  const int m0 = blockIdx.y * 128;
  const int n0 = blockIdx.x * 256;
  const int ntile = 16;                       // K=1024
  const int fr = lane & 15;
  const int fkb = (lane >> 4) << 4;

  int arow[2], acolb[2], brow[4], bcolb[4];
  #pragma unroll
  for (int i = 0; i < 2; ++i) {
    int off = i * 8192 + tid * 16;
    int r = off >> 7;
    arow[i] = r; acolb[i] = (off & 127) ^ ((r & 7) << 4);
  }
  #pragma unroll
  for (int i = 0; i < 4; ++i) {
    int off = i * 8192 + tid * 16;
    int r = off >> 7;
    brow[i] = r; bcolb[i] = (off & 127) ^ ((r & 7) << 4);
  }

  #define STAGE(t_) { \
    int tc = (t_) < ntile ? (t_) : ntile - 1; \
    unsigned short* lb_ = lds + ((t_) % 3) * 24576; \
    const int kk = tc * 64; \
    _Pragma("unroll") \
    for (int i = 0; i < 2; ++i) \
      gll16(A + (size_t)(m0 + arow[i]) * 1024 + kk + (acolb[i] >> 1), \
            lb_ + i * 4096 + wave * 512); \
    _Pragma("unroll") \
    for (int i = 0; i < 4; ++i) \
      gll16(Bt + (size_t)(n0 + brow[i]) * 1024 + kk + (bcolb[i] >> 1), \
            lb_ + 8192 + i * 4096 + wave * 512); \
  }

  f32x4 acc[4][4];
  #pragma unroll
  for (int i = 0; i < 4; ++i)
    #pragma unroll
    for (int j = 0; j < 4; ++j) { f32x4 zz = {0.f, 0.f, 0.f, 0.f}; acc[i][j] = zz; }

  STAGE(0)
  STAGE(1)
  asm volatile("s_waitcnt vmcnt(6)" ::: "memory");
  __syncthreads();

  for (int t = 0; t < ntile; ++t) {
    STAGE(t + 2)
    const unsigned short* lb = lds + (t % 3) * 24576;
    #pragma unroll
    for (int ks = 0; ks < 2; ++ks) {
      short8 af[4], bf[4];
      #pragma unroll
      for (int mt = 0; mt < 4; ++mt) {
        int r = wm * 64 + mt * 16 + fr;
        int byt = (ks * 64 + fkb) ^ ((r & 7) << 4);
        af[mt] = *(const short8*)(lb + r * 64 + (byt >> 1));
      }
      #pragma unroll
      for (int nt = 0; nt < 4; ++nt) {
        int r = wn * 64 + nt * 16 + fr;
        int byt = (ks * 64 + fkb) ^ ((r & 7) << 4);
        bf[nt] = *(const short8*)(lb + 8192 + r * 64 + (byt >> 1));
      }
      __builtin_amdgcn_s_setprio(1);
      #pragma unroll
      for (int mt = 0; mt < 4; ++mt)
        #pragma unroll
        for (int nt = 0; nt < 4; ++nt)
          acc[mt][nt] = __builtin_amdgcn_mfma_f32_16x16x32_bf16(af[mt], bf[nt], acc[mt][nt], 0, 0, 0);
      __builtin_amdgcn_s_setprio(0);
    }
    asm volatile("s_waitcnt vmcnt(6)" ::: "memory");
    __syncthreads();
  }
  #undef STAGE

  const int rbase = (lane >> 4) << 2;
  const int cbase = lane & 15;
  if (z != 1) {
    float* outF = z == 0 ? rbuf : vout;
    #pragma unroll
    for (int mt = 0; mt < 4; ++mt)
      #pragma unroll
      for (int nt = 0; nt < 4; ++nt)
        #pragma unroll
        for (int rr = 0; rr < 4; ++rr) {
          int row = m0 + wm * 64 + mt * 16 + rbase + rr;
          int col = n0 + wn * 64 + nt * 16 + cbase;
          outF[(size_t)row * Cc + col] = acc[mt][nt][rr];
        }
  } else {
    // fused k4: per-(row,head) kk-normalize + a/b vectors + k update
    float kkc4[4], kac4[4];
    #pragma unroll
    for (int nt = 0; nt < 4; ++nt) {
      int col = n0 + wn * 64 + nt * 16 + cbase;
      kkc4[nt] = kkc[col];
      kac4[nt] = kac[col];
    }
    #pragma unroll
    for (int mt = 0; mt < 4; ++mt)
      #pragma unroll
      for (int rr = 0; rr < 4; ++rr) {
        int row = m0 + wm * 64 + mt * 16 + rbase + rr;
        float h0 = acc[mt][0][rr] * kkc4[0];
        float h1 = acc[mt][1][rr] * kkc4[1];
        float h2 = acc[mt][2][rr] * kkc4[2];
        float h3 = acc[mt][3][rr] * kkc4[3];
        float ss = (h0 * h0 + h1 * h1) + (h2 * h2 + h3 * h3);
        ss = dppadd<0xB1>(ss);
        ss = dppadd<0x4E>(ss);
        ss = dppadd<0x124>(ss);
        ss = dppadd<0x128>(ss);
        float inv = 1.f / fmaxf(sqrtf(ss), 1e-12f);
        #pragma unroll
        for (int nt = 0; nt < 4; ++nt) {
          int col = n0 + wn * 64 + nt * 16 + cbase;
          size_t oi = (size_t)row * Cc + col;
          float kv = acc[mt][nt][rr];
          float hn = kv * kkc4[nt] * inv;
          float av = aicl[oi];
          awb[oi] = -hn;
          bwb[oi] = hn * av;
          kbuf[oi] = kv * (1.f + (av - 1.f) * kac4[nt]);
        }
      }
  }
}

// ---------------- K5: WKV7 — R2-proven: 8-wave blocks, shared staging ----------------
// 256 blocks = (half, bh) x 512 threads (8 waves); wave w owns rows
// half*32 + w*4 .. +3. Lane = (rw = lane>>4, cg = lane&15), S[4];
// 16-lane reduce = 4 serial DPPs. CS=8 double buffer, one barrier/chunk.
// Measured 114.1-116.1us across R2/R5-R8. Per-wave 5xb128+1xb32/step is
// the f32 information floor — do not touch without an algorithm change.
#define CS 8
__global__ __launch_bounds__(512, 2) void k5_wkv7(
    const float* __restrict__ r, const float* __restrict__ dec,
    const float* __restrict__ k, const float* __restrict__ v,
    const float* __restrict__ aw, const float* __restrict__ bw,
    float* __restrict__ o) {
  const int blk = blockIdx.x;              // 0..255
  const int bh = blk & 127, half = blk >> 7;
  const int b = bh >> 4, h = bh & 15;
  const int tid = threadIdx.x;
  const int lane = tid & 63;
  const int w = tid >> 6;                  // wave 0..7
  const int cg = lane & 15;                // column group (4 cols)
  const int rw = lane >> 4;                // row within wave's 4
  const int row = half * 32 + w * 4 + rw;  // state row i (0..63)
  const int cb = cg << 2;                  // column base j0

  __shared__ float buf[2][6 * CS * 64];    // 2 x 12 KB

  float S[4];
  #pragma unroll
  for (int j = 0; j < 4; ++j) S[j] = 0.f;

  const size_t base = (size_t)b * Tt * Cc + (size_t)h * Nh;

  const float* sptr = w == 0 ? aw : w == 1 ? dec : w == 2 ? bw
                    : w == 3 ? k  : w == 4 ? r   : v;
  const int srow = lane >> 4;              // t-offset within chunk (0..3)
  const int scol = (lane & 15) << 2;       // col (0..60 step 4)

  uint4 R0, R1;
  #define LOADC(cstart) if (w < 6) { \
    const size_t g0 = base + (size_t)((cstart) + srow) * Cc + scol; \
    R0 = *(const uint4*)(sptr + g0); \
    R1 = *(const uint4*)(sptr + g0 + 4 * Cc); }

  LOADC(0)

  #pragma unroll 1
  for (int c = 0; c < Tt / CS; ++c) {
    float* bp = buf[c & 1];
    if (w < 6) {
      *(uint4*)(bp + w * 512 + (lane << 2)) = R0;        // t 0..3
      *(uint4*)(bp + w * 512 + 256 + (lane << 2)) = R1;  // t 4..7
    }
    const int cn = (c + 1 < Tt / CS) ? (c + 1) : c;
    LOADC(cn * CS)
    __syncthreads();

    float4 Aq[2], Dq[2], Bq[2], Kq[2], Rq[2];
    float Vv[2];
    #define LOADOPS(slot, ss) { \
      const float* sp_ = bp + (ss) * 64; \
      Aq[slot] = *(const float4*)(sp_ + cb); \
      Dq[slot] = *(const float4*)(sp_ + 512 + cb); \
      Bq[slot] = *(const float4*)(sp_ + 1024 + cb); \
      Kq[slot] = *(const float4*)(sp_ + 1536 + cb); \
      Rq[slot] = *(const float4*)(sp_ + 2048 + cb); \
      Vv[slot] = sp_[2560 + row]; }

    LOADOPS(0, 0)
    #pragma unroll
    for (int s = 0; s < CS; ++s) {
      const int cu = s & 1, nx = cu ^ 1;
      if (s + 1 < CS) LOADOPS(nx, s + 1)     // prefetch next step's operands

      float4 a4 = Aq[cu];
      float sa = fmaf(S[1], a4.y, S[0] * a4.x) + fmaf(S[3], a4.w, S[2] * a4.z);
      sa = dppadd<0xB1>(sa);
      sa = dppadd<0x4E>(sa);
      sa = dppadd<0x124>(sa);
      sa = dppadd<0x128>(sa);

      const float vv = Vv[cu];
      float4 d4 = Dq[cu], b4 = Bq[cu], k4 = Kq[cu], r4 = Rq[cu];
      S[0] = fmaf(S[0], d4.x, fmaf(vv, k4.x, sa * b4.x));
      float oo = S[0] * r4.x;
      S[1] = fmaf(S[1], d4.y, fmaf(vv, k4.y, sa * b4.y));
      oo = fmaf(S[1], r4.y, oo);
      S[2] = fmaf(S[2], d4.z, fmaf(vv, k4.z, sa * b4.z));
      oo = fmaf(S[2], r4.z, oo);
      S[3] = fmaf(S[3], d4.w, fmaf(vv, k4.w, sa * b4.w));
      oo = fmaf(S[3], r4.w, oo);

      oo = dppadd<0xB1>(oo);
      oo = dppadd<0x4E>(oo);
      oo = dppadd<0x124>(oo);
      oo = dppadd<0x128>(oo);
      if (cg == 0) o[base + (size_t)(c * CS + s) * Cc + row] = oo;
    }
    #undef LOADOPS
  }
  #undef LOADC
}

// ---------------- K6: head GroupNorm + rk bonus + gate ----------------
__global__ __launch_bounds__(256) void k6_out(
    const float* __restrict__ o, const float* __restrict__ r, const float* __restrict__ k,
    const float* __restrict__ v, const float* __restrict__ rk,
    const float* __restrict__ gnw, const float* __restrict__ gnb,
    const float* __restrict__ g, unsigned short* __restrict__ og) {
  const int row = blockIdx.x, tid = threadIdx.x;
  const int c = tid * 4;
  const size_t base = (size_t)row * Cc + c;
  float o0 = o[base], o1 = o[base + 1], o2 = o[base + 2], o3 = o[base + 3];
  float r0 = r[base], r1 = r[base + 1], r2 = r[base + 2], r3 = r[base + 3];
  float k0 = k[base], k1 = k[base + 1], k2 = k[base + 2], k3 = k[base + 3];
  float s = o0 + o1 + o2 + o3;
  float q = o0 * o0 + o1 * o1 + o2 * o2 + o3 * o3;
  float bs = r0 * k0 * rk[c] + r1 * k1 * rk[c + 1] + r2 * k2 * rk[c + 2] + r3 * k3 * rk[c + 3];
  #pragma unroll
  for (int m = 8; m; m >>= 1) {
    s += __shfl_xor(s, m); q += __shfl_xor(q, m); bs += __shfl_xor(bs, m);
  }
  float mu = s * (1.f / 64.f);
  float var = q * (1.f / 64.f) - mu * mu;
  float rs = rsqrtf(var + 64e-5f);
  float v0 = v[base], v1 = v[base + 1], v2 = v[base + 2], v3 = v[base + 3];
  float z0 = (o0 - mu) * rs * gnw[c] + gnb[c] + bs * v0;
  float z1 = (o1 - mu) * rs * gnw[c + 1] + gnb[c + 1] + bs * v1;
  float z2 = (o2 - mu) * rs * gnw[c + 2] + gnb[c + 2] + bs * v2;
  float z3 = (o3 - mu) * rs * gnw[c + 3] + gnb[c + 3] + bs * v3;
  ushort4 u;
  u.x = f2bf(z0 * g[base]); u.y = f2bf(z1 * g[base + 1]);
  u.z = f2bf(z2 * g[base + 2]); u.w = f2bf(z3 * g[base + 3]);
  *(ushort4*)(og + base) = u;
}

// ---------------- K8: FFN LN + time-shift mix ----------------
__global__ __launch_bounds__(256) void k8_ffnmix(
    const float* __restrict__ x2, const float* __restrict__ lnw, const float* __restrict__ lnb,
    const float* __restrict__ fxk, unsigned short* __restrict__ kf) {
  __shared__ float red[8];
  const int row = blockIdx.x;
  const int t = row & (Tt - 1);
  const int tid = threadIdx.x;
  const int c = tid * 4;
  const size_t base = (size_t)row * Cc + c;
  float a0 = x2[base], a1 = x2[base + 1], a2 = x2[base + 2], a3 = x2[base + 3];
  float mu, rs;
  row_stats(a0, a1, a2, a3, red, mu, rs, 1e-5f);
  float w0 = lnw[c], w1 = lnw[c + 1], w2 = lnw[c + 2], w3 = lnw[c + 3];
  float b0 = lnb[c], b1 = lnb[c + 1], b2 = lnb[c + 2], b3 = lnb[c + 3];
  float f0 = (a0 - mu) * rs * w0 + b0, f1 = (a1 - mu) * rs * w1 + b1;
  float f2 = (a2 - mu) * rs * w2 + b2, f3 = (a3 - mu) * rs * w3 + b3;
  float p0 = 0.f, p1 = 0.f, p2 = 0.f, p3 = 0.f;
  if (t > 0) {
    const size_t pb_ = base - Cc;
    float q0 = x2[pb_], q1 = x2[pb_ + 1], q2 = x2[pb_ + 2], q3 = x2[pb_ + 3];
    row_stats(q0, q1, q2, q3, red, mu, rs, 1e-5f);
    p0 = (q0 - mu) * rs * w0 + b0; p1 = (q1 - mu) * rs * w1 + b1;
    p2 = (q2 - mu) * rs * w2 + b2; p3 = (q3 - mu) * rs * w3 + b3;
  }
  ushort4 u;
  u.x = f2bf(f0 + (p0 - f0) * fxk[c]);
  u.y = f2bf(f1 + (p1 - f1) * fxk[c + 1]);
  u.z = f2bf(f2 + (p2 - f2) * fxk[c + 2]);
  u.w = f2bf(f3 + (p3 - f3) * fxk[c + 3]);
  *(ushort4*)(kf + base) = u;
}

// ---------------- host ----------------
extern "C" void kernel_launch(void* const* d_in, const int* in_sizes, int n_in,
                              void* d_out, int out_size, void* d_ws, size_t ws_size,
                              hipStream_t stream) {
  (void)in_sizes; (void)n_in; (void)out_size; (void)ws_size;
  const float* x    = (const float*)d_in[0];
  const float* lnpw = (const float*)d_in[2];
  const float* lnpb = (const float*)d_in[3];
  const float* lnaw = (const float*)d_in[4];
  const float* lnab = (const float*)d_in[5];
  const float* lnfw = (const float*)d_in[6];
  const float* lnfb = (const float*)d_in[7];
  const float* cxr  = (const float*)d_in[8];
  const float* cxw  = (const float*)d_in[9];
  const float* cxk  = (const float*)d_in[10];
  const float* cxv  = (const float*)d_in[11];
  const float* cxa  = (const float*)d_in[12];
  const float* cxg  = (const float*)d_in[13];
  const float* w0v  = (const float*)d_in[14];
  const float* w1m  = (const float*)d_in[15];
  const float* w2m  = (const float*)d_in[16];
  const float* a0v  = (const float*)d_in[17];
  const float* a1m  = (const float*)d_in[18];
  const float* a2m  = (const float*)d_in[19];
  const float* g1m  = (const float*)d_in[20];
  const float* g2m  = (const float*)d_in[21];
  const float* kkv  = (const float*)d_in[22];
  const float* kav  = (const float*)d_in[23];
  const float* rkv  = (const float*)d_in[24];
  const float* Wr   = (const float*)d_in[25];
  const float* Wk   = (const float*)d_in[26];
  const float* Wv   = (const float*)d_in[27];
  const float* Wo   = (const float*)d_in[28];
  const float* gnw  = (const float*)d_in[29];
  const float* gnb  = (const float*)d_in[30];
  const float* fxk  = (const float*)d_in[31];
  const float* Wf1  = (const float*)d_in[32];
  const float* Wf2  = (const float*)d_in[33];

  char* ws = (char*)d_ws;
  float* outx = (float*)d_out;          // final x (B,T,C)
  float* vout = outx + BTC;             // v_first = v (B,T,C)

  // workspace layout (aliases noted)
  size_t off = 0;
  unsigned short* WrT  = (unsigned short*)(ws + off); off += 2097152;
  unsigned short* WkT  = (unsigned short*)(ws + off); off += 2097152;
  unsigned short* WvT  = (unsigned short*)(ws + off); off += 2097152;
  unsigned short* WoT  = (unsigned short*)(ws + off); off += 2097152;
  unsigned short* Wf1T = (unsigned short*)(ws + off); off += 8388608;
  unsigned short* Wf2T = (unsigned short*)(ws + off); off += 8388608;
  unsigned short* w1T  = (unsigned short*)(ws + off); off += 131072;
  unsigned short* w2T  = (unsigned short*)(ws + off); off += 131072;
  unsigned short* a1T  = (unsigned short*)(ws + off); off += 131072;
  unsigned short* a2T  = (unsigned short*)(ws + off); off += 131072;
  unsigned short* g1T  = (unsigned short*)(ws + off); off += 262144;
  unsigned short* g2T  = (unsigned short*)(ws + off); off += 262144;
  float* xln = (float*)(ws + off); off += 16777216;
  unsigned short* mixR = (unsigned short*)(ws + off);          // 6 x 8388608
  unsigned short* mixW = (unsigned short*)(ws + off + 8388608);
  unsigned short* mixK = (unsigned short*)(ws + off + 16777216);
  unsigned short* mixV = (unsigned short*)(ws + off + 25165824);
  unsigned short* mixA = (unsigned short*)(ws + off + 33554432);
  unsigned short* mixG = (unsigned short*)(ws + off + 41943040);
  unsigned short* hbuf = (unsigned short*)(ws + off);          // alias mix (dead by then)
  off += 50331648;
  unsigned short* tmpw = (unsigned short*)(ws + off); off += 524288;
  unsigned short* tmpa = (unsigned short*)(ws + off); off += 524288;
  unsigned short* tmpg = (unsigned short*)(ws + off); off += 1048576;
  float* decay = (float*)(ws + off);
  unsigned short* og = (unsigned short*)(ws + off);            // alias decay (dead after K5)
  off += 16777216;
  float* aicl = (float*)(ws + off);
  float* obuf = (float*)(ws + off);                            // alias aicl (dead after qkv)
  off += 16777216;
  float* gout = (float*)(ws + off); off += 16777216;
  float* rbuf = (float*)(ws + off);
  float* x2   = (float*)(ws + off);                            // alias rbuf (dead after K6)
  off += 16777216;
  float* kbuf = (float*)(ws + off); off += 16777216;
  float* awb  = (float*)(ws + off);
  unsigned short* kf = (unsigned short*)(ws + off);            // alias awb (dead after K5)
  off += 16777216;
  float* bwb  = (float*)(ws + off); off += 16777216;           // total ~187 MB

  dim3 tb(32, 8);
  // weight prep: f32 (K,N) -> bf16 (N,K) — ALL 12 jobs in one dispatch
  TPack tp;
  tp.d[0]  = TDesc{Wr,  WrT,  1024, 1024, 0,     32};
  tp.d[1]  = TDesc{Wk,  WkT,  1024, 1024, 1024,  32};
  tp.d[2]  = TDesc{Wv,  WvT,  1024, 1024, 2048,  32};
  tp.d[3]  = TDesc{Wo,  WoT,  1024, 1024, 3072,  32};
  tp.d[4]  = TDesc{Wf1, Wf1T, 1024, 4096, 4096,  128};
  tp.d[5]  = TDesc{Wf2, Wf2T, 4096, 1024, 8192,  32};
  tp.d[6]  = TDesc{w1m, w1T,  1024, 64,   12288, 2};
  tp.d[7]  = TDesc{w2m, w2T,  64,   1024, 12352, 32};
  tp.d[8]  = TDesc{a1m, a1T,  1024, 64,   12416, 2};
  tp.d[9]  = TDesc{a2m, a2T,  64,   1024, 12480, 32};
  tp.d[10] = TDesc{g1m, g1T,  1024, 128,  12544, 4};
  tp.d[11] = TDesc{g2m, g2T,  128,  1024, 12672, 32};
  kt_transpose_multi<<<12800, tb, 0, stream>>>(tp);

  // K1: pre-LN + attn-LN + shift mixes
  k1_mix<<<Mm, 256, 0, stream>>>(x, lnpw, lnpb, lnaw, lnab, cxr, cxw, cxk, cxv, cxa, cxg,
                                 xln, mixR, mixW, mixK, mixV, mixA, mixG);

  // LoRA chains — 2 z-batched dispatches
  kg_lora1<<<dim3(1, 32, 4), 256, 0, stream>>>(mixW, mixA, mixG, w1T, a1T, g1T,
                                               tmpw, tmpa, tmpg);
  kg_lora2<<<dim3(16, 32, 3), 256, 0, stream>>>(tmpw, tmpa, tmpg, w2T, a2T, g2T,
                                                decay, aicl, gout, w0v, a0v);

  // r / k / v projections + fused k4 — deep-pipeline, grid (4,32,3) = 384 blocks
  kg_qkv8p<<<dim3(4, 32, 3), 512, 0, stream>>>(mixR, mixK, mixV, WrT, WkT, WvT,
                                               rbuf, kbuf, vout,
                                               aicl, kkv, kav, awb, bwb);

  // WKV7 scan — R2-proven config
  k5_wkv7<<<256, 512, 0, stream>>>(rbuf, decay, kbuf, vout, awb, bwb, obuf);
  // GN + bonus + gate
  k6_out<<<Mm, 256, 0, stream>>>(obuf, rbuf, kbuf, vout, rkv, gnw, gnb, gout, og);
  // o-projection + residual -> x2 AND outx seed (mode 9; 128x64: 512 blocks = 2/CU)
  kg_gemm64<9><<<dim3(16, 32), 256, 0, stream>>>(og, WoT, Mm, 1024, 1024, x2, nullptr, nullptr, xln, outx);
  // FFN
  k8_ffnmix<<<Mm, 256, 0, stream>>>(x2, lnfw, lnfb, fxk, kf);
  // FFN1: deep-pipeline 128x256 tile, grid (16,32) = 512 blocks, K=1024
  kg_gemm8p<4><<<dim3(16, 32, 1), 512, 0, stream>>>(kf, Wf1T, 4096, 1024, 1024, nullptr, hbuf);
  // FFN2: deep-pipeline split-K z=2 (K=2048 each), atomicAdd into seeded outx
  kg_gemm8p<8><<<dim3(4, 32, 2), 512, 0, stream>>>(hbuf, Wf2T, 1024, 4096, 2048, outx, nullptr);
}